// Round 1
// baseline (8035.490 us; speedup 1.0000x reference)
//
#include <hip/hip_runtime.h>

// SparseNGCNLayer: base = relu(SpMM(feat, W) + bias); base = A @ base (x2)
// Round 1: atomic-scatter baseline.
//   - spmm_scatter: 32 threads per nnz, each thread handles 4 channels.
//   - prop_scatter: 32 threads per edge, each thread handles 4 channels.
//   - unsafeAtomicAdd -> HW global_atomic_add_f32 (device scope, L2/TCC RMW).
// Buffers: d_out (result) + d_ws (one [n_nodes,128] f32 ping buffer, 51.2 MB).

#define CH 128

__global__ void spmm_scatter_kernel(const int* __restrict__ rows,
                                    const int* __restrict__ cols,
                                    const float* __restrict__ vals,
                                    const float* __restrict__ weight, // [512, 128]
                                    float* __restrict__ out,          // [n, 128]
                                    int nnz) {
    long long tid = (long long)blockIdx.x * blockDim.x + threadIdx.x;
    long long total = (long long)nnz * 32;
    if (tid >= total) return;
    int e = (int)(tid >> 5);
    int lane = (int)(tid & 31);
    int r = rows[e];
    int c = cols[e];
    float v = vals[e];
    const float4 w = *reinterpret_cast<const float4*>(weight + (long long)c * CH + lane * 4);
    float* dst = out + (long long)r * CH + lane * 4;
    unsafeAtomicAdd(dst + 0, v * w.x);
    unsafeAtomicAdd(dst + 1, v * w.y);
    unsafeAtomicAdd(dst + 2, v * w.z);
    unsafeAtomicAdd(dst + 3, v * w.w);
}

__global__ void bias_relu_kernel(float* __restrict__ buf,
                                 const float* __restrict__ bias, // [128]
                                 long long total) {
    long long i = ((long long)blockIdx.x * blockDim.x + threadIdx.x) * 4;
    if (i >= total) return;
    float4 v = *reinterpret_cast<float4*>(buf + i);
    int ch = (int)(i & (CH - 1));
    float4 b = *reinterpret_cast<const float4*>(bias + ch);
    v.x = fmaxf(v.x + b.x, 0.0f);
    v.y = fmaxf(v.y + b.y, 0.0f);
    v.z = fmaxf(v.z + b.z, 0.0f);
    v.w = fmaxf(v.w + b.w, 0.0f);
    *reinterpret_cast<float4*>(buf + i) = v;
}

__global__ void prop_scatter_kernel(const int* __restrict__ rows,
                                    const int* __restrict__ cols,
                                    const float* __restrict__ vals,
                                    const float* __restrict__ src, // [n, 128]
                                    float* __restrict__ dst,       // [n, 128]
                                    int ne) {
    long long tid = (long long)blockIdx.x * blockDim.x + threadIdx.x;
    long long total = (long long)ne * 32;
    if (tid >= total) return;
    int e = (int)(tid >> 5);
    int lane = (int)(tid & 31);
    int r = rows[e];
    int c = cols[e];
    float v = vals[e];
    const float4 s = *reinterpret_cast<const float4*>(src + (long long)c * CH + lane * 4);
    float* d = dst + (long long)r * CH + lane * 4;
    unsafeAtomicAdd(d + 0, v * s.x);
    unsafeAtomicAdd(d + 1, v * s.y);
    unsafeAtomicAdd(d + 2, v * s.z);
    unsafeAtomicAdd(d + 3, v * s.w);
}

extern "C" void kernel_launch(void* const* d_in, const int* in_sizes, int n_in,
                              void* d_out, int out_size, void* d_ws, size_t ws_size,
                              hipStream_t stream) {
    const int*   feat_rows = (const int*)d_in[0];
    const int*   feat_cols = (const int*)d_in[1];
    const float* feat_vals = (const float*)d_in[2];
    const int*   adj_rows  = (const int*)d_in[3];
    const int*   adj_cols  = (const int*)d_in[4];
    const float* adj_vals  = (const float*)d_in[5];
    const float* weight    = (const float*)d_in[6];
    const float* bias      = (const float*)d_in[7];

    const int nnz = in_sizes[0];
    const int ne  = in_sizes[3];
    const int n_nodes = out_size / CH;

    float* out  = (float*)d_out;
    float* bufA = (float*)d_ws;  // needs n_nodes*128*4 = 51.2 MB

    const size_t nbytes = (size_t)n_nodes * CH * sizeof(float);
    const long long total_elems = (long long)n_nodes * CH;

    const int BLK = 256;
    const long long spmm_threads = (long long)nnz * 32;
    const int spmm_blocks = (int)((spmm_threads + BLK - 1) / BLK);
    const long long prop_threads = (long long)ne * 32;
    const int prop_blocks = (int)((prop_threads + BLK - 1) / BLK);
    const int ew_blocks = (int)((total_elems / 4 + BLK - 1) / BLK);

    // 1) base = SpMM(feat, W)  -> d_out
    hipMemsetAsync(d_out, 0, nbytes, stream);
    spmm_scatter_kernel<<<spmm_blocks, BLK, 0, stream>>>(
        feat_rows, feat_cols, feat_vals, weight, out, nnz);

    // 2) base = relu(base + bias)
    bias_relu_kernel<<<ew_blocks, BLK, 0, stream>>>(out, bias, total_elems);

    // 3) prop 1: bufA = A @ base
    hipMemsetAsync(bufA, 0, nbytes, stream);
    prop_scatter_kernel<<<prop_blocks, BLK, 0, stream>>>(
        adj_rows, adj_cols, adj_vals, out, bufA, ne);

    // 4) prop 2: d_out = A @ bufA
    hipMemsetAsync(d_out, 0, nbytes, stream);
    prop_scatter_kernel<<<prop_blocks, BLK, 0, stream>>>(
        adj_rows, adj_cols, adj_vals, bufA, out, ne);
}

// Round 2
// 1160.126 us; speedup vs baseline: 6.9264x; 6.9264x over previous
//
#include <hip/hip_runtime.h>

// SparseNGCNLayer: base = relu(SpMM(feat, W) + bias); base = A @ base (x2)
// Round 2: CSR gather-reduce. Build CSR (by destination row) on device each
// call, then one wave per output row accumulates in registers -> single
// coalesced 512B store. Eliminates all f32 atomics from the hot path.
// Fallback to round-1 atomic scatter if ws_size can't fit CSR arrays.

#define CH 128

// ---------------- CSR build ----------------

__global__ void hist_kernel(const int* __restrict__ rows, int* __restrict__ counts, int n) {
    int i = blockIdx.x * blockDim.x + threadIdx.x;
    if (i < n) atomicAdd(&counts[rows[i]], 1);
}

#define SCAN_T 1024
// exclusive scan of counts[0..n) -> row_ptr[0..n] (row_ptr[n]=total) and cursor[0..n)
__global__ void scan_kernel(const int* __restrict__ in, int* __restrict__ row_ptr,
                            int* __restrict__ cursor, int n) {
    __shared__ int lds[SCAN_T];
    __shared__ int s_carry;
    int tid = threadIdx.x;
    if (tid == 0) s_carry = 0;
    __syncthreads();
    for (int base = 0; base < n; base += SCAN_T) {
        int i = base + tid;
        int x = (i < n) ? in[i] : 0;
        lds[tid] = x;
        __syncthreads();
        for (int off = 1; off < SCAN_T; off <<= 1) {
            int y = (tid >= off) ? lds[tid - off] : 0;
            __syncthreads();
            lds[tid] += y;
            __syncthreads();
        }
        int incl = lds[tid];
        int c = s_carry;
        if (i < n) {
            int excl = c + incl - x;
            row_ptr[i] = excl;
            cursor[i] = excl;
        }
        __syncthreads();
        if (tid == 0) s_carry = c + lds[SCAN_T - 1];
        __syncthreads();
    }
    if (tid == 0) row_ptr[n] = s_carry;
}

__global__ void scatter_kernel(const int* __restrict__ rows, const int* __restrict__ cols,
                               const float* __restrict__ vals, int* __restrict__ cursor,
                               int* __restrict__ out_col, float* __restrict__ out_val, int n) {
    int i = blockIdx.x * blockDim.x + threadIdx.x;
    if (i >= n) return;
    int r = rows[i];
    int p = atomicAdd(&cursor[r], 1);
    out_col[p] = cols[i];
    out_val[p] = vals[i];
}

// ---------------- gather-reduce row kernels ----------------
// one wave (64 lanes) per output row; each lane owns 2 channels (float2).

__global__ void spmm_csr_kernel(const int* __restrict__ row_ptr, const int* __restrict__ cols,
                                const float* __restrict__ vals, const float* __restrict__ W,
                                float* __restrict__ out, int n) {
    int gtid = blockIdx.x * blockDim.x + threadIdx.x;
    int wid = gtid >> 6;
    int lane = gtid & 63;
    if (wid >= n) return;
    int s = row_ptr[wid], e = row_ptr[wid + 1];
    const float2* Wp = reinterpret_cast<const float2*>(W);
    float2 acc = {0.0f, 0.0f};
    for (int i = s; i < e; i++) {
        int c = cols[i];
        float v = vals[i];
        float2 w = Wp[c * 64 + lane];
        acc.x += v * w.x;
        acc.y += v * w.y;
    }
    reinterpret_cast<float2*>(out)[(long long)wid * 64 + lane] = acc;
}

__global__ void prop_csr_kernel(const int* __restrict__ row_ptr, const int* __restrict__ cols,
                                const float* __restrict__ vals, const float* __restrict__ src,
                                float* __restrict__ dst, int n) {
    int gtid = blockIdx.x * blockDim.x + threadIdx.x;
    int wid = gtid >> 6;
    int lane = gtid & 63;
    if (wid >= n) return;
    int s = row_ptr[wid], e = row_ptr[wid + 1];
    const float2* Sp = reinterpret_cast<const float2*>(src);
    float2 acc = {0.0f, 0.0f};
    for (int i = s; i < e; i++) {
        int c = cols[i];
        float v = vals[i];
        float2 x = Sp[(long long)c * 64 + lane];
        acc.x += v * x.x;
        acc.y += v * x.y;
    }
    reinterpret_cast<float2*>(dst)[(long long)wid * 64 + lane] = acc;
}

__global__ void bias_relu_kernel(float* __restrict__ buf, const float* __restrict__ bias,
                                 long long total) {
    long long i = ((long long)blockIdx.x * blockDim.x + threadIdx.x) * 4;
    if (i >= total) return;
    float4 v = *reinterpret_cast<float4*>(buf + i);
    int ch = (int)(i & (CH - 1));
    float4 b = *reinterpret_cast<const float4*>(bias + ch);
    v.x = fmaxf(v.x + b.x, 0.0f);
    v.y = fmaxf(v.y + b.y, 0.0f);
    v.z = fmaxf(v.z + b.z, 0.0f);
    v.w = fmaxf(v.w + b.w, 0.0f);
    *reinterpret_cast<float4*>(buf + i) = v;
}

// ---------------- round-1 fallback (atomic scatter) ----------------

__global__ void spmm_scatter_kernel(const int* __restrict__ rows, const int* __restrict__ cols,
                                    const float* __restrict__ vals, const float* __restrict__ weight,
                                    float* __restrict__ out, int nnz) {
    long long tid = (long long)blockIdx.x * blockDim.x + threadIdx.x;
    if (tid >= (long long)nnz * 32) return;
    int e = (int)(tid >> 5), lane = (int)(tid & 31);
    int r = rows[e], c = cols[e];
    float v = vals[e];
    const float4 w = *reinterpret_cast<const float4*>(weight + (long long)c * CH + lane * 4);
    float* dst = out + (long long)r * CH + lane * 4;
    unsafeAtomicAdd(dst + 0, v * w.x);
    unsafeAtomicAdd(dst + 1, v * w.y);
    unsafeAtomicAdd(dst + 2, v * w.z);
    unsafeAtomicAdd(dst + 3, v * w.w);
}

__global__ void prop_scatter_kernel(const int* __restrict__ rows, const int* __restrict__ cols,
                                    const float* __restrict__ vals, const float* __restrict__ src,
                                    float* __restrict__ dst, int ne) {
    long long tid = (long long)blockIdx.x * blockDim.x + threadIdx.x;
    if (tid >= (long long)ne * 32) return;
    int e = (int)(tid >> 5), lane = (int)(tid & 31);
    int r = rows[e], c = cols[e];
    float v = vals[e];
    const float4 s = *reinterpret_cast<const float4*>(src + (long long)c * CH + lane * 4);
    float* d = dst + (long long)r * CH + lane * 4;
    unsafeAtomicAdd(d + 0, v * s.x);
    unsafeAtomicAdd(d + 1, v * s.y);
    unsafeAtomicAdd(d + 2, v * s.z);
    unsafeAtomicAdd(d + 3, v * s.w);
}

// ---------------- launch ----------------

static inline size_t align16(size_t x) { return (x + 15) & ~(size_t)15; }

extern "C" void kernel_launch(void* const* d_in, const int* in_sizes, int n_in,
                              void* d_out, int out_size, void* d_ws, size_t ws_size,
                              hipStream_t stream) {
    const int*   feat_rows = (const int*)d_in[0];
    const int*   feat_cols = (const int*)d_in[1];
    const float* feat_vals = (const float*)d_in[2];
    const int*   adj_rows  = (const int*)d_in[3];
    const int*   adj_cols  = (const int*)d_in[4];
    const float* adj_vals  = (const float*)d_in[5];
    const float* weight    = (const float*)d_in[6];
    const float* bias      = (const float*)d_in[7];

    const int nnz = in_sizes[0];
    const int ne  = in_sizes[3];
    const int n   = out_size / CH;   // n_nodes

    float* out = (float*)d_out;
    char*  ws  = (char*)d_ws;

    const size_t NB = (size_t)n * CH * sizeof(float);
    const long long total_elems = (long long)n * CH;
    const int BLK = 256;
    const int ew_blocks = (int)((total_elems / 4 + BLK - 1) / BLK);
    const int maxe = nnz > ne ? nnz : ne;

    // ws layout (fast path)
    size_t off = 0;
    float* ping    = (float*)(ws + off); off += align16(NB);
    int*   row_ptr = (int*)(ws + off);   off += align16(((size_t)n + 1) * 4);
    int*   cursor  = (int*)(ws + off);   off += align16((size_t)n * 4);
    int*   ccols   = (int*)(ws + off);   off += align16((size_t)maxe * 4);
    float* cvals   = (float*)(ws + off); off += align16((size_t)maxe * 4);
    const bool fast = (ws_size >= off);

    if (fast) {
        const int eb_feat = (nnz + BLK - 1) / BLK;
        const int eb_adj  = (ne + BLK - 1) / BLK;
        const int row_blocks = (int)(((long long)n * 64 + BLK - 1) / BLK);

        // --- feat CSR ---
        hipMemsetAsync(cursor, 0, (size_t)n * 4, stream);
        hist_kernel<<<eb_feat, BLK, 0, stream>>>(feat_rows, cursor, nnz);
        scan_kernel<<<1, SCAN_T, 0, stream>>>(cursor, row_ptr, cursor, n);
        // note: scan reads cursor (counts) and rewrites it as cursor -- same
        // buffer is safe because each index is read before being written.
        scatter_kernel<<<eb_feat, BLK, 0, stream>>>(feat_rows, feat_cols, feat_vals,
                                                    cursor, ccols, cvals, nnz);
        // --- base = SpMM(feat, W) -> d_out ---
        spmm_csr_kernel<<<row_blocks, BLK, 0, stream>>>(row_ptr, ccols, cvals, weight, out, n);
        bias_relu_kernel<<<ew_blocks, BLK, 0, stream>>>(out, bias, total_elems);

        // --- adj CSR (reuses same region) ---
        hipMemsetAsync(cursor, 0, (size_t)n * 4, stream);
        hist_kernel<<<eb_adj, BLK, 0, stream>>>(adj_rows, cursor, ne);
        scan_kernel<<<1, SCAN_T, 0, stream>>>(cursor, row_ptr, cursor, n);
        scatter_kernel<<<eb_adj, BLK, 0, stream>>>(adj_rows, adj_cols, adj_vals,
                                                   cursor, ccols, cvals, ne);
        // --- prop x2 ---
        prop_csr_kernel<<<row_blocks, BLK, 0, stream>>>(row_ptr, ccols, cvals, out, ping, n);
        prop_csr_kernel<<<row_blocks, BLK, 0, stream>>>(row_ptr, ccols, cvals, ping, out, n);
    } else {
        // round-1 fallback: atomic scatter (needs only the ping buffer)
        const int spmm_blocks = (int)(((long long)nnz * 32 + BLK - 1) / BLK);
        const int prop_blocks = (int)(((long long)ne * 32 + BLK - 1) / BLK);
        hipMemsetAsync(d_out, 0, NB, stream);
        spmm_scatter_kernel<<<spmm_blocks, BLK, 0, stream>>>(feat_rows, feat_cols, feat_vals,
                                                             weight, out, nnz);
        bias_relu_kernel<<<ew_blocks, BLK, 0, stream>>>(out, bias, total_elems);
        hipMemsetAsync(ping, 0, NB, stream);
        prop_scatter_kernel<<<prop_blocks, BLK, 0, stream>>>(adj_rows, adj_cols, adj_vals,
                                                             out, ping, ne);
        hipMemsetAsync(d_out, 0, NB, stream);
        prop_scatter_kernel<<<prop_blocks, BLK, 0, stream>>>(adj_rows, adj_cols, adj_vals,
                                                             ping, out, ne);
    }
}

// Round 3
// 686.949 us; speedup vs baseline: 11.6974x; 1.6888x over previous
//
#include <hip/hip_runtime.h>

// SparseNGCNLayer: base = relu(SpMM(feat, W) + bias); base = A @ base (x2)
// Round 3: CSR gather-reduce with
//   - parallel 3-phase scan (was: 185us single-WG serial scan, x2)
//   - packed int2 (col, val) CSR entries (half the scattered stores/loads)
//   - 4x-unrolled gather loops (4 independent L3 gathers in flight)
//   - bias+relu fused into SpMM epilogue

#define CH 128
#define SCAN_BLK 1024

// ---------------- CSR build ----------------

__global__ void hist_kernel(const int* __restrict__ rows, int* __restrict__ counts, int n) {
    int i = blockIdx.x * blockDim.x + threadIdx.x;
    if (i < n) atomicAdd(&counts[rows[i]], 1);
}

// phase A: per-block (1024-elem chunk) local exclusive scan + block sum
__global__ void scan_local_kernel(const int* __restrict__ counts, int* __restrict__ row_ptr,
                                  int* __restrict__ bsum, int n) {
    __shared__ int lds[SCAN_BLK];
    int tid = threadIdx.x;
    int i = blockIdx.x * SCAN_BLK + tid;
    int x = (i < n) ? counts[i] : 0;
    lds[tid] = x;
    __syncthreads();
    for (int off = 1; off < SCAN_BLK; off <<= 1) {
        int y = (tid >= off) ? lds[tid - off] : 0;
        __syncthreads();
        lds[tid] += y;
        __syncthreads();
    }
    if (i < n) row_ptr[i] = lds[tid] - x;      // local exclusive
    if (tid == SCAN_BLK - 1) bsum[blockIdx.x] = lds[SCAN_BLK - 1];
}

// phase B: single-WG exclusive scan of block sums (nb <= 1024) + total
__global__ void scan_bsum_kernel(int* __restrict__ bsum, int nb, int* __restrict__ total_out) {
    __shared__ int lds[SCAN_BLK];
    int tid = threadIdx.x;
    int x = (tid < nb) ? bsum[tid] : 0;
    lds[tid] = x;
    __syncthreads();
    for (int off = 1; off < SCAN_BLK; off <<= 1) {
        int y = (tid >= off) ? lds[tid - off] : 0;
        __syncthreads();
        lds[tid] += y;
        __syncthreads();
    }
    if (tid < nb) bsum[tid] = lds[tid] - x;    // exclusive
    if (tid == SCAN_BLK - 1) *total_out = lds[SCAN_BLK - 1];
}

// phase C: add block offsets; produce row_ptr and cursor copies
__global__ void add_off_kernel(int* __restrict__ row_ptr, int* __restrict__ cursor,
                               const int* __restrict__ bsum, int n) {
    int i = blockIdx.x * blockDim.x + threadIdx.x;
    if (i >= n) return;
    int v = row_ptr[i] + bsum[i >> 10];
    row_ptr[i] = v;
    cursor[i] = v;
}

__global__ void scatter_kernel(const int* __restrict__ rows, const int* __restrict__ cols,
                               const float* __restrict__ vals, int* __restrict__ cursor,
                               int2* __restrict__ out_cv, int n) {
    int i = blockIdx.x * blockDim.x + threadIdx.x;
    if (i >= n) return;
    int r = rows[i];
    int p = atomicAdd(&cursor[r], 1);
    out_cv[p] = make_int2(cols[i], __float_as_int(vals[i]));
}

// ---------------- gather-reduce row kernels ----------------
// one wave (64 lanes) per output row; each lane owns 2 channels (float2).

__global__ void spmm_csr_kernel(const int* __restrict__ row_ptr, const int2* __restrict__ cv,
                                const float* __restrict__ W, const float* __restrict__ bias,
                                float* __restrict__ out, int n) {
    int gtid = blockIdx.x * blockDim.x + threadIdx.x;
    int wid = gtid >> 6;
    int lane = gtid & 63;
    if (wid >= n) return;
    int s = row_ptr[wid], e = row_ptr[wid + 1];
    const float2* Wp = reinterpret_cast<const float2*>(W);
    float2 acc = reinterpret_cast<const float2*>(bias)[lane];
    int i = s;
    for (; i + 4 <= e; i += 4) {
        int2 c0 = cv[i], c1 = cv[i + 1], c2 = cv[i + 2], c3 = cv[i + 3];
        float2 x0 = Wp[c0.x * 64 + lane];
        float2 x1 = Wp[c1.x * 64 + lane];
        float2 x2 = Wp[c2.x * 64 + lane];
        float2 x3 = Wp[c3.x * 64 + lane];
        acc.x += __int_as_float(c0.y) * x0.x; acc.y += __int_as_float(c0.y) * x0.y;
        acc.x += __int_as_float(c1.y) * x1.x; acc.y += __int_as_float(c1.y) * x1.y;
        acc.x += __int_as_float(c2.y) * x2.x; acc.y += __int_as_float(c2.y) * x2.y;
        acc.x += __int_as_float(c3.y) * x3.x; acc.y += __int_as_float(c3.y) * x3.y;
    }
    for (; i < e; i++) {
        int2 c = cv[i];
        float2 x = Wp[c.x * 64 + lane];
        acc.x += __int_as_float(c.y) * x.x;
        acc.y += __int_as_float(c.y) * x.y;
    }
    acc.x = fmaxf(acc.x, 0.0f);
    acc.y = fmaxf(acc.y, 0.0f);
    reinterpret_cast<float2*>(out)[(long long)wid * 64 + lane] = acc;
}

__global__ void prop_csr_kernel(const int* __restrict__ row_ptr, const int2* __restrict__ cv,
                                const float* __restrict__ src, float* __restrict__ dst, int n) {
    int gtid = blockIdx.x * blockDim.x + threadIdx.x;
    int wid = gtid >> 6;
    int lane = gtid & 63;
    if (wid >= n) return;
    int s = row_ptr[wid], e = row_ptr[wid + 1];
    const float2* Sp = reinterpret_cast<const float2*>(src);
    float2 acc = {0.0f, 0.0f};
    int i = s;
    for (; i + 4 <= e; i += 4) {
        int2 c0 = cv[i], c1 = cv[i + 1], c2 = cv[i + 2], c3 = cv[i + 3];
        float2 x0 = Sp[(long long)c0.x * 64 + lane];
        float2 x1 = Sp[(long long)c1.x * 64 + lane];
        float2 x2 = Sp[(long long)c2.x * 64 + lane];
        float2 x3 = Sp[(long long)c3.x * 64 + lane];
        acc.x += __int_as_float(c0.y) * x0.x; acc.y += __int_as_float(c0.y) * x0.y;
        acc.x += __int_as_float(c1.y) * x1.x; acc.y += __int_as_float(c1.y) * x1.y;
        acc.x += __int_as_float(c2.y) * x2.x; acc.y += __int_as_float(c2.y) * x2.y;
        acc.x += __int_as_float(c3.y) * x3.x; acc.y += __int_as_float(c3.y) * x3.y;
    }
    for (; i < e; i++) {
        int2 c = cv[i];
        float2 x = Sp[(long long)c.x * 64 + lane];
        acc.x += __int_as_float(c.y) * x.x;
        acc.y += __int_as_float(c.y) * x.y;
    }
    reinterpret_cast<float2*>(dst)[(long long)wid * 64 + lane] = acc;
}

__global__ void bias_relu_kernel(float* __restrict__ buf, const float* __restrict__ bias,
                                 long long total) {
    long long i = ((long long)blockIdx.x * blockDim.x + threadIdx.x) * 4;
    if (i >= total) return;
    float4 v = *reinterpret_cast<float4*>(buf + i);
    int ch = (int)(i & (CH - 1));
    float4 b = *reinterpret_cast<const float4*>(bias + ch);
    v.x = fmaxf(v.x + b.x, 0.0f);
    v.y = fmaxf(v.y + b.y, 0.0f);
    v.z = fmaxf(v.z + b.z, 0.0f);
    v.w = fmaxf(v.w + b.w, 0.0f);
    *reinterpret_cast<float4*>(buf + i) = v;
}

// ---------------- round-1 fallback (atomic scatter) ----------------

__global__ void spmm_scatter_kernel(const int* __restrict__ rows, const int* __restrict__ cols,
                                    const float* __restrict__ vals, const float* __restrict__ weight,
                                    float* __restrict__ out, int nnz) {
    long long tid = (long long)blockIdx.x * blockDim.x + threadIdx.x;
    if (tid >= (long long)nnz * 32) return;
    int e = (int)(tid >> 5), lane = (int)(tid & 31);
    int r = rows[e], c = cols[e];
    float v = vals[e];
    const float4 w = *reinterpret_cast<const float4*>(weight + (long long)c * CH + lane * 4);
    float* dst = out + (long long)r * CH + lane * 4;
    unsafeAtomicAdd(dst + 0, v * w.x);
    unsafeAtomicAdd(dst + 1, v * w.y);
    unsafeAtomicAdd(dst + 2, v * w.z);
    unsafeAtomicAdd(dst + 3, v * w.w);
}

__global__ void prop_scatter_kernel(const int* __restrict__ rows, const int* __restrict__ cols,
                                    const float* __restrict__ vals, const float* __restrict__ src,
                                    float* __restrict__ dst, int ne) {
    long long tid = (long long)blockIdx.x * blockDim.x + threadIdx.x;
    if (tid >= (long long)ne * 32) return;
    int e = (int)(tid >> 5), lane = (int)(tid & 31);
    int r = rows[e], c = cols[e];
    float v = vals[e];
    const float4 s = *reinterpret_cast<const float4*>(src + (long long)c * CH + lane * 4);
    float* d = dst + (long long)r * CH + lane * 4;
    unsafeAtomicAdd(d + 0, v * s.x);
    unsafeAtomicAdd(d + 1, v * s.y);
    unsafeAtomicAdd(d + 2, v * s.z);
    unsafeAtomicAdd(d + 3, v * s.w);
}

// ---------------- launch ----------------

static inline size_t align16(size_t x) { return (x + 15) & ~(size_t)15; }

extern "C" void kernel_launch(void* const* d_in, const int* in_sizes, int n_in,
                              void* d_out, int out_size, void* d_ws, size_t ws_size,
                              hipStream_t stream) {
    const int*   feat_rows = (const int*)d_in[0];
    const int*   feat_cols = (const int*)d_in[1];
    const float* feat_vals = (const float*)d_in[2];
    const int*   adj_rows  = (const int*)d_in[3];
    const int*   adj_cols  = (const int*)d_in[4];
    const float* adj_vals  = (const float*)d_in[5];
    const float* weight    = (const float*)d_in[6];
    const float* bias      = (const float*)d_in[7];

    const int nnz = in_sizes[0];
    const int ne  = in_sizes[3];
    const int n   = out_size / CH;   // n_nodes

    float* out = (float*)d_out;
    char*  ws  = (char*)d_ws;

    const size_t NB = (size_t)n * CH * sizeof(float);
    const long long total_elems = (long long)n * CH;
    const int BLK = 256;
    const int ew_blocks = (int)((total_elems / 4 + BLK - 1) / BLK);
    const int maxe = nnz > ne ? nnz : ne;
    const int nb_scan = (n + SCAN_BLK - 1) / SCAN_BLK;

    // ws layout (fast path)
    size_t off = 0;
    float* ping    = (float*)(ws + off); off += align16(NB);
    int*   row_ptr = (int*)(ws + off);   off += align16(((size_t)n + 1) * 4);
    int*   cursor  = (int*)(ws + off);   off += align16((size_t)n * 4);
    int*   bsum    = (int*)(ws + off);   off += align16((size_t)nb_scan * 4);
    int2*  cv      = (int2*)(ws + off);  off += align16((size_t)maxe * 8);
    const bool fast = (ws_size >= off) && (nb_scan <= SCAN_BLK);

    if (fast) {
        const int eb_feat = (nnz + BLK - 1) / BLK;
        const int eb_adj  = (ne + BLK - 1) / BLK;
        const int row_blocks = (int)(((long long)n * 64 + BLK - 1) / BLK);
        const int n_blocks = (n + BLK - 1) / BLK;

        // --- feat CSR ---
        hipMemsetAsync(cursor, 0, (size_t)n * 4, stream);
        hist_kernel<<<eb_feat, BLK, 0, stream>>>(feat_rows, cursor, nnz);
        scan_local_kernel<<<nb_scan, SCAN_BLK, 0, stream>>>(cursor, row_ptr, bsum, n);
        scan_bsum_kernel<<<1, SCAN_BLK, 0, stream>>>(bsum, nb_scan, row_ptr + n);
        add_off_kernel<<<n_blocks, BLK, 0, stream>>>(row_ptr, cursor, bsum, n);
        scatter_kernel<<<eb_feat, BLK, 0, stream>>>(feat_rows, feat_cols, feat_vals,
                                                    cursor, cv, nnz);
        // --- base = relu(SpMM(feat, W) + bias) -> d_out (fused) ---
        spmm_csr_kernel<<<row_blocks, BLK, 0, stream>>>(row_ptr, cv, weight, bias, out, n);

        // --- adj CSR (reuses same region) ---
        hipMemsetAsync(cursor, 0, (size_t)n * 4, stream);
        hist_kernel<<<eb_adj, BLK, 0, stream>>>(adj_rows, cursor, ne);
        scan_local_kernel<<<nb_scan, SCAN_BLK, 0, stream>>>(cursor, row_ptr, bsum, n);
        scan_bsum_kernel<<<1, SCAN_BLK, 0, stream>>>(bsum, nb_scan, row_ptr + n);
        add_off_kernel<<<n_blocks, BLK, 0, stream>>>(row_ptr, cursor, bsum, n);
        scatter_kernel<<<eb_adj, BLK, 0, stream>>>(adj_rows, adj_cols, adj_vals,
                                                   cursor, cv, ne);
        // --- prop x2 ---
        prop_csr_kernel<<<row_blocks, BLK, 0, stream>>>(row_ptr, cv, out, ping, n);
        prop_csr_kernel<<<row_blocks, BLK, 0, stream>>>(row_ptr, cv, ping, out, n);
    } else {
        // round-1 fallback: atomic scatter (needs only the ping buffer)
        const int spmm_blocks = (int)(((long long)nnz * 32 + BLK - 1) / BLK);
        const int prop_blocks = (int)(((long long)ne * 32 + BLK - 1) / BLK);
        hipMemsetAsync(d_out, 0, NB, stream);
        spmm_scatter_kernel<<<spmm_blocks, BLK, 0, stream>>>(feat_rows, feat_cols, feat_vals,
                                                             weight, out, nnz);
        bias_relu_kernel<<<ew_blocks, BLK, 0, stream>>>(out, bias, total_elems);
        hipMemsetAsync(ping, 0, NB, stream);
        prop_scatter_kernel<<<prop_blocks, BLK, 0, stream>>>(adj_rows, adj_cols, adj_vals,
                                                             out, ping, ne);
        hipMemsetAsync(d_out, 0, NB, stream);
        prop_scatter_kernel<<<prop_blocks, BLK, 0, stream>>>(adj_rows, adj_cols, adj_vals,
                                                             ping, out, ne);
    }
}

// Round 4
// 670.625 us; speedup vs baseline: 11.9821x; 1.0243x over previous
//
#include <hip/hip_runtime.h>

// SparseNGCNLayer: base = relu(SpMM(feat, W) + bias); base = A @ base (x2)
// Round 4: binned CSR build to kill the 8x scattered-write amplification
// (round-3 scatter: 12.8MB payload -> 100MB WRITE_SIZE).
//   pass 1 (bin): bucket = row>>7; entries stream to 782 contiguous fronts
//                 (full-line writes); rlocal packed into col bits [24:31).
//   pass 2 (reorder): WG per bucket, per-row cursors in LDS, writes land in
//                 the bucket's <=16KB window (L2-local, full lines).
// Gather kernels: one wave per row, float2/lane, 8x unrolled.

#define CH 128
#define BR 128            // rows per bucket (rlocal fits in 7 bits)
#define SCAN_BLK 1024

// ---------------- CSR build ----------------

__global__ void hist_kernel(const int* __restrict__ rows, int* __restrict__ counts, int n) {
    int i = blockIdx.x * blockDim.x + threadIdx.x;
    if (i < n) atomicAdd(&counts[rows[i]], 1);
}

// phase A: per-block (1024-elem chunk) local exclusive scan + block sum
__global__ void scan_local_kernel(const int* __restrict__ counts, int* __restrict__ row_ptr,
                                  int* __restrict__ bsum, int n) {
    __shared__ int lds[SCAN_BLK];
    int tid = threadIdx.x;
    int i = blockIdx.x * SCAN_BLK + tid;
    int x = (i < n) ? counts[i] : 0;
    lds[tid] = x;
    __syncthreads();
    for (int off = 1; off < SCAN_BLK; off <<= 1) {
        int y = (tid >= off) ? lds[tid - off] : 0;
        __syncthreads();
        lds[tid] += y;
        __syncthreads();
    }
    if (i < n) row_ptr[i] = lds[tid] - x;      // local exclusive
    if (tid == SCAN_BLK - 1) bsum[blockIdx.x] = lds[SCAN_BLK - 1];
}

// phase B: single-WG exclusive scan of block sums (nb <= 1024) + total
__global__ void scan_bsum_kernel(int* __restrict__ bsum, int nb, int* __restrict__ total_out) {
    __shared__ int lds[SCAN_BLK];
    int tid = threadIdx.x;
    int x = (tid < nb) ? bsum[tid] : 0;
    lds[tid] = x;
    __syncthreads();
    for (int off = 1; off < SCAN_BLK; off <<= 1) {
        int y = (tid >= off) ? lds[tid - off] : 0;
        __syncthreads();
        lds[tid] += y;
        __syncthreads();
    }
    if (tid < nb) bsum[tid] = lds[tid] - x;    // exclusive
    if (tid == SCAN_BLK - 1) *total_out = lds[SCAN_BLK - 1];
}

// phase C: add block offsets to row_ptr
__global__ void add_off_kernel(int* __restrict__ row_ptr, const int* __restrict__ bsum, int n) {
    int i = blockIdx.x * blockDim.x + threadIdx.x;
    if (i < n) row_ptr[i] += bsum[i >> 10];
}

// bucket cursors (padded to one per 64B line): bcur[b*16] = row_ptr[b*BR]
__global__ void bcur_init_kernel(const int* __restrict__ row_ptr, int* __restrict__ bcur,
                                 int nbuck) {
    int b = blockIdx.x * blockDim.x + threadIdx.x;
    if (b < nbuck) bcur[b << 4] = row_ptr[b * BR];
}

// pass 1: bin edges by row>>7; pack rlocal into col bits [24:31)
__global__ void bin_kernel(const int* __restrict__ rows, const int* __restrict__ cols,
                           const float* __restrict__ vals, int* __restrict__ bcur,
                           int2* __restrict__ cv_tmp, int nE) {
    int i = blockIdx.x * blockDim.x + threadIdx.x;
    if (i >= nE) return;
    int r = rows[i];
    int b = r >> 7;
    int p = atomicAdd(&bcur[b << 4], 1);
    cv_tmp[p] = make_int2(cols[i] | ((r & (BR - 1)) << 24), __float_as_int(vals[i]));
}

// pass 2: reorder within bucket using LDS per-row cursors
__global__ void reorder_kernel(const int* __restrict__ row_ptr, const int2* __restrict__ cv_tmp,
                               int2* __restrict__ cv, int n) {
    __shared__ int cur[BR];
    int b = blockIdx.x;
    int base = b * BR;
    int tid = threadIdx.x;
    if (tid < BR && base + tid < n) cur[tid] = row_ptr[base + tid];
    __syncthreads();
    int endrow = base + BR; if (endrow > n) endrow = n;
    int s = row_ptr[base];
    int e = row_ptr[endrow];
    for (int i = s + tid; i < e; i += blockDim.x) {
        int2 ent = cv_tmp[i];
        int rl = ((unsigned)ent.x) >> 24;
        int p = atomicAdd(&cur[rl], 1);
        cv[p] = make_int2(ent.x & 0x00FFFFFF, ent.y);
    }
}

// ---------------- gather-reduce row kernels ----------------
// one wave (64 lanes) per output row; each lane owns 2 channels (float2).

__global__ void spmm_csr_kernel(const int* __restrict__ row_ptr, const int2* __restrict__ cv,
                                const float* __restrict__ W, const float* __restrict__ bias,
                                float* __restrict__ out, int n) {
    int gtid = blockIdx.x * blockDim.x + threadIdx.x;
    int wid = gtid >> 6;
    int lane = gtid & 63;
    if (wid >= n) return;
    int s = row_ptr[wid], e = row_ptr[wid + 1];
    const float2* Wp = reinterpret_cast<const float2*>(W);
    float2 acc = reinterpret_cast<const float2*>(bias)[lane];
    int i = s;
    for (; i + 8 <= e; i += 8) {
        int2 c[8]; float2 x[8];
        #pragma unroll
        for (int k = 0; k < 8; k++) c[k] = cv[i + k];
        #pragma unroll
        for (int k = 0; k < 8; k++) x[k] = Wp[c[k].x * 64 + lane];
        #pragma unroll
        for (int k = 0; k < 8; k++) {
            float v = __int_as_float(c[k].y);
            acc.x += v * x[k].x; acc.y += v * x[k].y;
        }
    }
    for (; i < e; i++) {
        int2 c = cv[i];
        float v = __int_as_float(c.y);
        float2 x = Wp[c.x * 64 + lane];
        acc.x += v * x.x; acc.y += v * x.y;
    }
    acc.x = fmaxf(acc.x, 0.0f);
    acc.y = fmaxf(acc.y, 0.0f);
    reinterpret_cast<float2*>(out)[(long long)wid * 64 + lane] = acc;
}

__global__ void prop_csr_kernel(const int* __restrict__ row_ptr, const int2* __restrict__ cv,
                                const float* __restrict__ src, float* __restrict__ dst, int n) {
    int gtid = blockIdx.x * blockDim.x + threadIdx.x;
    int wid = gtid >> 6;
    int lane = gtid & 63;
    if (wid >= n) return;
    int s = row_ptr[wid], e = row_ptr[wid + 1];
    const float2* Sp = reinterpret_cast<const float2*>(src);
    float2 acc = {0.0f, 0.0f};
    int i = s;
    for (; i + 8 <= e; i += 8) {
        int2 c[8]; float2 x[8];
        #pragma unroll
        for (int k = 0; k < 8; k++) c[k] = cv[i + k];
        #pragma unroll
        for (int k = 0; k < 8; k++) x[k] = Sp[(long long)c[k].x * 64 + lane];
        #pragma unroll
        for (int k = 0; k < 8; k++) {
            float v = __int_as_float(c[k].y);
            acc.x += v * x[k].x; acc.y += v * x[k].y;
        }
    }
    for (; i < e; i++) {
        int2 c = cv[i];
        float v = __int_as_float(c.y);
        float2 x = Sp[(long long)c.x * 64 + lane];
        acc.x += v * x.x; acc.y += v * x.y;
    }
    reinterpret_cast<float2*>(dst)[(long long)wid * 64 + lane] = acc;
}

__global__ void bias_relu_kernel(float* __restrict__ buf, const float* __restrict__ bias,
                                 long long total) {
    long long i = ((long long)blockIdx.x * blockDim.x + threadIdx.x) * 4;
    if (i >= total) return;
    float4 v = *reinterpret_cast<float4*>(buf + i);
    int ch = (int)(i & (CH - 1));
    float4 b = *reinterpret_cast<const float4*>(bias + ch);
    v.x = fmaxf(v.x + b.x, 0.0f);
    v.y = fmaxf(v.y + b.y, 0.0f);
    v.z = fmaxf(v.z + b.z, 0.0f);
    v.w = fmaxf(v.w + b.w, 0.0f);
    *reinterpret_cast<float4*>(buf + i) = v;
}

// ---------------- round-1 fallback (atomic scatter) ----------------

__global__ void spmm_scatter_kernel(const int* __restrict__ rows, const int* __restrict__ cols,
                                    const float* __restrict__ vals, const float* __restrict__ weight,
                                    float* __restrict__ out, int nnz) {
    long long tid = (long long)blockIdx.x * blockDim.x + threadIdx.x;
    if (tid >= (long long)nnz * 32) return;
    int e = (int)(tid >> 5), lane = (int)(tid & 31);
    int r = rows[e], c = cols[e];
    float v = vals[e];
    const float4 w = *reinterpret_cast<const float4*>(weight + (long long)c * CH + lane * 4);
    float* dst = out + (long long)r * CH + lane * 4;
    unsafeAtomicAdd(dst + 0, v * w.x);
    unsafeAtomicAdd(dst + 1, v * w.y);
    unsafeAtomicAdd(dst + 2, v * w.z);
    unsafeAtomicAdd(dst + 3, v * w.w);
}

__global__ void prop_scatter_kernel(const int* __restrict__ rows, const int* __restrict__ cols,
                                    const float* __restrict__ vals, const float* __restrict__ src,
                                    float* __restrict__ dst, int ne) {
    long long tid = (long long)blockIdx.x * blockDim.x + threadIdx.x;
    if (tid >= (long long)ne * 32) return;
    int e = (int)(tid >> 5), lane = (int)(tid & 31);
    int r = rows[e], c = cols[e];
    float v = vals[e];
    const float4 s = *reinterpret_cast<const float4*>(src + (long long)c * CH + lane * 4);
    float* d = dst + (long long)r * CH + lane * 4;
    unsafeAtomicAdd(d + 0, v * s.x);
    unsafeAtomicAdd(d + 1, v * s.y);
    unsafeAtomicAdd(d + 2, v * s.z);
    unsafeAtomicAdd(d + 3, v * s.w);
}

// ---------------- launch ----------------

static inline size_t align64(size_t x) { return (x + 63) & ~(size_t)63; }

extern "C" void kernel_launch(void* const* d_in, const int* in_sizes, int n_in,
                              void* d_out, int out_size, void* d_ws, size_t ws_size,
                              hipStream_t stream) {
    const int*   feat_rows = (const int*)d_in[0];
    const int*   feat_cols = (const int*)d_in[1];
    const float* feat_vals = (const float*)d_in[2];
    const int*   adj_rows  = (const int*)d_in[3];
    const int*   adj_cols  = (const int*)d_in[4];
    const float* adj_vals  = (const float*)d_in[5];
    const float* weight    = (const float*)d_in[6];
    const float* bias      = (const float*)d_in[7];

    const int nnz = in_sizes[0];
    const int ne  = in_sizes[3];
    const int n   = out_size / CH;   // n_nodes
    const int in_ch = in_sizes[6] / CH;

    float* out = (float*)d_out;
    char*  ws  = (char*)d_ws;

    const size_t NB = (size_t)n * CH * sizeof(float);
    const long long total_elems = (long long)n * CH;
    const int BLK = 256;
    const int ew_blocks = (int)((total_elems / 4 + BLK - 1) / BLK);
    const int maxe = nnz > ne ? nnz : ne;
    const int nb_scan = (n + SCAN_BLK - 1) / SCAN_BLK;
    const int nbuck = (n + BR - 1) / BR;

    // ws layout (fast path); cv_tmp aliases ping (builds precede prop1)
    size_t off = 0;
    float* ping    = (float*)(ws + off); off += align64(NB);
    int*   row_ptr = (int*)(ws + off);   off += align64(((size_t)n + 1) * 4);
    int*   counts  = (int*)(ws + off);   off += align64((size_t)n * 4);
    int*   bsum    = (int*)(ws + off);   off += align64((size_t)nb_scan * 4);
    int*   bcur    = (int*)(ws + off);   off += align64((size_t)nbuck * 16 * 4);
    int2*  cv      = (int2*)(ws + off);  off += align64((size_t)maxe * 8);
    int2*  cv_tmp  = (int2*)ping;        // 12.8MB inside the 51.2MB ping buffer
    const bool fast = (ws_size >= off) && (nb_scan <= SCAN_BLK) &&
                      (n <= (1 << 24)) && (in_ch <= (1 << 24)) &&
                      ((size_t)maxe * 8 <= NB);

    if (fast) {
        const int eb_feat = (nnz + BLK - 1) / BLK;
        const int eb_adj  = (ne + BLK - 1) / BLK;
        const int row_blocks = (int)(((long long)n * 64 + BLK - 1) / BLK);
        const int n_blocks = (n + BLK - 1) / BLK;
        const int bk_blocks = (nbuck + BLK - 1) / BLK;

        // --- feat CSR ---
        hipMemsetAsync(counts, 0, (size_t)n * 4, stream);
        hist_kernel<<<eb_feat, BLK, 0, stream>>>(feat_rows, counts, nnz);
        scan_local_kernel<<<nb_scan, SCAN_BLK, 0, stream>>>(counts, row_ptr, bsum, n);
        scan_bsum_kernel<<<1, SCAN_BLK, 0, stream>>>(bsum, nb_scan, row_ptr + n);
        add_off_kernel<<<n_blocks, BLK, 0, stream>>>(row_ptr, bsum, n);
        bcur_init_kernel<<<bk_blocks, BLK, 0, stream>>>(row_ptr, bcur, nbuck);
        bin_kernel<<<eb_feat, BLK, 0, stream>>>(feat_rows, feat_cols, feat_vals,
                                                bcur, cv_tmp, nnz);
        reorder_kernel<<<nbuck, BLK, 0, stream>>>(row_ptr, cv_tmp, cv, n);
        // --- base = relu(SpMM(feat, W) + bias) -> d_out (fused) ---
        spmm_csr_kernel<<<row_blocks, BLK, 0, stream>>>(row_ptr, cv, weight, bias, out, n);

        // --- adj CSR (ping still free) ---
        hipMemsetAsync(counts, 0, (size_t)n * 4, stream);
        hist_kernel<<<eb_adj, BLK, 0, stream>>>(adj_rows, counts, ne);
        scan_local_kernel<<<nb_scan, SCAN_BLK, 0, stream>>>(counts, row_ptr, bsum, n);
        scan_bsum_kernel<<<1, SCAN_BLK, 0, stream>>>(bsum, nb_scan, row_ptr + n);
        add_off_kernel<<<n_blocks, BLK, 0, stream>>>(row_ptr, bsum, n);
        bcur_init_kernel<<<bk_blocks, BLK, 0, stream>>>(row_ptr, bcur, nbuck);
        bin_kernel<<<eb_adj, BLK, 0, stream>>>(adj_rows, adj_cols, adj_vals,
                                               bcur, cv_tmp, ne);
        reorder_kernel<<<nbuck, BLK, 0, stream>>>(row_ptr, cv_tmp, cv, n);
        // --- prop x2 (prop1 overwrites ping; cv_tmp no longer needed) ---
        prop_csr_kernel<<<row_blocks, BLK, 0, stream>>>(row_ptr, cv, out, ping, n);
        prop_csr_kernel<<<row_blocks, BLK, 0, stream>>>(row_ptr, cv, ping, out, n);
    } else {
        // round-1 fallback: atomic scatter (needs only the ping buffer)
        const int spmm_blocks = (int)(((long long)nnz * 32 + BLK - 1) / BLK);
        const int prop_blocks = (int)(((long long)ne * 32 + BLK - 1) / BLK);
        hipMemsetAsync(d_out, 0, NB, stream);
        spmm_scatter_kernel<<<spmm_blocks, BLK, 0, stream>>>(feat_rows, feat_cols, feat_vals,
                                                             weight, out, nnz);
        bias_relu_kernel<<<ew_blocks, BLK, 0, stream>>>(out, bias, total_elems);
        hipMemsetAsync(ping, 0, NB, stream);
        prop_scatter_kernel<<<prop_blocks, BLK, 0, stream>>>(adj_rows, adj_cols, adj_vals,
                                                             out, ping, ne);
        hipMemsetAsync(d_out, 0, NB, stream);
        prop_scatter_kernel<<<prop_blocks, BLK, 0, stream>>>(adj_rows, adj_cols, adj_vals,
                                                             ping, out, ne);
    }
}

// Round 5
// 583.569 us; speedup vs baseline: 13.7696x; 1.1492x over previous
//
#include <hip/hip_runtime.h>
#include <hip/hip_fp16.h>

// SparseNGCNLayer: base = relu(SpMM(feat, W) + bias); base = A @ base (x2)
// Round 5: fp16 intermediate node features (f32 accumulate, f16 storage).
// Prop gather row shrinks 512B -> 256B: per-prop fabric demand halves.
// CSR build: hist -> 3-phase scan (bcur init fused) -> bin (bucketed, full-
// line writes) -> reorder (LDS cursors). Gathers: wave/row, 2ch/lane, 8x unroll.

#define CH 128
#define BR 128            // rows per bucket (rlocal fits in 7 bits)
#define SCAN_BLK 1024

// ---------------- CSR build ----------------

__global__ void hist_kernel(const int* __restrict__ rows, int* __restrict__ counts, int n) {
    int i = blockIdx.x * blockDim.x + threadIdx.x;
    if (i < n) atomicAdd(&counts[rows[i]], 1);
}

__global__ void scan_local_kernel(const int* __restrict__ counts, int* __restrict__ row_ptr,
                                  int* __restrict__ bsum, int n) {
    __shared__ int lds[SCAN_BLK];
    int tid = threadIdx.x;
    int i = blockIdx.x * SCAN_BLK + tid;
    int x = (i < n) ? counts[i] : 0;
    lds[tid] = x;
    __syncthreads();
    for (int off = 1; off < SCAN_BLK; off <<= 1) {
        int y = (tid >= off) ? lds[tid - off] : 0;
        __syncthreads();
        lds[tid] += y;
        __syncthreads();
    }
    if (i < n) row_ptr[i] = lds[tid] - x;      // local exclusive
    if (tid == SCAN_BLK - 1) bsum[blockIdx.x] = lds[SCAN_BLK - 1];
}

__global__ void scan_bsum_kernel(int* __restrict__ bsum, int nb, int* __restrict__ total_out) {
    __shared__ int lds[SCAN_BLK];
    int tid = threadIdx.x;
    int x = (tid < nb) ? bsum[tid] : 0;
    lds[tid] = x;
    __syncthreads();
    for (int off = 1; off < SCAN_BLK; off <<= 1) {
        int y = (tid >= off) ? lds[tid - off] : 0;
        __syncthreads();
        lds[tid] += y;
        __syncthreads();
    }
    if (tid < nb) bsum[tid] = lds[tid] - x;    // exclusive
    if (tid == SCAN_BLK - 1) *total_out = lds[SCAN_BLK - 1];
}

// add block offsets to row_ptr; also init bucket cursors (fused)
__global__ void add_off_kernel(int* __restrict__ row_ptr, const int* __restrict__ bsum,
                               int* __restrict__ bcur, int n) {
    int i = blockIdx.x * blockDim.x + threadIdx.x;
    if (i >= n) return;
    int v = row_ptr[i] + bsum[i >> 10];
    row_ptr[i] = v;
    if ((i & (BR - 1)) == 0) bcur[(i >> 7) << 4] = v;
}

// pass 1: bin edges by row>>7; pack rlocal into col bits [24:31)
__global__ void bin_kernel(const int* __restrict__ rows, const int* __restrict__ cols,
                           const float* __restrict__ vals, int* __restrict__ bcur,
                           int2* __restrict__ cv_tmp, int nE) {
    int i = blockIdx.x * blockDim.x + threadIdx.x;
    if (i >= nE) return;
    int r = rows[i];
    int b = r >> 7;
    int p = atomicAdd(&bcur[b << 4], 1);
    cv_tmp[p] = make_int2(cols[i] | ((r & (BR - 1)) << 24), __float_as_int(vals[i]));
}

// pass 2: reorder within bucket using LDS per-row cursors
__global__ void reorder_kernel(const int* __restrict__ row_ptr, const int2* __restrict__ cv_tmp,
                               int2* __restrict__ cv, int n) {
    __shared__ int cur[BR];
    int b = blockIdx.x;
    int base = b * BR;
    int tid = threadIdx.x;
    if (tid < BR && base + tid < n) cur[tid] = row_ptr[base + tid];
    __syncthreads();
    int endrow = base + BR; if (endrow > n) endrow = n;
    int s = row_ptr[base];
    int e = row_ptr[endrow];
    for (int i = s + tid; i < e; i += blockDim.x) {
        int2 ent = cv_tmp[i];
        int rl = ((unsigned)ent.x) >> 24;
        int p = atomicAdd(&cur[rl], 1);
        cv[p] = make_int2(ent.x & 0x00FFFFFF, ent.y);
    }
}

// ---------------- gather-reduce row kernels ----------------
// one wave (64 lanes) per output row; each lane owns 2 channels.

// SpMM: gather f32 W rows (L2-resident), write f16 base
__global__ void spmm_csr_f2h_kernel(const int* __restrict__ row_ptr, const int2* __restrict__ cv,
                                    const float* __restrict__ W, const float* __restrict__ bias,
                                    __half2* __restrict__ outh, int n) {
    int gtid = blockIdx.x * blockDim.x + threadIdx.x;
    int wid = gtid >> 6;
    int lane = gtid & 63;
    if (wid >= n) return;
    int s = row_ptr[wid], e = row_ptr[wid + 1];
    const float2* Wp = reinterpret_cast<const float2*>(W);
    float2 acc = reinterpret_cast<const float2*>(bias)[lane];
    int i = s;
    for (; i + 8 <= e; i += 8) {
        int2 c[8]; float2 x[8];
        #pragma unroll
        for (int k = 0; k < 8; k++) c[k] = cv[i + k];
        #pragma unroll
        for (int k = 0; k < 8; k++) x[k] = Wp[c[k].x * 64 + lane];
        #pragma unroll
        for (int k = 0; k < 8; k++) {
            float v = __int_as_float(c[k].y);
            acc.x += v * x[k].x; acc.y += v * x[k].y;
        }
    }
    for (; i < e; i++) {
        int2 c = cv[i];
        float v = __int_as_float(c.y);
        float2 x = Wp[c.x * 64 + lane];
        acc.x += v * x.x; acc.y += v * x.y;
    }
    acc.x = fmaxf(acc.x, 0.0f);
    acc.y = fmaxf(acc.y, 0.0f);
    outh[(long long)wid * 64 + lane] = __float22half2_rn(acc);
}

// prop: gather f16 rows, f32 accumulate, write f16
__global__ void prop_csr_h2h_kernel(const int* __restrict__ row_ptr, const int2* __restrict__ cv,
                                    const __half2* __restrict__ src, __half2* __restrict__ dst,
                                    int n) {
    int gtid = blockIdx.x * blockDim.x + threadIdx.x;
    int wid = gtid >> 6;
    int lane = gtid & 63;
    if (wid >= n) return;
    int s = row_ptr[wid], e = row_ptr[wid + 1];
    float2 acc = {0.0f, 0.0f};
    int i = s;
    for (; i + 8 <= e; i += 8) {
        int2 c[8]; __half2 x[8];
        #pragma unroll
        for (int k = 0; k < 8; k++) c[k] = cv[i + k];
        #pragma unroll
        for (int k = 0; k < 8; k++) x[k] = src[(long long)c[k].x * 64 + lane];
        #pragma unroll
        for (int k = 0; k < 8; k++) {
            float v = __int_as_float(c[k].y);
            float2 xf = __half22float2(x[k]);
            acc.x += v * xf.x; acc.y += v * xf.y;
        }
    }
    for (; i < e; i++) {
        int2 c = cv[i];
        float v = __int_as_float(c.y);
        float2 xf = __half22float2(src[(long long)c.x * 64 + lane]);
        acc.x += v * xf.x; acc.y += v * xf.y;
    }
    dst[(long long)wid * 64 + lane] = __float22half2_rn(acc);
}

// prop: gather f16 rows, f32 accumulate, write f32 (final)
__global__ void prop_csr_h2f_kernel(const int* __restrict__ row_ptr, const int2* __restrict__ cv,
                                    const __half2* __restrict__ src, float* __restrict__ dst,
                                    int n) {
    int gtid = blockIdx.x * blockDim.x + threadIdx.x;
    int wid = gtid >> 6;
    int lane = gtid & 63;
    if (wid >= n) return;
    int s = row_ptr[wid], e = row_ptr[wid + 1];
    float2 acc = {0.0f, 0.0f};
    int i = s;
    for (; i + 8 <= e; i += 8) {
        int2 c[8]; __half2 x[8];
        #pragma unroll
        for (int k = 0; k < 8; k++) c[k] = cv[i + k];
        #pragma unroll
        for (int k = 0; k < 8; k++) x[k] = src[(long long)c[k].x * 64 + lane];
        #pragma unroll
        for (int k = 0; k < 8; k++) {
            float v = __int_as_float(c[k].y);
            float2 xf = __half22float2(x[k]);
            acc.x += v * xf.x; acc.y += v * xf.y;
        }
    }
    for (; i < e; i++) {
        int2 c = cv[i];
        float v = __int_as_float(c.y);
        float2 xf = __half22float2(src[(long long)c.x * 64 + lane]);
        acc.x += v * xf.x; acc.y += v * xf.y;
    }
    reinterpret_cast<float2*>(dst)[(long long)wid * 64 + lane] = acc;
}

// ---------------- round-1 fallback (atomic scatter, f32) ----------------

__global__ void bias_relu_kernel(float* __restrict__ buf, const float* __restrict__ bias,
                                 long long total) {
    long long i = ((long long)blockIdx.x * blockDim.x + threadIdx.x) * 4;
    if (i >= total) return;
    float4 v = *reinterpret_cast<float4*>(buf + i);
    int ch = (int)(i & (CH - 1));
    float4 b = *reinterpret_cast<const float4*>(bias + ch);
    v.x = fmaxf(v.x + b.x, 0.0f);
    v.y = fmaxf(v.y + b.y, 0.0f);
    v.z = fmaxf(v.z + b.z, 0.0f);
    v.w = fmaxf(v.w + b.w, 0.0f);
    *reinterpret_cast<float4*>(buf + i) = v;
}

__global__ void spmm_scatter_kernel(const int* __restrict__ rows, const int* __restrict__ cols,
                                    const float* __restrict__ vals, const float* __restrict__ weight,
                                    float* __restrict__ out, int nnz) {
    long long tid = (long long)blockIdx.x * blockDim.x + threadIdx.x;
    if (tid >= (long long)nnz * 32) return;
    int e = (int)(tid >> 5), lane = (int)(tid & 31);
    int r = rows[e], c = cols[e];
    float v = vals[e];
    const float4 w = *reinterpret_cast<const float4*>(weight + (long long)c * CH + lane * 4);
    float* dst = out + (long long)r * CH + lane * 4;
    unsafeAtomicAdd(dst + 0, v * w.x);
    unsafeAtomicAdd(dst + 1, v * w.y);
    unsafeAtomicAdd(dst + 2, v * w.z);
    unsafeAtomicAdd(dst + 3, v * w.w);
}

__global__ void prop_scatter_kernel(const int* __restrict__ rows, const int* __restrict__ cols,
                                    const float* __restrict__ vals, const float* __restrict__ src,
                                    float* __restrict__ dst, int ne) {
    long long tid = (long long)blockIdx.x * blockDim.x + threadIdx.x;
    if (tid >= (long long)ne * 32) return;
    int e = (int)(tid >> 5), lane = (int)(tid & 31);
    int r = rows[e], c = cols[e];
    float v = vals[e];
    const float4 s = *reinterpret_cast<const float4*>(src + (long long)c * CH + lane * 4);
    float* d = dst + (long long)r * CH + lane * 4;
    unsafeAtomicAdd(d + 0, v * s.x);
    unsafeAtomicAdd(d + 1, v * s.y);
    unsafeAtomicAdd(d + 2, v * s.z);
    unsafeAtomicAdd(d + 3, v * s.w);
}

// ---------------- launch ----------------

static inline size_t align64(size_t x) { return (x + 63) & ~(size_t)63; }

extern "C" void kernel_launch(void* const* d_in, const int* in_sizes, int n_in,
                              void* d_out, int out_size, void* d_ws, size_t ws_size,
                              hipStream_t stream) {
    const int*   feat_rows = (const int*)d_in[0];
    const int*   feat_cols = (const int*)d_in[1];
    const float* feat_vals = (const float*)d_in[2];
    const int*   adj_rows  = (const int*)d_in[3];
    const int*   adj_cols  = (const int*)d_in[4];
    const float* adj_vals  = (const float*)d_in[5];
    const float* weight    = (const float*)d_in[6];
    const float* bias      = (const float*)d_in[7];

    const int nnz = in_sizes[0];
    const int ne  = in_sizes[3];
    const int n   = out_size / CH;   // n_nodes

    float* out = (float*)d_out;
    char*  ws  = (char*)d_ws;

    const size_t NBF = (size_t)n * CH * sizeof(float);      // 51.2 MB
    const size_t NBH = (size_t)n * CH * sizeof(__half);     // 25.6 MB
    const long long total_elems = (long long)n * CH;
    const int BLK = 256;
    const int ew_blocks = (int)((total_elems / 4 + BLK - 1) / BLK);
    const int maxe = nnz > ne ? nnz : ne;
    const int nb_scan = (n + SCAN_BLK - 1) / SCAN_BLK;
    const int nbuck = (n + BR - 1) / BR;

    // ws layout (fast path); cv_tmp aliases pingh (builds precede prop1 write)
    size_t off = 0;
    __half2* baseh  = (__half2*)(ws + off); off += align64(NBH);
    __half2* pingh  = (__half2*)(ws + off); off += align64(NBH);
    int*   row_ptr = (int*)(ws + off);   off += align64(((size_t)n + 1) * 4);
    int*   counts  = (int*)(ws + off);   off += align64((size_t)n * 4);
    int*   bsum    = (int*)(ws + off);   off += align64((size_t)nb_scan * 4);
    int*   bcur    = (int*)(ws + off);   off += align64((size_t)nbuck * 16 * 4);
    int2*  cv      = (int2*)(ws + off);  off += align64((size_t)maxe * 8);
    int2*  cv_tmp  = (int2*)pingh;       // 12.8MB inside the 25.6MB pingh buffer
    const bool fast = (ws_size >= off) && (nb_scan <= SCAN_BLK) &&
                      (n <= (1 << 24)) &&
                      ((size_t)maxe * 8 <= NBH);

    if (fast) {
        const int eb_feat = (nnz + BLK - 1) / BLK;
        const int eb_adj  = (ne + BLK - 1) / BLK;
        const int row_blocks = (int)(((long long)n * 64 + BLK - 1) / BLK);
        const int n_blocks = (n + BLK - 1) / BLK;

        // --- feat CSR ---
        hipMemsetAsync(counts, 0, (size_t)n * 4, stream);
        hist_kernel<<<eb_feat, BLK, 0, stream>>>(feat_rows, counts, nnz);
        scan_local_kernel<<<nb_scan, SCAN_BLK, 0, stream>>>(counts, row_ptr, bsum, n);
        scan_bsum_kernel<<<1, SCAN_BLK, 0, stream>>>(bsum, nb_scan, row_ptr + n);
        add_off_kernel<<<n_blocks, BLK, 0, stream>>>(row_ptr, bsum, bcur, n);
        bin_kernel<<<eb_feat, BLK, 0, stream>>>(feat_rows, feat_cols, feat_vals,
                                                bcur, cv_tmp, nnz);
        reorder_kernel<<<nbuck, BLK, 0, stream>>>(row_ptr, cv_tmp, cv, n);
        // --- base = relu(SpMM(feat, W) + bias) -> baseh (f16) ---
        spmm_csr_f2h_kernel<<<row_blocks, BLK, 0, stream>>>(row_ptr, cv, weight, bias, baseh, n);

        // --- adj CSR (cv_tmp region free until prop1 writes pingh) ---
        hipMemsetAsync(counts, 0, (size_t)n * 4, stream);
        hist_kernel<<<eb_adj, BLK, 0, stream>>>(adj_rows, counts, ne);
        scan_local_kernel<<<nb_scan, SCAN_BLK, 0, stream>>>(counts, row_ptr, bsum, n);
        scan_bsum_kernel<<<1, SCAN_BLK, 0, stream>>>(bsum, nb_scan, row_ptr + n);
        add_off_kernel<<<n_blocks, BLK, 0, stream>>>(row_ptr, bsum, bcur, n);
        bin_kernel<<<eb_adj, BLK, 0, stream>>>(adj_rows, adj_cols, adj_vals,
                                               bcur, cv_tmp, ne);
        reorder_kernel<<<nbuck, BLK, 0, stream>>>(row_ptr, cv_tmp, cv, n);
        // --- prop x2 ---
        prop_csr_h2h_kernel<<<row_blocks, BLK, 0, stream>>>(row_ptr, cv, baseh, pingh, n);
        prop_csr_h2f_kernel<<<row_blocks, BLK, 0, stream>>>(row_ptr, cv, pingh, out, n);
    } else {
        // round-1 fallback: atomic scatter (f32, needs 51.2MB ping)
        float* ping = (float*)ws;
        const int spmm_blocks = (int)(((long long)nnz * 32 + BLK - 1) / BLK);
        const int prop_blocks = (int)(((long long)ne * 32 + BLK - 1) / BLK);
        hipMemsetAsync(d_out, 0, NBF, stream);
        spmm_scatter_kernel<<<spmm_blocks, BLK, 0, stream>>>(feat_rows, feat_cols, feat_vals,
                                                             weight, out, nnz);
        bias_relu_kernel<<<ew_blocks, BLK, 0, stream>>>(out, bias, total_elems);
        hipMemsetAsync(ping, 0, NBF, stream);
        prop_scatter_kernel<<<prop_blocks, BLK, 0, stream>>>(adj_rows, adj_cols, adj_vals,
                                                             out, ping, ne);
        hipMemsetAsync(d_out, 0, NBF, stream);
        prop_scatter_kernel<<<prop_blocks, BLK, 0, stream>>>(adj_rows, adj_cols, adj_vals,
                                                             ping, out, ne);
    }
}

// Round 6
// 504.763 us; speedup vs baseline: 15.9193x; 1.1561x over previous
//
#include <hip/hip_runtime.h>
#include <hip/hip_fp16.h>

// SparseNGCNLayer: base = relu(SpMM(feat, W) + bias); base = A @ base (x2)
// Round 6: 3-phase WG-multisplit bin pass (was: per-edge atomic fronts with
// 7x cross-XCD partial-line write amplification, 90MB WRITE for 12.8MB payload).
//   phase 1: per-WG LDS histogram over buckets (chunk of edges)
//   phase 2: one global atomicAdd per (WG,bucket) reserves a subrange
//   phase 3: write entries into WG-private subranges (single-XCD lines)
// Rest as round 5: fp16 intermediates, reorder with LDS cursors, wave/row
// gather kernels (2ch/lane, 8x unroll).

#define CH 128
#define BR 128            // rows per bucket (rlocal fits in 7 bits)
#define SCAN_BLK 1024
#define BIN_WGS 128       // multisplit workgroups (contiguous chunks)

// ---------------- CSR build ----------------

__global__ void hist_kernel(const int* __restrict__ rows, int* __restrict__ counts, int n) {
    int i = blockIdx.x * blockDim.x + threadIdx.x;
    if (i < n) atomicAdd(&counts[rows[i]], 1);
}

__global__ void scan_local_kernel(const int* __restrict__ counts, int* __restrict__ row_ptr,
                                  int* __restrict__ bsum, int n) {
    __shared__ int lds[SCAN_BLK];
    int tid = threadIdx.x;
    int i = blockIdx.x * SCAN_BLK + tid;
    int x = (i < n) ? counts[i] : 0;
    lds[tid] = x;
    __syncthreads();
    for (int off = 1; off < SCAN_BLK; off <<= 1) {
        int y = (tid >= off) ? lds[tid - off] : 0;
        __syncthreads();
        lds[tid] += y;
        __syncthreads();
    }
    if (i < n) row_ptr[i] = lds[tid] - x;      // local exclusive
    if (tid == SCAN_BLK - 1) bsum[blockIdx.x] = lds[SCAN_BLK - 1];
}

__global__ void scan_bsum_kernel(int* __restrict__ bsum, int nb, int* __restrict__ total_out) {
    __shared__ int lds[SCAN_BLK];
    int tid = threadIdx.x;
    int x = (tid < nb) ? bsum[tid] : 0;
    lds[tid] = x;
    __syncthreads();
    for (int off = 1; off < SCAN_BLK; off <<= 1) {
        int y = (tid >= off) ? lds[tid - off] : 0;
        __syncthreads();
        lds[tid] += y;
        __syncthreads();
    }
    if (tid < nb) bsum[tid] = lds[tid] - x;    // exclusive
    if (tid == SCAN_BLK - 1) *total_out = lds[SCAN_BLK - 1];
}

// add block offsets to row_ptr; also init bucket cursors (fused)
__global__ void add_off_kernel(int* __restrict__ row_ptr, const int* __restrict__ bsum,
                               int* __restrict__ bcur, int n) {
    int i = blockIdx.x * blockDim.x + threadIdx.x;
    if (i >= n) return;
    int v = row_ptr[i] + bsum[i >> 10];
    row_ptr[i] = v;
    if ((i & (BR - 1)) == 0) bcur[i >> 7] = v;
}

// 3-phase multisplit bin: WG-private subranges per bucket.
// rlocal packed into col bits [24:31).
__global__ void multisplit_bin_kernel(const int* __restrict__ rows, const int* __restrict__ cols,
                                      const float* __restrict__ vals, int* __restrict__ bcur,
                                      int2* __restrict__ cv_tmp, int nE, int nbuck, int chunk) {
    extern __shared__ int lds[];
    int* hcnt  = lds;            // [nbuck] counts, then reused as local cursors
    int* hbase = lds + nbuck;    // [nbuck] reserved global bases
    int tid = threadIdx.x;
    long long start = (long long)blockIdx.x * chunk;
    long long end = start + chunk;
    if (end > nE) end = nE;
    if (start >= end) return;

    for (int b = tid; b < nbuck; b += blockDim.x) hcnt[b] = 0;
    __syncthreads();
    // phase 1: count
    for (long long i = start + tid; i < end; i += blockDim.x)
        atomicAdd(&hcnt[rows[i] >> 7], 1);
    __syncthreads();
    // phase 2: reserve subranges
    for (int b = tid; b < nbuck; b += blockDim.x) {
        int c = hcnt[b];
        hbase[b] = c ? atomicAdd(&bcur[b], c) : 0;
        hcnt[b] = 0;
    }
    __syncthreads();
    // phase 3: write into WG-private subranges
    for (long long i = start + tid; i < end; i += blockDim.x) {
        int r = rows[i];
        int b = r >> 7;
        int p = hbase[b] + atomicAdd(&hcnt[b], 1);
        cv_tmp[p] = make_int2(cols[i] | ((r & (BR - 1)) << 24), __float_as_int(vals[i]));
    }
}

// reorder within bucket using LDS per-row cursors
__global__ void reorder_kernel(const int* __restrict__ row_ptr, const int2* __restrict__ cv_tmp,
                               int2* __restrict__ cv, int n) {
    __shared__ int cur[BR];
    int b = blockIdx.x;
    int base = b * BR;
    int tid = threadIdx.x;
    if (tid < BR && base + tid < n) cur[tid] = row_ptr[base + tid];
    __syncthreads();
    int endrow = base + BR; if (endrow > n) endrow = n;
    int s = row_ptr[base];
    int e = row_ptr[endrow];
    for (int i = s + tid; i < e; i += blockDim.x) {
        int2 ent = cv_tmp[i];
        int rl = ((unsigned)ent.x) >> 24;
        int p = atomicAdd(&cur[rl], 1);
        cv[p] = make_int2(ent.x & 0x00FFFFFF, ent.y);
    }
}

// ---------------- gather-reduce row kernels ----------------
// one wave (64 lanes) per output row; each lane owns 2 channels.

__global__ void spmm_csr_f2h_kernel(const int* __restrict__ row_ptr, const int2* __restrict__ cv,
                                    const float* __restrict__ W, const float* __restrict__ bias,
                                    __half2* __restrict__ outh, int n) {
    int gtid = blockIdx.x * blockDim.x + threadIdx.x;
    int wid = gtid >> 6;
    int lane = gtid & 63;
    if (wid >= n) return;
    int s = row_ptr[wid], e = row_ptr[wid + 1];
    const float2* Wp = reinterpret_cast<const float2*>(W);
    float2 acc = reinterpret_cast<const float2*>(bias)[lane];
    int i = s;
    for (; i + 8 <= e; i += 8) {
        int2 c[8]; float2 x[8];
        #pragma unroll
        for (int k = 0; k < 8; k++) c[k] = cv[i + k];
        #pragma unroll
        for (int k = 0; k < 8; k++) x[k] = Wp[c[k].x * 64 + lane];
        #pragma unroll
        for (int k = 0; k < 8; k++) {
            float v = __int_as_float(c[k].y);
            acc.x += v * x[k].x; acc.y += v * x[k].y;
        }
    }
    for (; i < e; i++) {
        int2 c = cv[i];
        float v = __int_as_float(c.y);
        float2 x = Wp[c.x * 64 + lane];
        acc.x += v * x.x; acc.y += v * x.y;
    }
    acc.x = fmaxf(acc.x, 0.0f);
    acc.y = fmaxf(acc.y, 0.0f);
    outh[(long long)wid * 64 + lane] = __float22half2_rn(acc);
}

__global__ void prop_csr_h2h_kernel(const int* __restrict__ row_ptr, const int2* __restrict__ cv,
                                    const __half2* __restrict__ src, __half2* __restrict__ dst,
                                    int n) {
    int gtid = blockIdx.x * blockDim.x + threadIdx.x;
    int wid = gtid >> 6;
    int lane = gtid & 63;
    if (wid >= n) return;
    int s = row_ptr[wid], e = row_ptr[wid + 1];
    float2 acc = {0.0f, 0.0f};
    int i = s;
    for (; i + 8 <= e; i += 8) {
        int2 c[8]; __half2 x[8];
        #pragma unroll
        for (int k = 0; k < 8; k++) c[k] = cv[i + k];
        #pragma unroll
        for (int k = 0; k < 8; k++) x[k] = src[(long long)c[k].x * 64 + lane];
        #pragma unroll
        for (int k = 0; k < 8; k++) {
            float v = __int_as_float(c[k].y);
            float2 xf = __half22float2(x[k]);
            acc.x += v * xf.x; acc.y += v * xf.y;
        }
    }
    for (; i < e; i++) {
        int2 c = cv[i];
        float v = __int_as_float(c.y);
        float2 xf = __half22float2(src[(long long)c.x * 64 + lane]);
        acc.x += v * xf.x; acc.y += v * xf.y;
    }
    dst[(long long)wid * 64 + lane] = __float22half2_rn(acc);
}

__global__ void prop_csr_h2f_kernel(const int* __restrict__ row_ptr, const int2* __restrict__ cv,
                                    const __half2* __restrict__ src, float* __restrict__ dst,
                                    int n) {
    int gtid = blockIdx.x * blockDim.x + threadIdx.x;
    int wid = gtid >> 6;
    int lane = gtid & 63;
    if (wid >= n) return;
    int s = row_ptr[wid], e = row_ptr[wid + 1];
    float2 acc = {0.0f, 0.0f};
    int i = s;
    for (; i + 8 <= e; i += 8) {
        int2 c[8]; __half2 x[8];
        #pragma unroll
        for (int k = 0; k < 8; k++) c[k] = cv[i + k];
        #pragma unroll
        for (int k = 0; k < 8; k++) x[k] = src[(long long)c[k].x * 64 + lane];
        #pragma unroll
        for (int k = 0; k < 8; k++) {
            float v = __int_as_float(c[k].y);
            float2 xf = __half22float2(x[k]);
            acc.x += v * xf.x; acc.y += v * xf.y;
        }
    }
    for (; i < e; i++) {
        int2 c = cv[i];
        float v = __int_as_float(c.y);
        float2 xf = __half22float2(src[(long long)c.x * 64 + lane]);
        acc.x += v * xf.x; acc.y += v * xf.y;
    }
    reinterpret_cast<float2*>(dst)[(long long)wid * 64 + lane] = acc;
}

// ---------------- round-1 fallback (atomic scatter, f32) ----------------

__global__ void bias_relu_kernel(float* __restrict__ buf, const float* __restrict__ bias,
                                 long long total) {
    long long i = ((long long)blockIdx.x * blockDim.x + threadIdx.x) * 4;
    if (i >= total) return;
    float4 v = *reinterpret_cast<float4*>(buf + i);
    int ch = (int)(i & (CH - 1));
    float4 b = *reinterpret_cast<const float4*>(bias + ch);
    v.x = fmaxf(v.x + b.x, 0.0f);
    v.y = fmaxf(v.y + b.y, 0.0f);
    v.z = fmaxf(v.z + b.z, 0.0f);
    v.w = fmaxf(v.w + b.w, 0.0f);
    *reinterpret_cast<float4*>(buf + i) = v;
}

__global__ void spmm_scatter_kernel(const int* __restrict__ rows, const int* __restrict__ cols,
                                    const float* __restrict__ vals, const float* __restrict__ weight,
                                    float* __restrict__ out, int nnz) {
    long long tid = (long long)blockIdx.x * blockDim.x + threadIdx.x;
    if (tid >= (long long)nnz * 32) return;
    int e = (int)(tid >> 5), lane = (int)(tid & 31);
    int r = rows[e], c = cols[e];
    float v = vals[e];
    const float4 w = *reinterpret_cast<const float4*>(weight + (long long)c * CH + lane * 4);
    float* dst = out + (long long)r * CH + lane * 4;
    unsafeAtomicAdd(dst + 0, v * w.x);
    unsafeAtomicAdd(dst + 1, v * w.y);
    unsafeAtomicAdd(dst + 2, v * w.z);
    unsafeAtomicAdd(dst + 3, v * w.w);
}

__global__ void prop_scatter_kernel(const int* __restrict__ rows, const int* __restrict__ cols,
                                    const float* __restrict__ vals, const float* __restrict__ src,
                                    float* __restrict__ dst, int ne) {
    long long tid = (long long)blockIdx.x * blockDim.x + threadIdx.x;
    if (tid >= (long long)ne * 32) return;
    int e = (int)(tid >> 5), lane = (int)(tid & 31);
    int r = rows[e], c = cols[e];
    float v = vals[e];
    const float4 s = *reinterpret_cast<const float4*>(src + (long long)c * CH + lane * 4);
    float* d = dst + (long long)r * CH + lane * 4;
    unsafeAtomicAdd(d + 0, v * s.x);
    unsafeAtomicAdd(d + 1, v * s.y);
    unsafeAtomicAdd(d + 2, v * s.z);
    unsafeAtomicAdd(d + 3, v * s.w);
}

// ---------------- launch ----------------

static inline size_t align64(size_t x) { return (x + 63) & ~(size_t)63; }

extern "C" void kernel_launch(void* const* d_in, const int* in_sizes, int n_in,
                              void* d_out, int out_size, void* d_ws, size_t ws_size,
                              hipStream_t stream) {
    const int*   feat_rows = (const int*)d_in[0];
    const int*   feat_cols = (const int*)d_in[1];
    const float* feat_vals = (const float*)d_in[2];
    const int*   adj_rows  = (const int*)d_in[3];
    const int*   adj_cols  = (const int*)d_in[4];
    const float* adj_vals  = (const float*)d_in[5];
    const float* weight    = (const float*)d_in[6];
    const float* bias      = (const float*)d_in[7];

    const int nnz = in_sizes[0];
    const int ne  = in_sizes[3];
    const int n   = out_size / CH;   // n_nodes

    float* out = (float*)d_out;
    char*  ws  = (char*)d_ws;

    const size_t NBF = (size_t)n * CH * sizeof(float);
    const size_t NBH = (size_t)n * CH * sizeof(__half);
    const long long total_elems = (long long)n * CH;
    const int BLK = 256;
    const int ew_blocks = (int)((total_elems / 4 + BLK - 1) / BLK);
    const int maxe = nnz > ne ? nnz : ne;
    const int nb_scan = (n + SCAN_BLK - 1) / SCAN_BLK;
    const int nbuck = (n + BR - 1) / BR;
    const size_t bin_lds = (size_t)nbuck * 2 * sizeof(int);

    // ws layout (fast path); cv_tmp aliases pingh (builds precede prop1 write)
    size_t off = 0;
    __half2* baseh  = (__half2*)(ws + off); off += align64(NBH);
    __half2* pingh  = (__half2*)(ws + off); off += align64(NBH);
    int*   row_ptr = (int*)(ws + off);   off += align64(((size_t)n + 1) * 4);
    int*   counts  = (int*)(ws + off);   off += align64((size_t)n * 4);
    int*   bsum    = (int*)(ws + off);   off += align64((size_t)nb_scan * 4);
    int*   bcur    = (int*)(ws + off);   off += align64((size_t)nbuck * 4);
    int2*  cv      = (int2*)(ws + off);  off += align64((size_t)maxe * 8);
    int2*  cv_tmp  = (int2*)pingh;       // 12.8MB inside the 25.6MB pingh buffer
    const bool fast = (ws_size >= off) && (nb_scan <= SCAN_BLK) &&
                      (n <= (1 << 24)) && (bin_lds <= 64 * 1024) &&
                      ((size_t)maxe * 8 <= NBH);

    if (fast) {
        const int row_blocks = (int)(((long long)n * 64 + BLK - 1) / BLK);
        const int n_blocks = (n + BLK - 1) / BLK;
        const int eb_feat = (nnz + BLK - 1) / BLK;
        const int eb_adj  = (ne + BLK - 1) / BLK;
        const int chunk_feat = (nnz + BIN_WGS - 1) / BIN_WGS;
        const int chunk_adj  = (ne + BIN_WGS - 1) / BIN_WGS;

        // --- feat CSR ---
        hipMemsetAsync(counts, 0, (size_t)n * 4, stream);
        hist_kernel<<<eb_feat, BLK, 0, stream>>>(feat_rows, counts, nnz);
        scan_local_kernel<<<nb_scan, SCAN_BLK, 0, stream>>>(counts, row_ptr, bsum, n);
        scan_bsum_kernel<<<1, SCAN_BLK, 0, stream>>>(bsum, nb_scan, row_ptr + n);
        add_off_kernel<<<n_blocks, BLK, 0, stream>>>(row_ptr, bsum, bcur, n);
        multisplit_bin_kernel<<<BIN_WGS, BLK, bin_lds, stream>>>(
            feat_rows, feat_cols, feat_vals, bcur, cv_tmp, nnz, nbuck, chunk_feat);
        reorder_kernel<<<nbuck, BLK, 0, stream>>>(row_ptr, cv_tmp, cv, n);
        // --- base = relu(SpMM(feat, W) + bias) -> baseh (f16) ---
        spmm_csr_f2h_kernel<<<row_blocks, BLK, 0, stream>>>(row_ptr, cv, weight, bias, baseh, n);

        // --- adj CSR (cv_tmp region free until prop1 writes pingh) ---
        hipMemsetAsync(counts, 0, (size_t)n * 4, stream);
        hist_kernel<<<eb_adj, BLK, 0, stream>>>(adj_rows, counts, ne);
        scan_local_kernel<<<nb_scan, SCAN_BLK, 0, stream>>>(counts, row_ptr, bsum, n);
        scan_bsum_kernel<<<1, SCAN_BLK, 0, stream>>>(bsum, nb_scan, row_ptr + n);
        add_off_kernel<<<n_blocks, BLK, 0, stream>>>(row_ptr, bsum, bcur, n);
        multisplit_bin_kernel<<<BIN_WGS, BLK, bin_lds, stream>>>(
            adj_rows, adj_cols, adj_vals, bcur, cv_tmp, ne, nbuck, chunk_adj);
        reorder_kernel<<<nbuck, BLK, 0, stream>>>(row_ptr, cv_tmp, cv, n);
        // --- prop x2 ---
        prop_csr_h2h_kernel<<<row_blocks, BLK, 0, stream>>>(row_ptr, cv, baseh, pingh, n);
        prop_csr_h2f_kernel<<<row_blocks, BLK, 0, stream>>>(row_ptr, cv, pingh, out, n);
    } else {
        // round-1 fallback: atomic scatter (f32)
        float* ping = (float*)ws;
        const int spmm_blocks = (int)(((long long)nnz * 32 + BLK - 1) / BLK);
        const int prop_blocks = (int)(((long long)ne * 32 + BLK - 1) / BLK);
        hipMemsetAsync(d_out, 0, NBF, stream);
        spmm_scatter_kernel<<<spmm_blocks, BLK, 0, stream>>>(feat_rows, feat_cols, feat_vals,
                                                             weight, out, nnz);
        bias_relu_kernel<<<ew_blocks, BLK, 0, stream>>>(out, bias, total_elems);
        hipMemsetAsync(ping, 0, NBF, stream);
        prop_scatter_kernel<<<prop_blocks, BLK, 0, stream>>>(adj_rows, adj_cols, adj_vals,
                                                             out, ping, ne);
        hipMemsetAsync(d_out, 0, NBF, stream);
        prop_scatter_kernel<<<prop_blocks, BLK, 0, stream>>>(adj_rows, adj_cols, adj_vals,
                                                             ping, out, ne);
    }
}

// Round 7
// 454.445 us; speedup vs baseline: 17.6820x; 1.1107x over previous
//
#include <hip/hip_runtime.h>
#include <hip/hip_fp16.h>

// SparseNGCNLayer: base = relu(SpMM(feat, W) + bias); base = A @ base (x2)
// Round 7: lane-edge-broadcast gather kernels. One coalesced per-lane load
// grabs 64 CSR entries; __shfl broadcasts each edge (DS pipe), so all W/src
// gathers in a chunk are independent -> latency-bound 88us spmm becomes
// throughput-bound. Zero-filled lanes self-mask (col=0, v=0.0f).
// CSR build (hist/scan/multisplit/reorder) and fp16 intermediates unchanged.

#define CH 128
#define BR 128            // rows per bucket (rlocal fits in 7 bits)
#define SCAN_BLK 1024
#define BIN_WGS 128       // multisplit workgroups (contiguous chunks)

// ---------------- CSR build ----------------

__global__ void hist_kernel(const int* __restrict__ rows, int* __restrict__ counts, int n) {
    int i = blockIdx.x * blockDim.x + threadIdx.x;
    if (i < n) atomicAdd(&counts[rows[i]], 1);
}

__global__ void scan_local_kernel(const int* __restrict__ counts, int* __restrict__ row_ptr,
                                  int* __restrict__ bsum, int n) {
    __shared__ int lds[SCAN_BLK];
    int tid = threadIdx.x;
    int i = blockIdx.x * SCAN_BLK + tid;
    int x = (i < n) ? counts[i] : 0;
    lds[tid] = x;
    __syncthreads();
    for (int off = 1; off < SCAN_BLK; off <<= 1) {
        int y = (tid >= off) ? lds[tid - off] : 0;
        __syncthreads();
        lds[tid] += y;
        __syncthreads();
    }
    if (i < n) row_ptr[i] = lds[tid] - x;      // local exclusive
    if (tid == SCAN_BLK - 1) bsum[blockIdx.x] = lds[SCAN_BLK - 1];
}

__global__ void scan_bsum_kernel(int* __restrict__ bsum, int nb, int* __restrict__ total_out) {
    __shared__ int lds[SCAN_BLK];
    int tid = threadIdx.x;
    int x = (tid < nb) ? bsum[tid] : 0;
    lds[tid] = x;
    __syncthreads();
    for (int off = 1; off < SCAN_BLK; off <<= 1) {
        int y = (tid >= off) ? lds[tid - off] : 0;
        __syncthreads();
        lds[tid] += y;
        __syncthreads();
    }
    if (tid < nb) bsum[tid] = lds[tid] - x;    // exclusive
    if (tid == SCAN_BLK - 1) *total_out = lds[SCAN_BLK - 1];
}

// add block offsets to row_ptr; also init bucket cursors (fused)
__global__ void add_off_kernel(int* __restrict__ row_ptr, const int* __restrict__ bsum,
                               int* __restrict__ bcur, int n) {
    int i = blockIdx.x * blockDim.x + threadIdx.x;
    if (i >= n) return;
    int v = row_ptr[i] + bsum[i >> 10];
    row_ptr[i] = v;
    if ((i & (BR - 1)) == 0) bcur[i >> 7] = v;
}

// 3-phase multisplit bin: WG-private subranges per bucket.
// rlocal packed into col bits [24:31).
__global__ void multisplit_bin_kernel(const int* __restrict__ rows, const int* __restrict__ cols,
                                      const float* __restrict__ vals, int* __restrict__ bcur,
                                      int2* __restrict__ cv_tmp, int nE, int nbuck, int chunk) {
    extern __shared__ int lds[];
    int* hcnt  = lds;            // [nbuck] counts, then reused as local cursors
    int* hbase = lds + nbuck;    // [nbuck] reserved global bases
    int tid = threadIdx.x;
    long long start = (long long)blockIdx.x * chunk;
    long long end = start + chunk;
    if (end > nE) end = nE;
    if (start >= end) return;

    for (int b = tid; b < nbuck; b += blockDim.x) hcnt[b] = 0;
    __syncthreads();
    // phase 1: count
    for (long long i = start + tid; i < end; i += blockDim.x)
        atomicAdd(&hcnt[rows[i] >> 7], 1);
    __syncthreads();
    // phase 2: reserve subranges
    for (int b = tid; b < nbuck; b += blockDim.x) {
        int c = hcnt[b];
        hbase[b] = c ? atomicAdd(&bcur[b], c) : 0;
        hcnt[b] = 0;
    }
    __syncthreads();
    // phase 3: write into WG-private subranges
    for (long long i = start + tid; i < end; i += blockDim.x) {
        int r = rows[i];
        int b = r >> 7;
        int p = hbase[b] + atomicAdd(&hcnt[b], 1);
        cv_tmp[p] = make_int2(cols[i] | ((r & (BR - 1)) << 24), __float_as_int(vals[i]));
    }
}

// reorder within bucket using LDS per-row cursors
__global__ void reorder_kernel(const int* __restrict__ row_ptr, const int2* __restrict__ cv_tmp,
                               int2* __restrict__ cv, int n) {
    __shared__ int cur[BR];
    int b = blockIdx.x;
    int base = b * BR;
    int tid = threadIdx.x;
    if (tid < BR && base + tid < n) cur[tid] = row_ptr[base + tid];
    __syncthreads();
    int endrow = base + BR; if (endrow > n) endrow = n;
    int s = row_ptr[base];
    int e = row_ptr[endrow];
    for (int i = s + tid; i < e; i += blockDim.x) {
        int2 ent = cv_tmp[i];
        int rl = ((unsigned)ent.x) >> 24;
        int p = atomicAdd(&cur[rl], 1);
        cv[p] = make_int2(ent.x & 0x00FFFFFF, ent.y);
    }
}

// ---------------- gather-reduce row kernels ----------------
// one wave (64 lanes) per output row; each lane owns 2 channels.
// lane-edge broadcast: one per-lane coalesced load of up to 64 CSR entries,
// then __shfl broadcasts each edge; zero-filled lanes self-mask (v=0).

__global__ void spmm_csr_f2h_kernel(const int* __restrict__ row_ptr,
                                    const long long* __restrict__ cv,
                                    const float* __restrict__ W, const float* __restrict__ bias,
                                    __half2* __restrict__ outh, int n) {
    int gtid = blockIdx.x * blockDim.x + threadIdx.x;
    int wid = gtid >> 6;
    int lane = gtid & 63;
    if (wid >= n) return;
    int s = row_ptr[wid], e = row_ptr[wid + 1];
    const float2* Wp = reinterpret_cast<const float2*>(W);
    float2 acc = reinterpret_cast<const float2*>(bias)[lane];
    for (int base = s; base < e; base += 64) {
        long long cvl = (base + lane < e) ? cv[base + lane] : 0;
        int m = e - base; if (m > 64) m = 64;
        for (int k0 = 0; k0 < m; k0 += 8) {
            #pragma unroll
            for (int j = 0; j < 8; j++) {
                long long ck = __shfl(cvl, k0 + j);
                int col = (int)ck;
                float v = __int_as_float((int)(ck >> 32));
                float2 w = Wp[col * 64 + lane];
                acc.x += v * w.x; acc.y += v * w.y;
            }
        }
    }
    acc.x = fmaxf(acc.x, 0.0f);
    acc.y = fmaxf(acc.y, 0.0f);
    outh[(long long)wid * 64 + lane] = __float22half2_rn(acc);
}

__global__ void prop_csr_h2h_kernel(const int* __restrict__ row_ptr,
                                    const long long* __restrict__ cv,
                                    const __half2* __restrict__ src, __half2* __restrict__ dst,
                                    int n) {
    int gtid = blockIdx.x * blockDim.x + threadIdx.x;
    int wid = gtid >> 6;
    int lane = gtid & 63;
    if (wid >= n) return;
    int s = row_ptr[wid], e = row_ptr[wid + 1];
    float2 acc = {0.0f, 0.0f};
    for (int base = s; base < e; base += 64) {
        long long cvl = (base + lane < e) ? cv[base + lane] : 0;
        int m = e - base; if (m > 64) m = 64;
        for (int k0 = 0; k0 < m; k0 += 8) {
            #pragma unroll
            for (int j = 0; j < 8; j++) {
                long long ck = __shfl(cvl, k0 + j);
                int col = (int)ck;
                float v = __int_as_float((int)(ck >> 32));
                float2 xf = __half22float2(src[(long long)col * 64 + lane]);
                acc.x += v * xf.x; acc.y += v * xf.y;
            }
        }
    }
    dst[(long long)wid * 64 + lane] = __float22half2_rn(acc);
}

__global__ void prop_csr_h2f_kernel(const int* __restrict__ row_ptr,
                                    const long long* __restrict__ cv,
                                    const __half2* __restrict__ src, float* __restrict__ dst,
                                    int n) {
    int gtid = blockIdx.x * blockDim.x + threadIdx.x;
    int wid = gtid >> 6;
    int lane = gtid & 63;
    if (wid >= n) return;
    int s = row_ptr[wid], e = row_ptr[wid + 1];
    float2 acc = {0.0f, 0.0f};
    for (int base = s; base < e; base += 64) {
        long long cvl = (base + lane < e) ? cv[base + lane] : 0;
        int m = e - base; if (m > 64) m = 64;
        for (int k0 = 0; k0 < m; k0 += 8) {
            #pragma unroll
            for (int j = 0; j < 8; j++) {
                long long ck = __shfl(cvl, k0 + j);
                int col = (int)ck;
                float v = __int_as_float((int)(ck >> 32));
                float2 xf = __half22float2(src[(long long)col * 64 + lane]);
                acc.x += v * xf.x; acc.y += v * xf.y;
            }
        }
    }
    reinterpret_cast<float2*>(dst)[(long long)wid * 64 + lane] = acc;
}

// ---------------- round-1 fallback (atomic scatter, f32) ----------------

__global__ void bias_relu_kernel(float* __restrict__ buf, const float* __restrict__ bias,
                                 long long total) {
    long long i = ((long long)blockIdx.x * blockDim.x + threadIdx.x) * 4;
    if (i >= total) return;
    float4 v = *reinterpret_cast<float4*>(buf + i);
    int ch = (int)(i & (CH - 1));
    float4 b = *reinterpret_cast<const float4*>(bias + ch);
    v.x = fmaxf(v.x + b.x, 0.0f);
    v.y = fmaxf(v.y + b.y, 0.0f);
    v.z = fmaxf(v.z + b.z, 0.0f);
    v.w = fmaxf(v.w + b.w, 0.0f);
    *reinterpret_cast<float4*>(buf + i) = v;
}

__global__ void spmm_scatter_kernel(const int* __restrict__ rows, const int* __restrict__ cols,
                                    const float* __restrict__ vals, const float* __restrict__ weight,
                                    float* __restrict__ out, int nnz) {
    long long tid = (long long)blockIdx.x * blockDim.x + threadIdx.x;
    if (tid >= (long long)nnz * 32) return;
    int e = (int)(tid >> 5), lane = (int)(tid & 31);
    int r = rows[e], c = cols[e];
    float v = vals[e];
    const float4 w = *reinterpret_cast<const float4*>(weight + (long long)c * CH + lane * 4);
    float* dst = out + (long long)r * CH + lane * 4;
    unsafeAtomicAdd(dst + 0, v * w.x);
    unsafeAtomicAdd(dst + 1, v * w.y);
    unsafeAtomicAdd(dst + 2, v * w.z);
    unsafeAtomicAdd(dst + 3, v * w.w);
}

__global__ void prop_scatter_kernel(const int* __restrict__ rows, const int* __restrict__ cols,
                                    const float* __restrict__ vals, const float* __restrict__ src,
                                    float* __restrict__ dst, int ne) {
    long long tid = (long long)blockIdx.x * blockDim.x + threadIdx.x;
    if (tid >= (long long)ne * 32) return;
    int e = (int)(tid >> 5), lane = (int)(tid & 31);
    int r = rows[e], c = cols[e];
    float v = vals[e];
    const float4 s = *reinterpret_cast<const float4*>(src + (long long)c * CH + lane * 4);
    float* d = dst + (long long)r * CH + lane * 4;
    unsafeAtomicAdd(d + 0, v * s.x);
    unsafeAtomicAdd(d + 1, v * s.y);
    unsafeAtomicAdd(d + 2, v * s.z);
    unsafeAtomicAdd(d + 3, v * s.w);
}

// ---------------- launch ----------------

static inline size_t align64(size_t x) { return (x + 63) & ~(size_t)63; }

extern "C" void kernel_launch(void* const* d_in, const int* in_sizes, int n_in,
                              void* d_out, int out_size, void* d_ws, size_t ws_size,
                              hipStream_t stream) {
    const int*   feat_rows = (const int*)d_in[0];
    const int*   feat_cols = (const int*)d_in[1];
    const float* feat_vals = (const float*)d_in[2];
    const int*   adj_rows  = (const int*)d_in[3];
    const int*   adj_cols  = (const int*)d_in[4];
    const float* adj_vals  = (const float*)d_in[5];
    const float* weight    = (const float*)d_in[6];
    const float* bias      = (const float*)d_in[7];

    const int nnz = in_sizes[0];
    const int ne  = in_sizes[3];
    const int n   = out_size / CH;   // n_nodes

    float* out = (float*)d_out;
    char*  ws  = (char*)d_ws;

    const size_t NBF = (size_t)n * CH * sizeof(float);
    const size_t NBH = (size_t)n * CH * sizeof(__half);
    const long long total_elems = (long long)n * CH;
    const int BLK = 256;
    const int ew_blocks = (int)((total_elems / 4 + BLK - 1) / BLK);
    const int maxe = nnz > ne ? nnz : ne;
    const int nb_scan = (n + SCAN_BLK - 1) / SCAN_BLK;
    const int nbuck = (n + BR - 1) / BR;
    const size_t bin_lds = (size_t)nbuck * 2 * sizeof(int);

    // ws layout (fast path); cv_tmp aliases pingh (builds precede prop1 write)
    size_t off = 0;
    __half2* baseh  = (__half2*)(ws + off); off += align64(NBH);
    __half2* pingh  = (__half2*)(ws + off); off += align64(NBH);
    int*   row_ptr = (int*)(ws + off);   off += align64(((size_t)n + 1) * 4);
    int*   counts  = (int*)(ws + off);   off += align64((size_t)n * 4);
    int*   bsum    = (int*)(ws + off);   off += align64((size_t)nb_scan * 4);
    int*   bcur    = (int*)(ws + off);   off += align64((size_t)nbuck * 4);
    int2*  cv      = (int2*)(ws + off);  off += align64((size_t)maxe * 8);
    int2*  cv_tmp  = (int2*)pingh;       // 12.8MB inside the 25.6MB pingh buffer
    const bool fast = (ws_size >= off) && (nb_scan <= SCAN_BLK) &&
                      (n <= (1 << 24)) && (bin_lds <= 64 * 1024) &&
                      ((size_t)maxe * 8 <= NBH);

    if (fast) {
        const int row_blocks = (int)(((long long)n * 64 + BLK - 1) / BLK);
        const int n_blocks = (n + BLK - 1) / BLK;
        const int eb_feat = (nnz + BLK - 1) / BLK;
        const int eb_adj  = (ne + BLK - 1) / BLK;
        const int chunk_feat = (nnz + BIN_WGS - 1) / BIN_WGS;
        const int chunk_adj  = (ne + BIN_WGS - 1) / BIN_WGS;

        // --- feat CSR ---
        hipMemsetAsync(counts, 0, (size_t)n * 4, stream);
        hist_kernel<<<eb_feat, BLK, 0, stream>>>(feat_rows, counts, nnz);
        scan_local_kernel<<<nb_scan, SCAN_BLK, 0, stream>>>(counts, row_ptr, bsum, n);
        scan_bsum_kernel<<<1, SCAN_BLK, 0, stream>>>(bsum, nb_scan, row_ptr + n);
        add_off_kernel<<<n_blocks, BLK, 0, stream>>>(row_ptr, bsum, bcur, n);
        multisplit_bin_kernel<<<BIN_WGS, BLK, bin_lds, stream>>>(
            feat_rows, feat_cols, feat_vals, bcur, cv_tmp, nnz, nbuck, chunk_feat);
        reorder_kernel<<<nbuck, BLK, 0, stream>>>(row_ptr, cv_tmp, cv, n);
        // --- base = relu(SpMM(feat, W) + bias) -> baseh (f16) ---
        spmm_csr_f2h_kernel<<<row_blocks, BLK, 0, stream>>>(
            row_ptr, (const long long*)cv, weight, bias, baseh, n);

        // --- adj CSR (cv_tmp region free until prop1 writes pingh) ---
        hipMemsetAsync(counts, 0, (size_t)n * 4, stream);
        hist_kernel<<<eb_adj, BLK, 0, stream>>>(adj_rows, counts, ne);
        scan_local_kernel<<<nb_scan, SCAN_BLK, 0, stream>>>(counts, row_ptr, bsum, n);
        scan_bsum_kernel<<<1, SCAN_BLK, 0, stream>>>(bsum, nb_scan, row_ptr + n);
        add_off_kernel<<<n_blocks, BLK, 0, stream>>>(row_ptr, bsum, bcur, n);
        multisplit_bin_kernel<<<BIN_WGS, BLK, bin_lds, stream>>>(
            adj_rows, adj_cols, adj_vals, bcur, cv_tmp, ne, nbuck, chunk_adj);
        reorder_kernel<<<nbuck, BLK, 0, stream>>>(row_ptr, cv_tmp, cv, n);
        // --- prop x2 ---
        prop_csr_h2h_kernel<<<row_blocks, BLK, 0, stream>>>(
            row_ptr, (const long long*)cv, baseh, pingh, n);
        prop_csr_h2f_kernel<<<row_blocks, BLK, 0, stream>>>(
            row_ptr, (const long long*)cv, pingh, out, n);
    } else {
        // round-1 fallback: atomic scatter (f32)
        float* ping = (float*)ws;
        const int spmm_blocks = (int)(((long long)nnz * 32 + BLK - 1) / BLK);
        const int prop_blocks = (int)(((long long)ne * 32 + BLK - 1) / BLK);
        hipMemsetAsync(d_out, 0, NBF, stream);
        spmm_scatter_kernel<<<spmm_blocks, BLK, 0, stream>>>(feat_rows, feat_cols, feat_vals,
                                                             weight, out, nnz);
        bias_relu_kernel<<<ew_blocks, BLK, 0, stream>>>(out, bias, total_elems);
        hipMemsetAsync(ping, 0, NBF, stream);
        prop_scatter_kernel<<<prop_blocks, BLK, 0, stream>>>(adj_rows, adj_cols, adj_vals,
                                                             out, ping, ne);
        hipMemsetAsync(d_out, 0, NBF, stream);
        prop_scatter_kernel<<<prop_blocks, BLK, 0, stream>>>(adj_rows, adj_cols, adj_vals,
                                                             ping, out, ne);
    }
}

// Round 8
// 451.668 us; speedup vs baseline: 17.7907x; 1.0061x over previous
//
#include <hip/hip_runtime.h>
#include <hip/hip_fp16.h>

// SparseNGCNLayer: base = relu(SpMM(feat, W) + bias); base = A @ base (x2)
// Round 8:
//   - spmm: W staged in LDS as fp16 (512x64 half2 = 128KB, 1 WG/CU, 512 thr).
//     Per-edge gather becomes a conflict-free LDS read instead of an L2
//     round-trip (73us kernel was latency-bound at 6% HBM / 28% VALU).
//   - all gather kernels: wave-private LDS scratch broadcast for CSR entries
//     (1 uniform ds_read_b64 per edge) replaces 64-bit __shfl (2 ds_bpermute).
// CSR build (hist/scan/multisplit/reorder) and fp16 intermediates unchanged.

#define CH 128
#define BR 128            // rows per bucket (rlocal fits in 7 bits)
#define SCAN_BLK 1024
#define BIN_WGS 128       // multisplit workgroups (contiguous chunks)
#define SPMM_WGS 256      // one per CU (128KB LDS)

// ---------------- CSR build ----------------

__global__ void hist_kernel(const int* __restrict__ rows, int* __restrict__ counts, int n) {
    int i = blockIdx.x * blockDim.x + threadIdx.x;
    if (i < n) atomicAdd(&counts[rows[i]], 1);
}

__global__ void scan_local_kernel(const int* __restrict__ counts, int* __restrict__ row_ptr,
                                  int* __restrict__ bsum, int n) {
    __shared__ int lds[SCAN_BLK];
    int tid = threadIdx.x;
    int i = blockIdx.x * SCAN_BLK + tid;
    int x = (i < n) ? counts[i] : 0;
    lds[tid] = x;
    __syncthreads();
    for (int off = 1; off < SCAN_BLK; off <<= 1) {
        int y = (tid >= off) ? lds[tid - off] : 0;
        __syncthreads();
        lds[tid] += y;
        __syncthreads();
    }
    if (i < n) row_ptr[i] = lds[tid] - x;      // local exclusive
    if (tid == SCAN_BLK - 1) bsum[blockIdx.x] = lds[SCAN_BLK - 1];
}

__global__ void scan_bsum_kernel(int* __restrict__ bsum, int nb, int* __restrict__ total_out) {
    __shared__ int lds[SCAN_BLK];
    int tid = threadIdx.x;
    int x = (tid < nb) ? bsum[tid] : 0;
    lds[tid] = x;
    __syncthreads();
    for (int off = 1; off < SCAN_BLK; off <<= 1) {
        int y = (tid >= off) ? lds[tid - off] : 0;
        __syncthreads();
        lds[tid] += y;
        __syncthreads();
    }
    if (tid < nb) bsum[tid] = lds[tid] - x;    // exclusive
    if (tid == SCAN_BLK - 1) *total_out = lds[SCAN_BLK - 1];
}

// add block offsets to row_ptr; also init bucket cursors (fused)
__global__ void add_off_kernel(int* __restrict__ row_ptr, const int* __restrict__ bsum,
                               int* __restrict__ bcur, int n) {
    int i = blockIdx.x * blockDim.x + threadIdx.x;
    if (i >= n) return;
    int v = row_ptr[i] + bsum[i >> 10];
    row_ptr[i] = v;
    if ((i & (BR - 1)) == 0) bcur[i >> 7] = v;
}

// 3-phase multisplit bin: WG-private subranges per bucket.
// rlocal packed into col bits [24:31).
__global__ void multisplit_bin_kernel(const int* __restrict__ rows, const int* __restrict__ cols,
                                      const float* __restrict__ vals, int* __restrict__ bcur,
                                      int2* __restrict__ cv_tmp, int nE, int nbuck, int chunk) {
    extern __shared__ int lds[];
    int* hcnt  = lds;            // [nbuck] counts, then reused as local cursors
    int* hbase = lds + nbuck;    // [nbuck] reserved global bases
    int tid = threadIdx.x;
    long long start = (long long)blockIdx.x * chunk;
    long long end = start + chunk;
    if (end > nE) end = nE;
    if (start >= end) return;

    for (int b = tid; b < nbuck; b += blockDim.x) hcnt[b] = 0;
    __syncthreads();
    for (long long i = start + tid; i < end; i += blockDim.x)
        atomicAdd(&hcnt[rows[i] >> 7], 1);
    __syncthreads();
    for (int b = tid; b < nbuck; b += blockDim.x) {
        int c = hcnt[b];
        hbase[b] = c ? atomicAdd(&bcur[b], c) : 0;
        hcnt[b] = 0;
    }
    __syncthreads();
    for (long long i = start + tid; i < end; i += blockDim.x) {
        int r = rows[i];
        int b = r >> 7;
        int p = hbase[b] + atomicAdd(&hcnt[b], 1);
        cv_tmp[p] = make_int2(cols[i] | ((r & (BR - 1)) << 24), __float_as_int(vals[i]));
    }
}

// reorder within bucket using LDS per-row cursors
__global__ void reorder_kernel(const int* __restrict__ row_ptr, const int2* __restrict__ cv_tmp,
                               int2* __restrict__ cv, int n) {
    __shared__ int cur[BR];
    int b = blockIdx.x;
    int base = b * BR;
    int tid = threadIdx.x;
    if (tid < BR && base + tid < n) cur[tid] = row_ptr[base + tid];
    __syncthreads();
    int endrow = base + BR; if (endrow > n) endrow = n;
    int s = row_ptr[base];
    int e = row_ptr[endrow];
    for (int i = s + tid; i < e; i += blockDim.x) {
        int2 ent = cv_tmp[i];
        int rl = ((unsigned)ent.x) >> 24;
        int p = atomicAdd(&cur[rl], 1);
        cv[p] = make_int2(ent.x & 0x00FFFFFF, ent.y);
    }
}

// ---------------- gather-reduce row kernels ----------------

// SpMM with W staged in LDS as fp16. 512 threads (8 waves), one wave per row.
// LDS: 512*64 half2 (128KB) + 8*64 long long scratch (4KB) = 132KB -> 1 WG/CU.
__global__ void __launch_bounds__(512, 1)
spmm_lds_kernel(const int* __restrict__ row_ptr, const long long* __restrict__ cv,
                const float* __restrict__ W, const float* __restrict__ bias,
                __half2* __restrict__ outh, int n, int rows_per_wg) {
    __shared__ __half2 wlds[512 * 64];     // [col][lane] fp16 pairs
    __shared__ long long sc[8 * 64];       // per-wave CSR entry scratch

    // stage W: f32 -> half2, coalesced
    const float2* Wf2 = reinterpret_cast<const float2*>(W);
    for (int i = threadIdx.x; i < 512 * 64; i += blockDim.x)
        wlds[i] = __float22half2_rn(Wf2[i]);
    __syncthreads();

    int wave = threadIdx.x >> 6;
    int lane = threadIdx.x & 63;
    int rstart = blockIdx.x * rows_per_wg;
    int rend = rstart + rows_per_wg; if (rend > n) rend = n;
    float2 b = reinterpret_cast<const float2*>(bias)[lane];
    long long* mysc = sc + wave * 64;

    for (int wid = rstart + wave; wid < rend; wid += 8) {
        int s = row_ptr[wid], e = row_ptr[wid + 1];
        float2 acc = b;
        for (int base = s; base < e; base += 64) {
            int idx = base + lane;
            mysc[lane] = (idx < e) ? cv[idx] : 0;   // wave-private, no barrier
            int m = e - base; if (m > 64) m = 64;
            for (int k0 = 0; k0 < m; k0 += 8) {
                #pragma unroll
                for (int j = 0; j < 8; j++) {
                    long long ck = mysc[k0 + j];     // uniform -> broadcast read
                    int col = (int)ck;
                    float v = __int_as_float((int)(ck >> 32));
                    float2 wf = __half22float2(wlds[col * 64 + lane]);
                    acc.x += v * wf.x; acc.y += v * wf.y;
                }
            }
        }
        acc.x = fmaxf(acc.x, 0.0f);
        acc.y = fmaxf(acc.y, 0.0f);
        outh[(long long)wid * 64 + lane] = __float22half2_rn(acc);
    }
}

// prop: gather f16 rows, f32 accumulate. one wave per row, scratch broadcast.
__global__ void prop_csr_h2h_kernel(const int* __restrict__ row_ptr,
                                    const long long* __restrict__ cv,
                                    const __half2* __restrict__ src, __half2* __restrict__ dst,
                                    int n) {
    __shared__ long long sc[4 * 64];
    int gtid = blockIdx.x * blockDim.x + threadIdx.x;
    int wid = gtid >> 6;
    int lane = gtid & 63;
    if (wid >= n) return;
    long long* mysc = sc + (threadIdx.x >> 6) * 64;
    int s = row_ptr[wid], e = row_ptr[wid + 1];
    float2 acc = {0.0f, 0.0f};
    for (int base = s; base < e; base += 64) {
        int idx = base + lane;
        mysc[lane] = (idx < e) ? cv[idx] : 0;
        int m = e - base; if (m > 64) m = 64;
        for (int k0 = 0; k0 < m; k0 += 8) {
            #pragma unroll
            for (int j = 0; j < 8; j++) {
                long long ck = mysc[k0 + j];
                int col = (int)ck;
                float v = __int_as_float((int)(ck >> 32));
                float2 xf = __half22float2(src[(long long)col * 64 + lane]);
                acc.x += v * xf.x; acc.y += v * xf.y;
            }
        }
    }
    dst[(long long)wid * 64 + lane] = __float22half2_rn(acc);
}

__global__ void prop_csr_h2f_kernel(const int* __restrict__ row_ptr,
                                    const long long* __restrict__ cv,
                                    const __half2* __restrict__ src, float* __restrict__ dst,
                                    int n) {
    __shared__ long long sc[4 * 64];
    int gtid = blockIdx.x * blockDim.x + threadIdx.x;
    int wid = gtid >> 6;
    int lane = gtid & 63;
    if (wid >= n) return;
    long long* mysc = sc + (threadIdx.x >> 6) * 64;
    int s = row_ptr[wid], e = row_ptr[wid + 1];
    float2 acc = {0.0f, 0.0f};
    for (int base = s; base < e; base += 64) {
        int idx = base + lane;
        mysc[lane] = (idx < e) ? cv[idx] : 0;
        int m = e - base; if (m > 64) m = 64;
        for (int k0 = 0; k0 < m; k0 += 8) {
            #pragma unroll
            for (int j = 0; j < 8; j++) {
                long long ck = mysc[k0 + j];
                int col = (int)ck;
                float v = __int_as_float((int)(ck >> 32));
                float2 xf = __half22float2(src[(long long)col * 64 + lane]);
                acc.x += v * xf.x; acc.y += v * xf.y;
            }
        }
    }
    reinterpret_cast<float2*>(dst)[(long long)wid * 64 + lane] = acc;
}

// ---------------- round-1 fallback (atomic scatter, f32) ----------------

__global__ void bias_relu_kernel(float* __restrict__ buf, const float* __restrict__ bias,
                                 long long total) {
    long long i = ((long long)blockIdx.x * blockDim.x + threadIdx.x) * 4;
    if (i >= total) return;
    float4 v = *reinterpret_cast<float4*>(buf + i);
    int ch = (int)(i & (CH - 1));
    float4 b = *reinterpret_cast<const float4*>(bias + ch);
    v.x = fmaxf(v.x + b.x, 0.0f);
    v.y = fmaxf(v.y + b.y, 0.0f);
    v.z = fmaxf(v.z + b.z, 0.0f);
    v.w = fmaxf(v.w + b.w, 0.0f);
    *reinterpret_cast<float4*>(buf + i) = v;
}

__global__ void spmm_scatter_kernel(const int* __restrict__ rows, const int* __restrict__ cols,
                                    const float* __restrict__ vals, const float* __restrict__ weight,
                                    float* __restrict__ out, int nnz) {
    long long tid = (long long)blockIdx.x * blockDim.x + threadIdx.x;
    if (tid >= (long long)nnz * 32) return;
    int e = (int)(tid >> 5), lane = (int)(tid & 31);
    int r = rows[e], c = cols[e];
    float v = vals[e];
    const float4 w = *reinterpret_cast<const float4*>(weight + (long long)c * CH + lane * 4);
    float* dst = out + (long long)r * CH + lane * 4;
    unsafeAtomicAdd(dst + 0, v * w.x);
    unsafeAtomicAdd(dst + 1, v * w.y);
    unsafeAtomicAdd(dst + 2, v * w.z);
    unsafeAtomicAdd(dst + 3, v * w.w);
}

__global__ void prop_scatter_kernel(const int* __restrict__ rows, const int* __restrict__ cols,
                                    const float* __restrict__ vals, const float* __restrict__ src,
                                    float* __restrict__ dst, int ne) {
    long long tid = (long long)blockIdx.x * blockDim.x + threadIdx.x;
    if (tid >= (long long)ne * 32) return;
    int e = (int)(tid >> 5), lane = (int)(tid & 31);
    int r = rows[e], c = cols[e];
    float v = vals[e];
    const float4 s = *reinterpret_cast<const float4*>(src + (long long)c * CH + lane * 4);
    float* d = dst + (long long)r * CH + lane * 4;
    unsafeAtomicAdd(d + 0, v * s.x);
    unsafeAtomicAdd(d + 1, v * s.y);
    unsafeAtomicAdd(d + 2, v * s.z);
    unsafeAtomicAdd(d + 3, v * s.w);
}

// ---------------- launch ----------------

static inline size_t align64(size_t x) { return (x + 63) & ~(size_t)63; }

extern "C" void kernel_launch(void* const* d_in, const int* in_sizes, int n_in,
                              void* d_out, int out_size, void* d_ws, size_t ws_size,
                              hipStream_t stream) {
    const int*   feat_rows = (const int*)d_in[0];
    const int*   feat_cols = (const int*)d_in[1];
    const float* feat_vals = (const float*)d_in[2];
    const int*   adj_rows  = (const int*)d_in[3];
    const int*   adj_cols  = (const int*)d_in[4];
    const float* adj_vals  = (const float*)d_in[5];
    const float* weight    = (const float*)d_in[6];
    const float* bias      = (const float*)d_in[7];

    const int nnz = in_sizes[0];
    const int ne  = in_sizes[3];
    const int n   = out_size / CH;   // n_nodes
    const int in_ch = in_sizes[6] / CH;

    float* out = (float*)d_out;
    char*  ws  = (char*)d_ws;

    const size_t NBF = (size_t)n * CH * sizeof(float);
    const size_t NBH = (size_t)n * CH * sizeof(__half);
    const long long total_elems = (long long)n * CH;
    const int BLK = 256;
    const int ew_blocks = (int)((total_elems / 4 + BLK - 1) / BLK);
    const int maxe = nnz > ne ? nnz : ne;
    const int nb_scan = (n + SCAN_BLK - 1) / SCAN_BLK;
    const int nbuck = (n + BR - 1) / BR;
    const size_t bin_lds = (size_t)nbuck * 2 * sizeof(int);

    // ws layout (fast path); cv_tmp aliases pingh (builds precede prop1 write)
    size_t off = 0;
    __half2* baseh  = (__half2*)(ws + off); off += align64(NBH);
    __half2* pingh  = (__half2*)(ws + off); off += align64(NBH);
    int*   row_ptr = (int*)(ws + off);   off += align64(((size_t)n + 1) * 4);
    int*   counts  = (int*)(ws + off);   off += align64((size_t)n * 4);
    int*   bsum    = (int*)(ws + off);   off += align64((size_t)nb_scan * 4);
    int*   bcur    = (int*)(ws + off);   off += align64((size_t)nbuck * 4);
    int2*  cv      = (int2*)(ws + off);  off += align64((size_t)maxe * 8);
    int2*  cv_tmp  = (int2*)pingh;       // 12.8MB inside the 25.6MB pingh buffer
    const bool fast = (ws_size >= off) && (nb_scan <= SCAN_BLK) &&
                      (n <= (1 << 24)) && (bin_lds <= 64 * 1024) &&
                      (in_ch == 512) &&
                      ((size_t)maxe * 8 <= NBH);

    if (fast) {
        const int row_blocks = (int)(((long long)n * 64 + BLK - 1) / BLK);
        const int n_blocks = (n + BLK - 1) / BLK;
        const int eb_feat = (nnz + BLK - 1) / BLK;
        const int eb_adj  = (ne + BLK - 1) / BLK;
        const int chunk_feat = (nnz + BIN_WGS - 1) / BIN_WGS;
        const int chunk_adj  = (ne + BIN_WGS - 1) / BIN_WGS;
        const int rows_per_wg = (n + SPMM_WGS - 1) / SPMM_WGS;

        // --- feat CSR ---
        hipMemsetAsync(counts, 0, (size_t)n * 4, stream);
        hist_kernel<<<eb_feat, BLK, 0, stream>>>(feat_rows, counts, nnz);
        scan_local_kernel<<<nb_scan, SCAN_BLK, 0, stream>>>(counts, row_ptr, bsum, n);
        scan_bsum_kernel<<<1, SCAN_BLK, 0, stream>>>(bsum, nb_scan, row_ptr + n);
        add_off_kernel<<<n_blocks, BLK, 0, stream>>>(row_ptr, bsum, bcur, n);
        multisplit_bin_kernel<<<BIN_WGS, BLK, bin_lds, stream>>>(
            feat_rows, feat_cols, feat_vals, bcur, cv_tmp, nnz, nbuck, chunk_feat);
        reorder_kernel<<<nbuck, BLK, 0, stream>>>(row_ptr, cv_tmp, cv, n);
        // --- base = relu(SpMM(feat, W) + bias) -> baseh (f16, LDS-staged W) ---
        spmm_lds_kernel<<<SPMM_WGS, 512, 0, stream>>>(
            row_ptr, (const long long*)cv, weight, bias, baseh, n, rows_per_wg);

        // --- adj CSR (cv_tmp region free until prop1 writes pingh) ---
        hipMemsetAsync(counts, 0, (size_t)n * 4, stream);
        hist_kernel<<<eb_adj, BLK, 0, stream>>>(adj_rows, counts, ne);
        scan_local_kernel<<<nb_scan, SCAN_BLK, 0, stream>>>(counts, row_ptr, bsum, n);
        scan_bsum_kernel<<<1, SCAN_BLK, 0, stream>>>(bsum, nb_scan, row_ptr + n);
        add_off_kernel<<<n_blocks, BLK, 0, stream>>>(row_ptr, bsum, bcur, n);
        multisplit_bin_kernel<<<BIN_WGS, BLK, bin_lds, stream>>>(
            adj_rows, adj_cols, adj_vals, bcur, cv_tmp, ne, nbuck, chunk_adj);
        reorder_kernel<<<nbuck, BLK, 0, stream>>>(row_ptr, cv_tmp, cv, n);
        // --- prop x2 ---
        prop_csr_h2h_kernel<<<row_blocks, BLK, 0, stream>>>(
            row_ptr, (const long long*)cv, baseh, pingh, n);
        prop_csr_h2f_kernel<<<row_blocks, BLK, 0, stream>>>(
            row_ptr, (const long long*)cv, pingh, out, n);
    } else {
        // round-1 fallback: atomic scatter (f32)
        float* ping = (float*)ws;
        const int spmm_blocks = (int)(((long long)nnz * 32 + BLK - 1) / BLK);
        const int prop_blocks = (int)(((long long)ne * 32 + BLK - 1) / BLK);
        hipMemsetAsync(d_out, 0, NBF, stream);
        spmm_scatter_kernel<<<spmm_blocks, BLK, 0, stream>>>(feat_rows, feat_cols, feat_vals,
                                                             weight, out, nnz);
        bias_relu_kernel<<<ew_blocks, BLK, 0, stream>>>(out, bias, total_elems);
        hipMemsetAsync(ping, 0, NBF, stream);
        prop_scatter_kernel<<<prop_blocks, BLK, 0, stream>>>(adj_rows, adj_cols, adj_vals,
                                                             out, ping, ne);
        hipMemsetAsync(d_out, 0, NBF, stream);
        prop_scatter_kernel<<<prop_blocks, BLK, 0, stream>>>(adj_rows, adj_cols, adj_vals,
                                                             ping, out, ne);
    }
}

// Round 9
// 384.676 us; speedup vs baseline: 20.8890x; 1.1742x over previous
//
#include <hip/hip_runtime.h>
#include <hip/hip_fp16.h>

// SparseNGCNLayer: base = relu(SpMM(feat, W) + bias); base = A @ base (x2)
// Round 9:
//   - bin: 256 WGs x 512 thr (was 128x256 @ 4.6% occupancy) + 4-deep ILP
//     unroll of count/scatter phases. Fragments stay ~1 line (write-local).
//   - spmm: W pre-converted to fp16 (Wh, 128KB, L2-hot) once; gather kernel
//     uses 4-edges-per-wave-step: 16 lanes x 16B (float4 = 4 half2) cover one
//     edge's 128 ch; cross-group shfl_xor reduce at row end. High occupancy,
//     1/4 the per-edge instruction cost of the LDS-staged version.
//   - props unchanged (near gather-fabric floor).

#define CH 128
#define BR 128            // rows per bucket (rlocal fits in 7 bits)
#define SCAN_BLK 1024
#define BIN_WGS 256       // multisplit workgroups (contiguous chunks)
#define BIN_THR 512

// ---------------- CSR build ----------------

__global__ void hist_kernel(const int* __restrict__ rows, int* __restrict__ counts, int n) {
    int i = blockIdx.x * blockDim.x + threadIdx.x;
    if (i < n) atomicAdd(&counts[rows[i]], 1);
}

__global__ void scan_local_kernel(const int* __restrict__ counts, int* __restrict__ row_ptr,
                                  int* __restrict__ bsum, int n) {
    __shared__ int lds[SCAN_BLK];
    int tid = threadIdx.x;
    int i = blockIdx.x * SCAN_BLK + tid;
    int x = (i < n) ? counts[i] : 0;
    lds[tid] = x;
    __syncthreads();
    for (int off = 1; off < SCAN_BLK; off <<= 1) {
        int y = (tid >= off) ? lds[tid - off] : 0;
        __syncthreads();
        lds[tid] += y;
        __syncthreads();
    }
    if (i < n) row_ptr[i] = lds[tid] - x;      // local exclusive
    if (tid == SCAN_BLK - 1) bsum[blockIdx.x] = lds[SCAN_BLK - 1];
}

__global__ void scan_bsum_kernel(int* __restrict__ bsum, int nb, int* __restrict__ total_out) {
    __shared__ int lds[SCAN_BLK];
    int tid = threadIdx.x;
    int x = (tid < nb) ? bsum[tid] : 0;
    lds[tid] = x;
    __syncthreads();
    for (int off = 1; off < SCAN_BLK; off <<= 1) {
        int y = (tid >= off) ? lds[tid - off] : 0;
        __syncthreads();
        lds[tid] += y;
        __syncthreads();
    }
    if (tid < nb) bsum[tid] = lds[tid] - x;    // exclusive
    if (tid == SCAN_BLK - 1) *total_out = lds[SCAN_BLK - 1];
}

// add block offsets to row_ptr; also init bucket cursors (fused)
__global__ void add_off_kernel(int* __restrict__ row_ptr, const int* __restrict__ bsum,
                               int* __restrict__ bcur, int n) {
    int i = blockIdx.x * blockDim.x + threadIdx.x;
    if (i >= n) return;
    int v = row_ptr[i] + bsum[i >> 10];
    row_ptr[i] = v;
    if ((i & (BR - 1)) == 0) bcur[i >> 7] = v;
}

// 3-phase multisplit bin: WG-private subranges per bucket.
// rlocal packed into col bits [24:31).
__global__ void multisplit_bin_kernel(const int* __restrict__ rows, const int* __restrict__ cols,
                                      const float* __restrict__ vals, int* __restrict__ bcur,
                                      int2* __restrict__ cv_tmp, int nE, int nbuck, int chunk) {
    extern __shared__ int lds[];
    int* hcnt  = lds;            // [nbuck] counts, then reused as local cursors
    int* hbase = lds + nbuck;    // [nbuck] reserved global bases
    const int tid = threadIdx.x;
    const long long T = blockDim.x;
    long long start = (long long)blockIdx.x * chunk;
    long long end = start + chunk;
    if (end > nE) end = nE;
    if (start >= end) return;

    for (int b = tid; b < nbuck; b += blockDim.x) hcnt[b] = 0;
    __syncthreads();
    // phase 1: count (4-deep ILP)
    {
        long long i = start + tid;
        for (; i + 3 * T < end; i += 4 * T) {
            int r0 = rows[i], r1 = rows[i + T], r2 = rows[i + 2 * T], r3 = rows[i + 3 * T];
            atomicAdd(&hcnt[r0 >> 7], 1);
            atomicAdd(&hcnt[r1 >> 7], 1);
            atomicAdd(&hcnt[r2 >> 7], 1);
            atomicAdd(&hcnt[r3 >> 7], 1);
        }
        for (; i < end; i += T) atomicAdd(&hcnt[rows[i] >> 7], 1);
    }
    __syncthreads();
    // phase 2: reserve subranges
    for (int b = tid; b < nbuck; b += blockDim.x) {
        int c = hcnt[b];
        hbase[b] = c ? atomicAdd(&bcur[b], c) : 0;
        hcnt[b] = 0;
    }
    __syncthreads();
    // phase 3: write into WG-private subranges (4-deep ILP)
    {
        long long i = start + tid;
        for (; i + 3 * T < end; i += 4 * T) {
            int r0 = rows[i], r1 = rows[i + T], r2 = rows[i + 2 * T], r3 = rows[i + 3 * T];
            int c0 = cols[i], c1 = cols[i + T], c2 = cols[i + 2 * T], c3 = cols[i + 3 * T];
            float v0 = vals[i], v1 = vals[i + T], v2 = vals[i + 2 * T], v3 = vals[i + 3 * T];
            int b0 = r0 >> 7, b1 = r1 >> 7, b2 = r2 >> 7, b3 = r3 >> 7;
            int p0 = hbase[b0] + atomicAdd(&hcnt[b0], 1);
            int p1 = hbase[b1] + atomicAdd(&hcnt[b1], 1);
            int p2 = hbase[b2] + atomicAdd(&hcnt[b2], 1);
            int p3 = hbase[b3] + atomicAdd(&hcnt[b3], 1);
            cv_tmp[p0] = make_int2(c0 | ((r0 & (BR - 1)) << 24), __float_as_int(v0));
            cv_tmp[p1] = make_int2(c1 | ((r1 & (BR - 1)) << 24), __float_as_int(v1));
            cv_tmp[p2] = make_int2(c2 | ((r2 & (BR - 1)) << 24), __float_as_int(v2));
            cv_tmp[p3] = make_int2(c3 | ((r3 & (BR - 1)) << 24), __float_as_int(v3));
        }
        for (; i < end; i += T) {
            int r = rows[i];
            int b = r >> 7;
            int p = hbase[b] + atomicAdd(&hcnt[b], 1);
            cv_tmp[p] = make_int2(cols[i] | ((r & (BR - 1)) << 24), __float_as_int(vals[i]));
        }
    }
}

// reorder within bucket using LDS per-row cursors
__global__ void reorder_kernel(const int* __restrict__ row_ptr, const int2* __restrict__ cv_tmp,
                               int2* __restrict__ cv, int n) {
    __shared__ int cur[BR];
    int b = blockIdx.x;
    int base = b * BR;
    int tid = threadIdx.x;
    if (tid < BR && base + tid < n) cur[tid] = row_ptr[base + tid];
    __syncthreads();
    int endrow = base + BR; if (endrow > n) endrow = n;
    int s = row_ptr[base];
    int e = row_ptr[endrow];
    for (int i = s + tid; i < e; i += blockDim.x) {
        int2 ent = cv_tmp[i];
        int rl = ((unsigned)ent.x) >> 24;
        int p = atomicAdd(&cur[rl], 1);
        cv[p] = make_int2(ent.x & 0x00FFFFFF, ent.y);
    }
}

// ---------------- W fp16 conversion ----------------

__global__ void wconv_kernel(const float* __restrict__ W, __half2* __restrict__ Wh, int n2) {
    int i = blockIdx.x * blockDim.x + threadIdx.x;
    if (i < n2) Wh[i] = __float22half2_rn(reinterpret_cast<const float2*>(W)[i]);
}

// ---------------- gather-reduce row kernels ----------------

// SpMM, 4 edges per wave-step: group g = lane>>4 owns edge base+g, channel
// lane cl = lane&15 owns ch [cl*8, cl*8+8) via one 16B load of Wh.
// Cross-group shfl_xor reduce at row end; bias+relu in epilogue.
__global__ void spmm_g4_kernel(const int* __restrict__ row_ptr,
                               const long long* __restrict__ cv,
                               const __half2* __restrict__ Wh,   // [in_ch][64] half2
                               const float* __restrict__ bias,
                               __half2* __restrict__ outh, int n) {
    __shared__ long long sc[4 * 64];
    int gtid = blockIdx.x * blockDim.x + threadIdx.x;
    int wid = gtid >> 6;
    int lane = gtid & 63;
    if (wid >= n) return;
    int g = lane >> 4;
    int cl = lane & 15;
    long long* mysc = sc + (threadIdx.x >> 6) * 64;
    int s = row_ptr[wid], e = row_ptr[wid + 1];
    float acc0 = 0.f, acc1 = 0.f, acc2 = 0.f, acc3 = 0.f;
    float acc4 = 0.f, acc5 = 0.f, acc6 = 0.f, acc7 = 0.f;
    for (int base = s; base < e; base += 64) {
        int idx = base + lane;
        mysc[lane] = (idx < e) ? cv[idx] : 0;   // wave-private, no barrier
        int m = e - base; if (m > 64) m = 64;
        for (int k0 = 0; k0 < m; k0 += 4) {
            long long ck = mysc[k0 + g];        // 4 distinct 8B addrs: no conflict
            int col = (int)ck;
            float v = __int_as_float((int)(ck >> 32));
            float4 wv = *reinterpret_cast<const float4*>(Wh + (long long)col * 64 + cl * 4);
            float2 f0 = __half22float2(*reinterpret_cast<const __half2*>(&wv.x));
            float2 f1 = __half22float2(*reinterpret_cast<const __half2*>(&wv.y));
            float2 f2 = __half22float2(*reinterpret_cast<const __half2*>(&wv.z));
            float2 f3 = __half22float2(*reinterpret_cast<const __half2*>(&wv.w));
            acc0 += v * f0.x; acc1 += v * f0.y;
            acc2 += v * f1.x; acc3 += v * f1.y;
            acc4 += v * f2.x; acc5 += v * f2.y;
            acc6 += v * f3.x; acc7 += v * f3.y;
        }
    }
    // reduce across the 4 edge-groups (lanes ±16, ±32)
    acc0 += __shfl_xor(acc0, 16); acc1 += __shfl_xor(acc1, 16);
    acc2 += __shfl_xor(acc2, 16); acc3 += __shfl_xor(acc3, 16);
    acc4 += __shfl_xor(acc4, 16); acc5 += __shfl_xor(acc5, 16);
    acc6 += __shfl_xor(acc6, 16); acc7 += __shfl_xor(acc7, 16);
    acc0 += __shfl_xor(acc0, 32); acc1 += __shfl_xor(acc1, 32);
    acc2 += __shfl_xor(acc2, 32); acc3 += __shfl_xor(acc3, 32);
    acc4 += __shfl_xor(acc4, 32); acc5 += __shfl_xor(acc5, 32);
    acc6 += __shfl_xor(acc6, 32); acc7 += __shfl_xor(acc7, 32);
    if (g == 0) {
        const float4* bp = reinterpret_cast<const float4*>(bias);
        float4 b0 = bp[cl * 2], b1 = bp[cl * 2 + 1];
        acc0 = fmaxf(acc0 + b0.x, 0.f); acc1 = fmaxf(acc1 + b0.y, 0.f);
        acc2 = fmaxf(acc2 + b0.z, 0.f); acc3 = fmaxf(acc3 + b0.w, 0.f);
        acc4 = fmaxf(acc4 + b1.x, 0.f); acc5 = fmaxf(acc5 + b1.y, 0.f);
        acc6 = fmaxf(acc6 + b1.z, 0.f); acc7 = fmaxf(acc7 + b1.w, 0.f);
        __half2 h0 = __floats2half2_rn(acc0, acc1);
        __half2 h1 = __floats2half2_rn(acc2, acc3);
        __half2 h2 = __floats2half2_rn(acc4, acc5);
        __half2 h3 = __floats2half2_rn(acc6, acc7);
        float4 ov;
        *reinterpret_cast<__half2*>(&ov.x) = h0;
        *reinterpret_cast<__half2*>(&ov.y) = h1;
        *reinterpret_cast<__half2*>(&ov.z) = h2;
        *reinterpret_cast<__half2*>(&ov.w) = h3;
        *reinterpret_cast<float4*>(outh + (long long)wid * 64 + cl * 4) = ov;
    }
}

// prop: gather f16 rows, f32 accumulate. one wave per row, scratch broadcast.
__global__ void prop_csr_h2h_kernel(const int* __restrict__ row_ptr,
                                    const long long* __restrict__ cv,
                                    const __half2* __restrict__ src, __half2* __restrict__ dst,
                                    int n) {
    __shared__ long long sc[4 * 64];
    int gtid = blockIdx.x * blockDim.x + threadIdx.x;
    int wid = gtid >> 6;
    int lane = gtid & 63;
    if (wid >= n) return;
    long long* mysc = sc + (threadIdx.x >> 6) * 64;
    int s = row_ptr[wid], e = row_ptr[wid + 1];
    float2 acc = {0.0f, 0.0f};
    for (int base = s; base < e; base += 64) {
        int idx = base + lane;
        mysc[lane] = (idx < e) ? cv[idx] : 0;
        int m = e - base; if (m > 64) m = 64;
        for (int k0 = 0; k0 < m; k0 += 8) {
            #pragma unroll
            for (int j = 0; j < 8; j++) {
                long long ck = mysc[k0 + j];
                int col = (int)ck;
                float v = __int_as_float((int)(ck >> 32));
                float2 xf = __half22float2(src[(long long)col * 64 + lane]);
                acc.x += v * xf.x; acc.y += v * xf.y;
            }
        }
    }
    dst[(long long)wid * 64 + lane] = __float22half2_rn(acc);
}

__global__ void prop_csr_h2f_kernel(const int* __restrict__ row_ptr,
                                    const long long* __restrict__ cv,
                                    const __half2* __restrict__ src, float* __restrict__ dst,
                                    int n) {
    __shared__ long long sc[4 * 64];
    int gtid = blockIdx.x * blockDim.x + threadIdx.x;
    int wid = gtid >> 6;
    int lane = gtid & 63;
    if (wid >= n) return;
    long long* mysc = sc + (threadIdx.x >> 6) * 64;
    int s = row_ptr[wid], e = row_ptr[wid + 1];
    float2 acc = {0.0f, 0.0f};
    for (int base = s; base < e; base += 64) {
        int idx = base + lane;
        mysc[lane] = (idx < e) ? cv[idx] : 0;
        int m = e - base; if (m > 64) m = 64;
        for (int k0 = 0; k0 < m; k0 += 8) {
            #pragma unroll
            for (int j = 0; j < 8; j++) {
                long long ck = mysc[k0 + j];
                int col = (int)ck;
                float v = __int_as_float((int)(ck >> 32));
                float2 xf = __half22float2(src[(long long)col * 64 + lane]);
                acc.x += v * xf.x; acc.y += v * xf.y;
            }
        }
    }
    reinterpret_cast<float2*>(dst)[(long long)wid * 64 + lane] = acc;
}

// ---------------- round-1 fallback (atomic scatter, f32) ----------------

__global__ void bias_relu_kernel(float* __restrict__ buf, const float* __restrict__ bias,
                                 long long total) {
    long long i = ((long long)blockIdx.x * blockDim.x + threadIdx.x) * 4;
    if (i >= total) return;
    float4 v = *reinterpret_cast<float4*>(buf + i);
    int ch = (int)(i & (CH - 1));
    float4 b = *reinterpret_cast<const float4*>(bias + ch);
    v.x = fmaxf(v.x + b.x, 0.0f);
    v.y = fmaxf(v.y + b.y, 0.0f);
    v.z = fmaxf(v.z + b.z, 0.0f);
    v.w = fmaxf(v.w + b.w, 0.0f);
    *reinterpret_cast<float4*>(buf + i) = v;
}

__global__ void spmm_scatter_kernel(const int* __restrict__ rows, const int* __restrict__ cols,
                                    const float* __restrict__ vals, const float* __restrict__ weight,
                                    float* __restrict__ out, int nnz) {
    long long tid = (long long)blockIdx.x * blockDim.x + threadIdx.x;
    if (tid >= (long long)nnz * 32) return;
    int e = (int)(tid >> 5), lane = (int)(tid & 31);
    int r = rows[e], c = cols[e];
    float v = vals[e];
    const float4 w = *reinterpret_cast<const float4*>(weight + (long long)c * CH + lane * 4);
    float* dst = out + (long long)r * CH + lane * 4;
    unsafeAtomicAdd(dst + 0, v * w.x);
    unsafeAtomicAdd(dst + 1, v * w.y);
    unsafeAtomicAdd(dst + 2, v * w.z);
    unsafeAtomicAdd(dst + 3, v * w.w);
}

__global__ void prop_scatter_kernel(const int* __restrict__ rows, const int* __restrict__ cols,
                                    const float* __restrict__ vals, const float* __restrict__ src,
                                    float* __restrict__ dst, int ne) {
    long long tid = (long long)blockIdx.x * blockDim.x + threadIdx.x;
    if (tid >= (long long)ne * 32) return;
    int e = (int)(tid >> 5), lane = (int)(tid & 31);
    int r = rows[e], c = cols[e];
    float v = vals[e];
    const float4 s = *reinterpret_cast<const float4*>(src + (long long)c * CH + lane * 4);
    float* d = dst + (long long)r * CH + lane * 4;
    unsafeAtomicAdd(d + 0, v * s.x);
    unsafeAtomicAdd(d + 1, v * s.y);
    unsafeAtomicAdd(d + 2, v * s.z);
    unsafeAtomicAdd(d + 3, v * s.w);
}

// ---------------- launch ----------------

static inline size_t align64(size_t x) { return (x + 63) & ~(size_t)63; }

extern "C" void kernel_launch(void* const* d_in, const int* in_sizes, int n_in,
                              void* d_out, int out_size, void* d_ws, size_t ws_size,
                              hipStream_t stream) {
    const int*   feat_rows = (const int*)d_in[0];
    const int*   feat_cols = (const int*)d_in[1];
    const float* feat_vals = (const float*)d_in[2];
    const int*   adj_rows  = (const int*)d_in[3];
    const int*   adj_cols  = (const int*)d_in[4];
    const float* adj_vals  = (const float*)d_in[5];
    const float* weight    = (const float*)d_in[6];
    const float* bias      = (const float*)d_in[7];

    const int nnz = in_sizes[0];
    const int ne  = in_sizes[3];
    const int n   = out_size / CH;   // n_nodes
    const int in_ch = in_sizes[6] / CH;

    float* out = (float*)d_out;
    char*  ws  = (char*)d_ws;

    const size_t NBF = (size_t)n * CH * sizeof(float);
    const size_t NBH = (size_t)n * CH * sizeof(__half);
    const long long total_elems = (long long)n * CH;
    const int BLK = 256;
    const int ew_blocks = (int)((total_elems / 4 + BLK - 1) / BLK);
    const int maxe = nnz > ne ? nnz : ne;
    const int nb_scan = (n + SCAN_BLK - 1) / SCAN_BLK;
    const int nbuck = (n + BR - 1) / BR;
    const size_t bin_lds = (size_t)nbuck * 2 * sizeof(int);

    // ws layout (fast path); cv_tmp aliases pingh (builds precede prop1 write)
    size_t off = 0;
    __half2* baseh  = (__half2*)(ws + off); off += align64(NBH);
    __half2* pingh  = (__half2*)(ws + off); off += align64(NBH);
    int*   row_ptr = (int*)(ws + off);   off += align64(((size_t)n + 1) * 4);
    int*   counts  = (int*)(ws + off);   off += align64((size_t)n * 4);
    int*   bsum    = (int*)(ws + off);   off += align64((size_t)nb_scan * 4);
    int*   bcur    = (int*)(ws + off);   off += align64((size_t)nbuck * 4);
    __half2* Wh    = (__half2*)(ws + off); off += align64((size_t)in_ch * 64 * 4);
    int2*  cv      = (int2*)(ws + off);  off += align64((size_t)maxe * 8);
    int2*  cv_tmp  = (int2*)pingh;       // 12.8MB inside the 25.6MB pingh buffer
    const bool fast = (ws_size >= off) && (nb_scan <= SCAN_BLK) &&
                      (n <= (1 << 24)) && (bin_lds <= 64 * 1024) &&
                      (in_ch <= (1 << 22)) &&
                      ((size_t)maxe * 8 <= NBH);

    if (fast) {
        const int row_blocks = (int)(((long long)n * 64 + BLK - 1) / BLK);
        const int n_blocks = (n + BLK - 1) / BLK;
        const int eb_feat = (nnz + BLK - 1) / BLK;
        const int eb_adj  = (ne + BLK - 1) / BLK;
        const int chunk_feat = (nnz + BIN_WGS - 1) / BIN_WGS;
        const int chunk_adj  = (ne + BIN_WGS - 1) / BIN_WGS;
        const int w2 = in_ch * 64;

        // --- W fp16 conversion (independent of CSR build) ---
        wconv_kernel<<<(w2 + BLK - 1) / BLK, BLK, 0, stream>>>(weight, Wh, w2);

        // --- feat CSR ---
        hipMemsetAsync(counts, 0, (size_t)n * 4, stream);
        hist_kernel<<<eb_feat, BLK, 0, stream>>>(feat_rows, counts, nnz);
        scan_local_kernel<<<nb_scan, SCAN_BLK, 0, stream>>>(counts, row_ptr, bsum, n);
        scan_bsum_kernel<<<1, SCAN_BLK, 0, stream>>>(bsum, nb_scan, row_ptr + n);
        add_off_kernel<<<n_blocks, BLK, 0, stream>>>(row_ptr, bsum, bcur, n);
        multisplit_bin_kernel<<<BIN_WGS, BIN_THR, bin_lds, stream>>>(
            feat_rows, feat_cols, feat_vals, bcur, cv_tmp, nnz, nbuck, chunk_feat);
        reorder_kernel<<<nbuck, BIN_THR, 0, stream>>>(row_ptr, cv_tmp, cv, n);
        // --- base = relu(SpMM(feat, W) + bias) -> baseh (f16) ---
        spmm_g4_kernel<<<row_blocks, BLK, 0, stream>>>(
            row_ptr, (const long long*)cv, Wh, bias, baseh, n);

        // --- adj CSR (cv_tmp region free until prop1 writes pingh) ---
        hipMemsetAsync(counts, 0, (size_t)n * 4, stream);
        hist_kernel<<<eb_adj, BLK, 0, stream>>>(adj_rows, counts, ne);
        scan_local_kernel<<<nb_scan, SCAN_BLK, 0, stream>>>(counts, row_ptr, bsum, n);
        scan_bsum_kernel<<<1, SCAN_BLK, 0, stream>>>(bsum, nb_scan, row_ptr + n);
        add_off_kernel<<<n_blocks, BLK, 0, stream>>>(row_ptr, bsum, bcur, n);
        multisplit_bin_kernel<<<BIN_WGS, BIN_THR, bin_lds, stream>>>(
            adj_rows, adj_cols, adj_vals, bcur, cv_tmp, ne, nbuck, chunk_adj);
        reorder_kernel<<<nbuck, BIN_THR, 0, stream>>>(row_ptr, cv_tmp, cv, n);
        // --- prop x2 ---
        prop_csr_h2h_kernel<<<row_blocks, BLK, 0, stream>>>(
            row_ptr, (const long long*)cv, baseh, pingh, n);
        prop_csr_h2f_kernel<<<row_blocks, BLK, 0, stream>>>(
            row_ptr, (const long long*)cv, pingh, out, n);
    } else {
        // round-1 fallback: atomic scatter (f32)
        float* ping = (float*)ws;
        const int spmm_blocks = (int)(((long long)nnz * 32 + BLK - 1) / BLK);
        const int prop_blocks = (int)(((long long)ne * 32 + BLK - 1) / BLK);
        hipMemsetAsync(d_out, 0, NBF, stream);
        spmm_scatter_kernel<<<spmm_blocks, BLK, 0, stream>>>(feat_rows, feat_cols, feat_vals,
                                                             weight, out, nnz);
        bias_relu_kernel<<<ew_blocks, BLK, 0, stream>>>(out, bias, total_elems);
        hipMemsetAsync(ping, 0, NBF, stream);
        prop_scatter_kernel<<<prop_blocks, BLK, 0, stream>>>(adj_rows, adj_cols, adj_vals,
                                                             out, ping, ne);
        hipMemsetAsync(d_out, 0, NBF, stream);
        prop_scatter_kernel<<<prop_blocks, BLK, 0, stream>>>(adj_rows, adj_cols, adj_vals,
                                                             ping, out, ne);
    }
}

// Round 10
// 259.067 us; speedup vs baseline: 31.0170x; 1.4849x over previous
//
#include <hip/hip_runtime.h>
#include <hip/hip_fp16.h>

// SparseNGCNLayer: base = relu(SpMM(feat, W) + bias); base = A @ base (x2)
// Round 10: bucket-level CSR build. Kills the row-level histogram pipeline
// (hist_kernel: 66us, 50MB WRITE for 400KB payload -- cross-XCD atomic line
// ping-pong on 100k counters) by deriving row_ptr inside the per-bucket
// reorder pass from the rlocal tags.
//   K1 bucket_hist: per-WG LDS hist -> 1 atomicAdd/(WG,bucket) into 3KB array
//   K2 bucket_scan: 1-WG scan of 782 bucket counts -> bcur, bucket_base, rp[n]
//   K3 multisplit_bin: unchanged (WG-private subranges, write-local)
//   K4 reorder2: LDS row-count + 128-wide scan -> row_ptr + scatter
// Gather kernels unchanged from round 9.

#define CH 128
#define BR 128            // rows per bucket (rlocal fits in 7 bits)
#define SCAN_BLK 1024
#define BIN_WGS 256       // multisplit workgroups (contiguous chunks)
#define BIN_THR 512

// ---------------- CSR build ----------------

// K1: per-WG LDS histogram over buckets; one global atomicAdd per (WG,bucket)
__global__ void bucket_hist_kernel(const int* __restrict__ rows, int* __restrict__ bcounts,
                                   int nE, int nbuck, int chunk) {
    extern __shared__ int hcnt[];
    const int tid = threadIdx.x;
    const long long T = blockDim.x;
    long long start = (long long)blockIdx.x * chunk;
    long long end = start + chunk;
    if (end > nE) end = nE;
    for (int b = tid; b < nbuck; b += blockDim.x) hcnt[b] = 0;
    __syncthreads();
    if (start < end) {
        long long i = start + tid;
        for (; i + 3 * T < end; i += 4 * T) {
            int r0 = rows[i], r1 = rows[i + T], r2 = rows[i + 2 * T], r3 = rows[i + 3 * T];
            atomicAdd(&hcnt[r0 >> 7], 1);
            atomicAdd(&hcnt[r1 >> 7], 1);
            atomicAdd(&hcnt[r2 >> 7], 1);
            atomicAdd(&hcnt[r3 >> 7], 1);
        }
        for (; i < end; i += T) atomicAdd(&hcnt[rows[i] >> 7], 1);
    }
    __syncthreads();
    for (int b = tid; b < nbuck; b += blockDim.x) {
        int c = hcnt[b];
        if (c) atomicAdd(&bcounts[b], c);
    }
}

// K2: single-WG scan of bucket counts -> bcur (bin cursors), bucket_base[0..nbuck],
// and row_ptr[n] = total.
__global__ void bucket_scan_kernel(const int* __restrict__ bcounts, int* __restrict__ bcur,
                                   int* __restrict__ bucket_base, int* __restrict__ row_ptr_n,
                                   int nbuck) {
    __shared__ int lds[SCAN_BLK];
    int tid = threadIdx.x;
    int x = (tid < nbuck) ? bcounts[tid] : 0;
    lds[tid] = x;
    __syncthreads();
    for (int off = 1; off < SCAN_BLK; off <<= 1) {
        int y = (tid >= off) ? lds[tid - off] : 0;
        __syncthreads();
        lds[tid] += y;
        __syncthreads();
    }
    if (tid < nbuck) {
        int excl = lds[tid] - x;
        bcur[tid] = excl;
        bucket_base[tid] = excl;
    }
    if (tid == nbuck - 1) {
        bucket_base[nbuck] = lds[tid];
        *row_ptr_n = lds[tid];
    }
}

// K3: 3-phase multisplit bin: WG-private subranges per bucket.
// rlocal packed into col bits [24:31).
__global__ void multisplit_bin_kernel(const int* __restrict__ rows, const int* __restrict__ cols,
                                      const float* __restrict__ vals, int* __restrict__ bcur,
                                      int2* __restrict__ cv_tmp, int nE, int nbuck, int chunk) {
    extern __shared__ int lds[];
    int* hcnt  = lds;            // [nbuck] counts, then reused as local cursors
    int* hbase = lds + nbuck;    // [nbuck] reserved global bases
    const int tid = threadIdx.x;
    const long long T = blockDim.x;
    long long start = (long long)blockIdx.x * chunk;
    long long end = start + chunk;
    if (end > nE) end = nE;
    if (start >= end) return;

    for (int b = tid; b < nbuck; b += blockDim.x) hcnt[b] = 0;
    __syncthreads();
    // phase 1: count (4-deep ILP)
    {
        long long i = start + tid;
        for (; i + 3 * T < end; i += 4 * T) {
            int r0 = rows[i], r1 = rows[i + T], r2 = rows[i + 2 * T], r3 = rows[i + 3 * T];
            atomicAdd(&hcnt[r0 >> 7], 1);
            atomicAdd(&hcnt[r1 >> 7], 1);
            atomicAdd(&hcnt[r2 >> 7], 1);
            atomicAdd(&hcnt[r3 >> 7], 1);
        }
        for (; i < end; i += T) atomicAdd(&hcnt[rows[i] >> 7], 1);
    }
    __syncthreads();
    // phase 2: reserve subranges
    for (int b = tid; b < nbuck; b += blockDim.x) {
        int c = hcnt[b];
        hbase[b] = c ? atomicAdd(&bcur[b], c) : 0;
        hcnt[b] = 0;
    }
    __syncthreads();
    // phase 3: write into WG-private subranges (4-deep ILP)
    {
        long long i = start + tid;
        for (; i + 3 * T < end; i += 4 * T) {
            int r0 = rows[i], r1 = rows[i + T], r2 = rows[i + 2 * T], r3 = rows[i + 3 * T];
            int c0 = cols[i], c1 = cols[i + T], c2 = cols[i + 2 * T], c3 = cols[i + 3 * T];
            float v0 = vals[i], v1 = vals[i + T], v2 = vals[i + 2 * T], v3 = vals[i + 3 * T];
            int b0 = r0 >> 7, b1 = r1 >> 7, b2 = r2 >> 7, b3 = r3 >> 7;
            int p0 = hbase[b0] + atomicAdd(&hcnt[b0], 1);
            int p1 = hbase[b1] + atomicAdd(&hcnt[b1], 1);
            int p2 = hbase[b2] + atomicAdd(&hcnt[b2], 1);
            int p3 = hbase[b3] + atomicAdd(&hcnt[b3], 1);
            cv_tmp[p0] = make_int2(c0 | ((r0 & (BR - 1)) << 24), __float_as_int(v0));
            cv_tmp[p1] = make_int2(c1 | ((r1 & (BR - 1)) << 24), __float_as_int(v1));
            cv_tmp[p2] = make_int2(c2 | ((r2 & (BR - 1)) << 24), __float_as_int(v2));
            cv_tmp[p3] = make_int2(c3 | ((r3 & (BR - 1)) << 24), __float_as_int(v3));
        }
        for (; i < end; i += T) {
            int r = rows[i];
            int b = r >> 7;
            int p = hbase[b] + atomicAdd(&hcnt[b], 1);
            cv_tmp[p] = make_int2(cols[i] | ((r & (BR - 1)) << 24), __float_as_int(vals[i]));
        }
    }
}

// K4: reorder within bucket; derives per-row counts/offsets from rlocal tags,
// writes row_ptr for its 128 rows, then scatters into row-sorted cv.
__global__ void reorder2_kernel(const int* __restrict__ bucket_base,
                                const int2* __restrict__ cv_tmp, int2* __restrict__ cv,
                                int* __restrict__ row_ptr, int n) {
    __shared__ int cnt[BR];
    __shared__ int tmp[BR];
    int b = blockIdx.x;
    int rbase = b * BR;
    int tid = threadIdx.x;
    int s = bucket_base[b], e = bucket_base[b + 1];
    if (tid < BR) cnt[tid] = 0;
    __syncthreads();
    // pass 1: per-row counts
    for (int i = s + tid; i < e; i += blockDim.x)
        atomicAdd(&cnt[((unsigned)cv_tmp[i].x) >> 24], 1);
    __syncthreads();
    if (tid < BR) tmp[tid] = cnt[tid];
    __syncthreads();
    // 128-wide inclusive scan (ladder)
    for (int off = 1; off < BR; off <<= 1) {
        int y = 0;
        if (tid < BR && tid >= off) y = tmp[tid - off];
        __syncthreads();
        if (tid < BR) tmp[tid] += y;
        __syncthreads();
    }
    if (tid < BR) {
        int excl = s + tmp[tid] - cnt[tid];
        if (rbase + tid < n) row_ptr[rbase + tid] = excl;
        cnt[tid] = excl;       // becomes the scatter cursor
    }
    __syncthreads();
    // pass 2: scatter row-sorted
    for (int i = s + tid; i < e; i += blockDim.x) {
        int2 ent = cv_tmp[i];
        int rl = ((unsigned)ent.x) >> 24;
        int p = atomicAdd(&cnt[rl], 1);
        cv[p] = make_int2(ent.x & 0x00FFFFFF, ent.y);
    }
}

// ---------------- W fp16 conversion ----------------

__global__ void wconv_kernel(const float* __restrict__ W, __half2* __restrict__ Wh, int n2) {
    int i = blockIdx.x * blockDim.x + threadIdx.x;
    if (i < n2) Wh[i] = __float22half2_rn(reinterpret_cast<const float2*>(W)[i]);
}

// ---------------- gather-reduce row kernels ----------------

// SpMM, 4 edges per wave-step: group g = lane>>4 owns edge base+g, channel
// lane cl = lane&15 owns ch [cl*8, cl*8+8) via one 16B load of Wh.
__global__ void spmm_g4_kernel(const int* __restrict__ row_ptr,
                               const long long* __restrict__ cv,
                               const __half2* __restrict__ Wh,   // [in_ch][64] half2
                               const float* __restrict__ bias,
                               __half2* __restrict__ outh, int n) {
    __shared__ long long sc[4 * 64];
    int gtid = blockIdx.x * blockDim.x + threadIdx.x;
    int wid = gtid >> 6;
    int lane = gtid & 63;
    if (wid >= n) return;
    int g = lane >> 4;
    int cl = lane & 15;
    long long* mysc = sc + (threadIdx.x >> 6) * 64;
    int s = row_ptr[wid], e = row_ptr[wid + 1];
    float acc0 = 0.f, acc1 = 0.f, acc2 = 0.f, acc3 = 0.f;
    float acc4 = 0.f, acc5 = 0.f, acc6 = 0.f, acc7 = 0.f;
    for (int base = s; base < e; base += 64) {
        int idx = base + lane;
        mysc[lane] = (idx < e) ? cv[idx] : 0;   // wave-private, no barrier
        int m = e - base; if (m > 64) m = 64;
        for (int k0 = 0; k0 < m; k0 += 4) {
            long long ck = mysc[k0 + g];        // 4 distinct 8B addrs: no conflict
            int col = (int)ck;
            float v = __int_as_float((int)(ck >> 32));
            float4 wv = *reinterpret_cast<const float4*>(Wh + (long long)col * 64 + cl * 4);
            float2 f0 = __half22float2(*reinterpret_cast<const __half2*>(&wv.x));
            float2 f1 = __half22float2(*reinterpret_cast<const __half2*>(&wv.y));
            float2 f2 = __half22float2(*reinterpret_cast<const __half2*>(&wv.z));
            float2 f3 = __half22float2(*reinterpret_cast<const __half2*>(&wv.w));
            acc0 += v * f0.x; acc1 += v * f0.y;
            acc2 += v * f1.x; acc3 += v * f1.y;
            acc4 += v * f2.x; acc5 += v * f2.y;
            acc6 += v * f3.x; acc7 += v * f3.y;
        }
    }
    acc0 += __shfl_xor(acc0, 16); acc1 += __shfl_xor(acc1, 16);
    acc2 += __shfl_xor(acc2, 16); acc3 += __shfl_xor(acc3, 16);
    acc4 += __shfl_xor(acc4, 16); acc5 += __shfl_xor(acc5, 16);
    acc6 += __shfl_xor(acc6, 16); acc7 += __shfl_xor(acc7, 16);
    acc0 += __shfl_xor(acc0, 32); acc1 += __shfl_xor(acc1, 32);
    acc2 += __shfl_xor(acc2, 32); acc3 += __shfl_xor(acc3, 32);
    acc4 += __shfl_xor(acc4, 32); acc5 += __shfl_xor(acc5, 32);
    acc6 += __shfl_xor(acc6, 32); acc7 += __shfl_xor(acc7, 32);
    if (g == 0) {
        const float4* bp = reinterpret_cast<const float4*>(bias);
        float4 b0 = bp[cl * 2], b1 = bp[cl * 2 + 1];
        acc0 = fmaxf(acc0 + b0.x, 0.f); acc1 = fmaxf(acc1 + b0.y, 0.f);
        acc2 = fmaxf(acc2 + b0.z, 0.f); acc3 = fmaxf(acc3 + b0.w, 0.f);
        acc4 = fmaxf(acc4 + b1.x, 0.f); acc5 = fmaxf(acc5 + b1.y, 0.f);
        acc6 = fmaxf(acc6 + b1.z, 0.f); acc7 = fmaxf(acc7 + b1.w, 0.f);
        __half2 h0 = __floats2half2_rn(acc0, acc1);
        __half2 h1 = __floats2half2_rn(acc2, acc3);
        __half2 h2 = __floats2half2_rn(acc4, acc5);
        __half2 h3 = __floats2half2_rn(acc6, acc7);
        float4 ov;
        *reinterpret_cast<__half2*>(&ov.x) = h0;
        *reinterpret_cast<__half2*>(&ov.y) = h1;
        *reinterpret_cast<__half2*>(&ov.z) = h2;
        *reinterpret_cast<__half2*>(&ov.w) = h3;
        *reinterpret_cast<float4*>(outh + (long long)wid * 64 + cl * 4) = ov;
    }
}

// prop: gather f16 rows, f32 accumulate. one wave per row, scratch broadcast.
__global__ void prop_csr_h2h_kernel(const int* __restrict__ row_ptr,
                                    const long long* __restrict__ cv,
                                    const __half2* __restrict__ src, __half2* __restrict__ dst,
                                    int n) {
    __shared__ long long sc[4 * 64];
    int gtid = blockIdx.x * blockDim.x + threadIdx.x;
    int wid = gtid >> 6;
    int lane = gtid & 63;
    if (wid >= n) return;
    long long* mysc = sc + (threadIdx.x >> 6) * 64;
    int s = row_ptr[wid], e = row_ptr[wid + 1];
    float2 acc = {0.0f, 0.0f};
    for (int base = s; base < e; base += 64) {
        int idx = base + lane;
        mysc[lane] = (idx < e) ? cv[idx] : 0;
        int m = e - base; if (m > 64) m = 64;
        for (int k0 = 0; k0 < m; k0 += 8) {
            #pragma unroll
            for (int j = 0; j < 8; j++) {
                long long ck = mysc[k0 + j];
                int col = (int)ck;
                float v = __int_as_float((int)(ck >> 32));
                float2 xf = __half22float2(src[(long long)col * 64 + lane]);
                acc.x += v * xf.x; acc.y += v * xf.y;
            }
        }
    }
    dst[(long long)wid * 64 + lane] = __float22half2_rn(acc);
}

__global__ void prop_csr_h2f_kernel(const int* __restrict__ row_ptr,
                                    const long long* __restrict__ cv,
                                    const __half2* __restrict__ src, float* __restrict__ dst,
                                    int n) {
    __shared__ long long sc[4 * 64];
    int gtid = blockIdx.x * blockDim.x + threadIdx.x;
    int wid = gtid >> 6;
    int lane = gtid & 63;
    if (wid >= n) return;
    long long* mysc = sc + (threadIdx.x >> 6) * 64;
    int s = row_ptr[wid], e = row_ptr[wid + 1];
    float2 acc = {0.0f, 0.0f};
    for (int base = s; base < e; base += 64) {
        int idx = base + lane;
        mysc[lane] = (idx < e) ? cv[idx] : 0;
        int m = e - base; if (m > 64) m = 64;
        for (int k0 = 0; k0 < m; k0 += 8) {
            #pragma unroll
            for (int j = 0; j < 8; j++) {
                long long ck = mysc[k0 + j];
                int col = (int)ck;
                float v = __int_as_float((int)(ck >> 32));
                float2 xf = __half22float2(src[(long long)col * 64 + lane]);
                acc.x += v * xf.x; acc.y += v * xf.y;
            }
        }
    }
    reinterpret_cast<float2*>(dst)[(long long)wid * 64 + lane] = acc;
}

// ---------------- round-1 fallback (atomic scatter, f32) ----------------

__global__ void bias_relu_kernel(float* __restrict__ buf, const float* __restrict__ bias,
                                 long long total) {
    long long i = ((long long)blockIdx.x * blockDim.x + threadIdx.x) * 4;
    if (i >= total) return;
    float4 v = *reinterpret_cast<float4*>(buf + i);
    int ch = (int)(i & (CH - 1));
    float4 b = *reinterpret_cast<const float4*>(bias + ch);
    v.x = fmaxf(v.x + b.x, 0.0f);
    v.y = fmaxf(v.y + b.y, 0.0f);
    v.z = fmaxf(v.z + b.z, 0.0f);
    v.w = fmaxf(v.w + b.w, 0.0f);
    *reinterpret_cast<float4*>(buf + i) = v;
}

__global__ void spmm_scatter_kernel(const int* __restrict__ rows, const int* __restrict__ cols,
                                    const float* __restrict__ vals, const float* __restrict__ weight,
                                    float* __restrict__ out, int nnz) {
    long long tid = (long long)blockIdx.x * blockDim.x + threadIdx.x;
    if (tid >= (long long)nnz * 32) return;
    int e = (int)(tid >> 5), lane = (int)(tid & 31);
    int r = rows[e], c = cols[e];
    float v = vals[e];
    const float4 w = *reinterpret_cast<const float4*>(weight + (long long)c * CH + lane * 4);
    float* dst = out + (long long)r * CH + lane * 4;
    unsafeAtomicAdd(dst + 0, v * w.x);
    unsafeAtomicAdd(dst + 1, v * w.y);
    unsafeAtomicAdd(dst + 2, v * w.z);
    unsafeAtomicAdd(dst + 3, v * w.w);
}

__global__ void prop_scatter_kernel(const int* __restrict__ rows, const int* __restrict__ cols,
                                    const float* __restrict__ vals, const float* __restrict__ src,
                                    float* __restrict__ dst, int ne) {
    long long tid = (long long)blockIdx.x * blockDim.x + threadIdx.x;
    if (tid >= (long long)ne * 32) return;
    int e = (int)(tid >> 5), lane = (int)(tid & 31);
    int r = rows[e], c = cols[e];
    float v = vals[e];
    const float4 s = *reinterpret_cast<const float4*>(src + (long long)c * CH + lane * 4);
    float* d = dst + (long long)r * CH + lane * 4;
    unsafeAtomicAdd(d + 0, v * s.x);
    unsafeAtomicAdd(d + 1, v * s.y);
    unsafeAtomicAdd(d + 2, v * s.z);
    unsafeAtomicAdd(d + 3, v * s.w);
}

// ---------------- launch ----------------

static inline size_t align64(size_t x) { return (x + 63) & ~(size_t)63; }

extern "C" void kernel_launch(void* const* d_in, const int* in_sizes, int n_in,
                              void* d_out, int out_size, void* d_ws, size_t ws_size,
                              hipStream_t stream) {
    const int*   feat_rows = (const int*)d_in[0];
    const int*   feat_cols = (const int*)d_in[1];
    const float* feat_vals = (const float*)d_in[2];
    const int*   adj_rows  = (const int*)d_in[3];
    const int*   adj_cols  = (const int*)d_in[4];
    const float* adj_vals  = (const float*)d_in[5];
    const float* weight    = (const float*)d_in[6];
    const float* bias      = (const float*)d_in[7];

    const int nnz = in_sizes[0];
    const int ne  = in_sizes[3];
    const int n   = out_size / CH;   // n_nodes
    const int in_ch = in_sizes[6] / CH;

    float* out = (float*)d_out;
    char*  ws  = (char*)d_ws;

    const size_t NBF = (size_t)n * CH * sizeof(float);
    const size_t NBH = (size_t)n * CH * sizeof(__half);
    const long long total_elems = (long long)n * CH;
    const int BLK = 256;
    const int ew_blocks = (int)((total_elems / 4 + BLK - 1) / BLK);
    const int maxe = nnz > ne ? nnz : ne;
    const int nbuck = (n + BR - 1) / BR;
    const size_t bin_lds = (size_t)nbuck * 2 * sizeof(int);

    // ws layout (fast path); cv_tmp aliases pingh (builds precede prop1 write)
    size_t off = 0;
    __half2* baseh   = (__half2*)(ws + off); off += align64(NBH);
    __half2* pingh   = (__half2*)(ws + off); off += align64(NBH);
    int*   row_ptr  = (int*)(ws + off);   off += align64(((size_t)n + 1) * 4);
    int*   bcounts  = (int*)(ws + off);   off += align64((size_t)nbuck * 4);
    int*   bcur     = (int*)(ws + off);   off += align64((size_t)nbuck * 4);
    int*   bbase    = (int*)(ws + off);   off += align64(((size_t)nbuck + 1) * 4);
    __half2* Wh     = (__half2*)(ws + off); off += align64((size_t)in_ch * 64 * 4);
    int2*  cv       = (int2*)(ws + off);  off += align64((size_t)maxe * 8);
    int2*  cv_tmp   = (int2*)pingh;       // 12.8MB inside the 25.6MB pingh buffer
    const bool fast = (ws_size >= off) && (nbuck <= SCAN_BLK) &&
                      (n <= (1 << 24)) && (bin_lds <= 64 * 1024) &&
                      (in_ch <= (1 << 22)) &&
                      ((size_t)maxe * 8 <= NBH);

    if (fast) {
        const int row_blocks = (int)(((long long)n * 64 + BLK - 1) / BLK);
        const int chunk_feat = (nnz + BIN_WGS - 1) / BIN_WGS;
        const int chunk_adj  = (ne + BIN_WGS - 1) / BIN_WGS;
        const int w2 = in_ch * 64;
        const size_t hist_lds = (size_t)nbuck * sizeof(int);

        // --- W fp16 conversion (independent of CSR build) ---
        wconv_kernel<<<(w2 + BLK - 1) / BLK, BLK, 0, stream>>>(weight, Wh, w2);

        // --- feat CSR (bucket-level build) ---
        hipMemsetAsync(bcounts, 0, (size_t)nbuck * 4, stream);
        bucket_hist_kernel<<<BIN_WGS, BIN_THR, hist_lds, stream>>>(
            feat_rows, bcounts, nnz, nbuck, chunk_feat);
        bucket_scan_kernel<<<1, SCAN_BLK, 0, stream>>>(bcounts, bcur, bbase, row_ptr + n, nbuck);
        multisplit_bin_kernel<<<BIN_WGS, BIN_THR, bin_lds, stream>>>(
            feat_rows, feat_cols, feat_vals, bcur, cv_tmp, nnz, nbuck, chunk_feat);
        reorder2_kernel<<<nbuck, BIN_THR, 0, stream>>>(bbase, cv_tmp, cv, row_ptr, n);
        // --- base = relu(SpMM(feat, W) + bias) -> baseh (f16) ---
        spmm_g4_kernel<<<row_blocks, BLK, 0, stream>>>(
            row_ptr, (const long long*)cv, Wh, bias, baseh, n);

        // --- adj CSR (cv_tmp region free until prop1 writes pingh) ---
        hipMemsetAsync(bcounts, 0, (size_t)nbuck * 4, stream);
        bucket_hist_kernel<<<BIN_WGS, BIN_THR, hist_lds, stream>>>(
            adj_rows, bcounts, ne, nbuck, chunk_adj);
        bucket_scan_kernel<<<1, SCAN_BLK, 0, stream>>>(bcounts, bcur, bbase, row_ptr + n, nbuck);
        multisplit_bin_kernel<<<BIN_WGS, BIN_THR, bin_lds, stream>>>(
            adj_rows, adj_cols, adj_vals, bcur, cv_tmp, ne, nbuck, chunk_adj);
        reorder2_kernel<<<nbuck, BIN_THR, 0, stream>>>(bbase, cv_tmp, cv, row_ptr, n);
        // --- prop x2 ---
        prop_csr_h2h_kernel<<<row_blocks, BLK, 0, stream>>>(
            row_ptr, (const long long*)cv, baseh, pingh, n);
        prop_csr_h2f_kernel<<<row_blocks, BLK, 0, stream>>>(
            row_ptr, (const long long*)cv, pingh, out, n);
    } else {
        // round-1 fallback: atomic scatter (f32)
        float* ping = (float*)ws;
        const int spmm_blocks = (int)(((long long)nnz * 32 + BLK - 1) / BLK);
        const int prop_blocks = (int)(((long long)ne * 32 + BLK - 1) / BLK);
        hipMemsetAsync(d_out, 0, NBF, stream);
        spmm_scatter_kernel<<<spmm_blocks, BLK, 0, stream>>>(feat_rows, feat_cols, feat_vals,
                                                             weight, out, nnz);
        bias_relu_kernel<<<ew_blocks, BLK, 0, stream>>>(out, bias, total_elems);
        hipMemsetAsync(ping, 0, NBF, stream);
        prop_scatter_kernel<<<prop_blocks, BLK, 0, stream>>>(adj_rows, adj_cols, adj_vals,
                                                             out, ping, ne);
        hipMemsetAsync(d_out, 0, NBF, stream);
        prop_scatter_kernel<<<prop_blocks, BLK, 0, stream>>>(adj_rows, adj_cols, adj_vals,
                                                             ping, out, ne);
    }
}

// Round 11
// 253.156 us; speedup vs baseline: 31.7413x; 1.0234x over previous
//
#include <hip/hip_runtime.h>
#include <hip/hip_fp16.h>

// SparseNGCNLayer: base = relu(SpMM(feat, W) + bias); base = A @ base (x2)
// Round 11:
//   - props converted to g4 layout (4 edges/wave-step, 16 lanes x 16B loads,
//     shfl_xor reduce): was 64x 4B loads + 42% VALU at 50% fabric.
//   - CSR build: bucket_hist persists per-(WG,bucket) counts -> wg_counts
//     (800KB, coalesced); wgscan computes per-WG subrange bases; bin drops
//     its count/reserve phases (no rows re-read, no 2nd LDS histogram).
//   - reorder2 unchanged (derives row_ptr from rlocal tags).

#define CH 128
#define BR 128            // rows per bucket (rlocal fits in 7 bits)
#define SCAN_BLK 1024
#define BIN_WGS 256       // multisplit workgroups (contiguous chunks)
#define BIN_THR 512

// ---------------- CSR build ----------------

// K1: per-WG LDS histogram; writes per-(WG,bucket) counts (coalesced lines)
__global__ void bucket_hist_kernel(const int* __restrict__ rows, int* __restrict__ wg_counts,
                                   int nE, int nbuck, int chunk) {
    extern __shared__ int hcnt[];
    const int tid = threadIdx.x;
    const long long T = blockDim.x;
    long long start = (long long)blockIdx.x * chunk;
    long long end = start + chunk;
    if (end > nE) end = nE;
    for (int b = tid; b < nbuck; b += blockDim.x) hcnt[b] = 0;
    __syncthreads();
    if (start < end) {
        long long i = start + tid;
        for (; i + 3 * T < end; i += 4 * T) {
            int r0 = rows[i], r1 = rows[i + T], r2 = rows[i + 2 * T], r3 = rows[i + 3 * T];
            atomicAdd(&hcnt[r0 >> 7], 1);
            atomicAdd(&hcnt[r1 >> 7], 1);
            atomicAdd(&hcnt[r2 >> 7], 1);
            atomicAdd(&hcnt[r3 >> 7], 1);
        }
        for (; i < end; i += T) atomicAdd(&hcnt[rows[i] >> 7], 1);
    }
    __syncthreads();
    for (int b = tid; b < nbuck; b += blockDim.x)
        wg_counts[(long long)blockIdx.x * nbuck + b] = hcnt[b];
}

// K1b: per-bucket exclusive scan across the WG dimension (in place);
// bcounts[b] = bucket total. One wave per bucket.
__global__ void wgscan_kernel(int* __restrict__ wg_counts, int* __restrict__ bcounts,
                              int nbuck, int nwg) {
    int b = blockIdx.x * (blockDim.x >> 6) + (threadIdx.x >> 6);
    int lane = threadIdx.x & 63;
    if (b >= nbuck) return;
    int carry = 0;
    for (int base = 0; base < nwg; base += 64) {
        int wg = base + lane;
        int v = (wg < nwg) ? wg_counts[(long long)wg * nbuck + b] : 0;
        int x = v;
        #pragma unroll
        for (int off = 1; off < 64; off <<= 1) {
            int y = __shfl_up(x, off);
            if (lane >= off) x += y;
        }
        if (wg < nwg) wg_counts[(long long)wg * nbuck + b] = carry + x - v; // exclusive
        carry += __shfl(x, 63);
    }
    if (lane == 0) bcounts[b] = carry;
}

// K2: single-WG scan of bucket totals -> bucket_base[0..nbuck], row_ptr[n]=total
__global__ void bucket_scan_kernel(const int* __restrict__ bcounts,
                                   int* __restrict__ bucket_base, int* __restrict__ row_ptr_n,
                                   int nbuck) {
    __shared__ int lds[SCAN_BLK];
    int tid = threadIdx.x;
    int x = (tid < nbuck) ? bcounts[tid] : 0;
    lds[tid] = x;
    __syncthreads();
    for (int off = 1; off < SCAN_BLK; off <<= 1) {
        int y = (tid >= off) ? lds[tid - off] : 0;
        __syncthreads();
        lds[tid] += y;
        __syncthreads();
    }
    if (tid < nbuck) bucket_base[tid] = lds[tid] - x;
    if (tid == nbuck - 1) {
        bucket_base[nbuck] = lds[tid];
        *row_ptr_n = lds[tid];
    }
}

// K3: scatter into precomputed WG-private subranges (no count/reserve phases).
// rlocal packed into col bits [24:31).
__global__ void multisplit_bin_kernel(const int* __restrict__ rows, const int* __restrict__ cols,
                                      const float* __restrict__ vals,
                                      const int* __restrict__ bbase,
                                      const int* __restrict__ wg_counts,
                                      int2* __restrict__ cv_tmp, int nE, int nbuck, int chunk) {
    extern __shared__ int lds[];
    int* hcnt  = lds;            // [nbuck] local cursors
    int* hbase = lds + nbuck;    // [nbuck] this WG's subrange bases
    const int tid = threadIdx.x;
    const long long T = blockDim.x;
    long long start = (long long)blockIdx.x * chunk;
    long long end = start + chunk;
    if (end > nE) end = nE;
    for (int b = tid; b < nbuck; b += blockDim.x) {
        hbase[b] = bbase[b] + wg_counts[(long long)blockIdx.x * nbuck + b];
        hcnt[b] = 0;
    }
    __syncthreads();
    if (start >= end) return;
    long long i = start + tid;
    for (; i + 3 * T < end; i += 4 * T) {
        int r0 = rows[i], r1 = rows[i + T], r2 = rows[i + 2 * T], r3 = rows[i + 3 * T];
        int c0 = cols[i], c1 = cols[i + T], c2 = cols[i + 2 * T], c3 = cols[i + 3 * T];
        float v0 = vals[i], v1 = vals[i + T], v2 = vals[i + 2 * T], v3 = vals[i + 3 * T];
        int b0 = r0 >> 7, b1 = r1 >> 7, b2 = r2 >> 7, b3 = r3 >> 7;
        int p0 = hbase[b0] + atomicAdd(&hcnt[b0], 1);
        int p1 = hbase[b1] + atomicAdd(&hcnt[b1], 1);
        int p2 = hbase[b2] + atomicAdd(&hcnt[b2], 1);
        int p3 = hbase[b3] + atomicAdd(&hcnt[b3], 1);
        cv_tmp[p0] = make_int2(c0 | ((r0 & (BR - 1)) << 24), __float_as_int(v0));
        cv_tmp[p1] = make_int2(c1 | ((r1 & (BR - 1)) << 24), __float_as_int(v1));
        cv_tmp[p2] = make_int2(c2 | ((r2 & (BR - 1)) << 24), __float_as_int(v2));
        cv_tmp[p3] = make_int2(c3 | ((r3 & (BR - 1)) << 24), __float_as_int(v3));
    }
    for (; i < end; i += T) {
        int r = rows[i];
        int b = r >> 7;
        int p = hbase[b] + atomicAdd(&hcnt[b], 1);
        cv_tmp[p] = make_int2(cols[i] | ((r & (BR - 1)) << 24), __float_as_int(vals[i]));
    }
}

// K4: reorder within bucket; derives per-row counts/offsets from rlocal tags,
// writes row_ptr for its 128 rows, then scatters into row-sorted cv.
__global__ void reorder2_kernel(const int* __restrict__ bucket_base,
                                const int2* __restrict__ cv_tmp, int2* __restrict__ cv,
                                int* __restrict__ row_ptr, int n) {
    __shared__ int cnt[BR];
    __shared__ int tmp[BR];
    int b = blockIdx.x;
    int rbase = b * BR;
    int tid = threadIdx.x;
    int s = bucket_base[b], e = bucket_base[b + 1];
    if (tid < BR) cnt[tid] = 0;
    __syncthreads();
    for (int i = s + tid; i < e; i += blockDim.x)
        atomicAdd(&cnt[((unsigned)cv_tmp[i].x) >> 24], 1);
    __syncthreads();
    if (tid < BR) tmp[tid] = cnt[tid];
    __syncthreads();
    for (int off = 1; off < BR; off <<= 1) {
        int y = 0;
        if (tid < BR && tid >= off) y = tmp[tid - off];
        __syncthreads();
        if (tid < BR) tmp[tid] += y;
        __syncthreads();
    }
    if (tid < BR) {
        int excl = s + tmp[tid] - cnt[tid];
        if (rbase + tid < n) row_ptr[rbase + tid] = excl;
        cnt[tid] = excl;       // becomes the scatter cursor
    }
    __syncthreads();
    for (int i = s + tid; i < e; i += blockDim.x) {
        int2 ent = cv_tmp[i];
        int rl = ((unsigned)ent.x) >> 24;
        int p = atomicAdd(&cnt[rl], 1);
        cv[p] = make_int2(ent.x & 0x00FFFFFF, ent.y);
    }
}

// ---------------- W fp16 conversion ----------------

__global__ void wconv_kernel(const float* __restrict__ W, __half2* __restrict__ Wh, int n2) {
    int i = blockIdx.x * blockDim.x + threadIdx.x;
    if (i < n2) Wh[i] = __float22half2_rn(reinterpret_cast<const float2*>(W)[i]);
}

// ---------------- gather-reduce row kernels (g4 layout) ----------------
// 4 edge-groups per wave (g = lane>>4), 16 lanes x 16B cover a 128ch f16 row.
// CSR entries via wave-private LDS scratch; zero-filled lanes self-mask.

__global__ void spmm_g4_kernel(const int* __restrict__ row_ptr,
                               const long long* __restrict__ cv,
                               const __half2* __restrict__ Wh,   // [in_ch][64] half2
                               const float* __restrict__ bias,
                               __half2* __restrict__ outh, int n) {
    __shared__ long long sc[4 * 64];
    int gtid = blockIdx.x * blockDim.x + threadIdx.x;
    int wid = gtid >> 6;
    int lane = gtid & 63;
    if (wid >= n) return;
    int g = lane >> 4;
    int cl = lane & 15;
    long long* mysc = sc + (threadIdx.x >> 6) * 64;
    int s = row_ptr[wid], e = row_ptr[wid + 1];
    float acc0 = 0.f, acc1 = 0.f, acc2 = 0.f, acc3 = 0.f;
    float acc4 = 0.f, acc5 = 0.f, acc6 = 0.f, acc7 = 0.f;
    for (int base = s; base < e; base += 64) {
        int idx = base + lane;
        mysc[lane] = (idx < e) ? cv[idx] : 0;
        int m = e - base; if (m > 64) m = 64;
        for (int k0 = 0; k0 < m; k0 += 4) {
            long long ck = mysc[k0 + g];
            int col = (int)ck;
            float v = __int_as_float((int)(ck >> 32));
            float4 wv = *reinterpret_cast<const float4*>(Wh + (long long)col * 64 + cl * 4);
            float2 f0 = __half22float2(*reinterpret_cast<const __half2*>(&wv.x));
            float2 f1 = __half22float2(*reinterpret_cast<const __half2*>(&wv.y));
            float2 f2 = __half22float2(*reinterpret_cast<const __half2*>(&wv.z));
            float2 f3 = __half22float2(*reinterpret_cast<const __half2*>(&wv.w));
            acc0 += v * f0.x; acc1 += v * f0.y;
            acc2 += v * f1.x; acc3 += v * f1.y;
            acc4 += v * f2.x; acc5 += v * f2.y;
            acc6 += v * f3.x; acc7 += v * f3.y;
        }
    }
    acc0 += __shfl_xor(acc0, 16); acc1 += __shfl_xor(acc1, 16);
    acc2 += __shfl_xor(acc2, 16); acc3 += __shfl_xor(acc3, 16);
    acc4 += __shfl_xor(acc4, 16); acc5 += __shfl_xor(acc5, 16);
    acc6 += __shfl_xor(acc6, 16); acc7 += __shfl_xor(acc7, 16);
    acc0 += __shfl_xor(acc0, 32); acc1 += __shfl_xor(acc1, 32);
    acc2 += __shfl_xor(acc2, 32); acc3 += __shfl_xor(acc3, 32);
    acc4 += __shfl_xor(acc4, 32); acc5 += __shfl_xor(acc5, 32);
    acc6 += __shfl_xor(acc6, 32); acc7 += __shfl_xor(acc7, 32);
    if (g == 0) {
        const float4* bp = reinterpret_cast<const float4*>(bias);
        float4 b0 = bp[cl * 2], b1 = bp[cl * 2 + 1];
        acc0 = fmaxf(acc0 + b0.x, 0.f); acc1 = fmaxf(acc1 + b0.y, 0.f);
        acc2 = fmaxf(acc2 + b0.z, 0.f); acc3 = fmaxf(acc3 + b0.w, 0.f);
        acc4 = fmaxf(acc4 + b1.x, 0.f); acc5 = fmaxf(acc5 + b1.y, 0.f);
        acc6 = fmaxf(acc6 + b1.z, 0.f); acc7 = fmaxf(acc7 + b1.w, 0.f);
        __half2 h0 = __floats2half2_rn(acc0, acc1);
        __half2 h1 = __floats2half2_rn(acc2, acc3);
        __half2 h2 = __floats2half2_rn(acc4, acc5);
        __half2 h3 = __floats2half2_rn(acc6, acc7);
        float4 ov;
        *reinterpret_cast<__half2*>(&ov.x) = h0;
        *reinterpret_cast<__half2*>(&ov.y) = h1;
        *reinterpret_cast<__half2*>(&ov.z) = h2;
        *reinterpret_cast<__half2*>(&ov.w) = h3;
        *reinterpret_cast<float4*>(outh + (long long)wid * 64 + cl * 4) = ov;
    }
}

__global__ void prop_g4_h2h_kernel(const int* __restrict__ row_ptr,
                                   const long long* __restrict__ cv,
                                   const __half2* __restrict__ src, __half2* __restrict__ dst,
                                   int n) {
    __shared__ long long sc[4 * 64];
    int gtid = blockIdx.x * blockDim.x + threadIdx.x;
    int wid = gtid >> 6;
    int lane = gtid & 63;
    if (wid >= n) return;
    int g = lane >> 4;
    int cl = lane & 15;
    long long* mysc = sc + (threadIdx.x >> 6) * 64;
    int s = row_ptr[wid], e = row_ptr[wid + 1];
    float acc0 = 0.f, acc1 = 0.f, acc2 = 0.f, acc3 = 0.f;
    float acc4 = 0.f, acc5 = 0.f, acc6 = 0.f, acc7 = 0.f;
    for (int base = s; base < e; base += 64) {
        int idx = base + lane;
        mysc[lane] = (idx < e) ? cv[idx] : 0;
        int m = e - base; if (m > 64) m = 64;
        for (int k0 = 0; k0 < m; k0 += 4) {
            long long ck = mysc[k0 + g];
            int col = (int)ck;
            float v = __int_as_float((int)(ck >> 32));
            float4 sv = *reinterpret_cast<const float4*>(src + (long long)col * 64 + cl * 4);
            float2 f0 = __half22float2(*reinterpret_cast<const __half2*>(&sv.x));
            float2 f1 = __half22float2(*reinterpret_cast<const __half2*>(&sv.y));
            float2 f2 = __half22float2(*reinterpret_cast<const __half2*>(&sv.z));
            float2 f3 = __half22float2(*reinterpret_cast<const __half2*>(&sv.w));
            acc0 += v * f0.x; acc1 += v * f0.y;
            acc2 += v * f1.x; acc3 += v * f1.y;
            acc4 += v * f2.x; acc5 += v * f2.y;
            acc6 += v * f3.x; acc7 += v * f3.y;
        }
    }
    acc0 += __shfl_xor(acc0, 16); acc1 += __shfl_xor(acc1, 16);
    acc2 += __shfl_xor(acc2, 16); acc3 += __shfl_xor(acc3, 16);
    acc4 += __shfl_xor(acc4, 16); acc5 += __shfl_xor(acc5, 16);
    acc6 += __shfl_xor(acc6, 16); acc7 += __shfl_xor(acc7, 16);
    acc0 += __shfl_xor(acc0, 32); acc1 += __shfl_xor(acc1, 32);
    acc2 += __shfl_xor(acc2, 32); acc3 += __shfl_xor(acc3, 32);
    acc4 += __shfl_xor(acc4, 32); acc5 += __shfl_xor(acc5, 32);
    acc6 += __shfl_xor(acc6, 32); acc7 += __shfl_xor(acc7, 32);
    if (g == 0) {
        __half2 h0 = __floats2half2_rn(acc0, acc1);
        __half2 h1 = __floats2half2_rn(acc2, acc3);
        __half2 h2 = __floats2half2_rn(acc4, acc5);
        __half2 h3 = __floats2half2_rn(acc6, acc7);
        float4 ov;
        *reinterpret_cast<__half2*>(&ov.x) = h0;
        *reinterpret_cast<__half2*>(&ov.y) = h1;
        *reinterpret_cast<__half2*>(&ov.z) = h2;
        *reinterpret_cast<__half2*>(&ov.w) = h3;
        *reinterpret_cast<float4*>(dst + (long long)wid * 64 + cl * 4) = ov;
    }
}

__global__ void prop_g4_h2f_kernel(const int* __restrict__ row_ptr,
                                   const long long* __restrict__ cv,
                                   const __half2* __restrict__ src, float* __restrict__ dst,
                                   int n) {
    __shared__ long long sc[4 * 64];
    int gtid = blockIdx.x * blockDim.x + threadIdx.x;
    int wid = gtid >> 6;
    int lane = gtid & 63;
    if (wid >= n) return;
    int g = lane >> 4;
    int cl = lane & 15;
    long long* mysc = sc + (threadIdx.x >> 6) * 64;
    int s = row_ptr[wid], e = row_ptr[wid + 1];
    float acc0 = 0.f, acc1 = 0.f, acc2 = 0.f, acc3 = 0.f;
    float acc4 = 0.f, acc5 = 0.f, acc6 = 0.f, acc7 = 0.f;
    for (int base = s; base < e; base += 64) {
        int idx = base + lane;
        mysc[lane] = (idx < e) ? cv[idx] : 0;
        int m = e - base; if (m > 64) m = 64;
        for (int k0 = 0; k0 < m; k0 += 4) {
            long long ck = mysc[k0 + g];
            int col = (int)ck;
            float v = __int_as_float((int)(ck >> 32));
            float4 sv = *reinterpret_cast<const float4*>(src + (long long)col * 64 + cl * 4);
            float2 f0 = __half22float2(*reinterpret_cast<const __half2*>(&sv.x));
            float2 f1 = __half22float2(*reinterpret_cast<const __half2*>(&sv.y));
            float2 f2 = __half22float2(*reinterpret_cast<const __half2*>(&sv.z));
            float2 f3 = __half22float2(*reinterpret_cast<const __half2*>(&sv.w));
            acc0 += v * f0.x; acc1 += v * f0.y;
            acc2 += v * f1.x; acc3 += v * f1.y;
            acc4 += v * f2.x; acc5 += v * f2.y;
            acc6 += v * f3.x; acc7 += v * f3.y;
        }
    }
    acc0 += __shfl_xor(acc0, 16); acc1 += __shfl_xor(acc1, 16);
    acc2 += __shfl_xor(acc2, 16); acc3 += __shfl_xor(acc3, 16);
    acc4 += __shfl_xor(acc4, 16); acc5 += __shfl_xor(acc5, 16);
    acc6 += __shfl_xor(acc6, 16); acc7 += __shfl_xor(acc7, 16);
    acc0 += __shfl_xor(acc0, 32); acc1 += __shfl_xor(acc1, 32);
    acc2 += __shfl_xor(acc2, 32); acc3 += __shfl_xor(acc3, 32);
    acc4 += __shfl_xor(acc4, 32); acc5 += __shfl_xor(acc5, 32);
    acc6 += __shfl_xor(acc6, 32); acc7 += __shfl_xor(acc7, 32);
    if (g == 0) {
        float4 o0 = make_float4(acc0, acc1, acc2, acc3);
        float4 o1 = make_float4(acc4, acc5, acc6, acc7);
        float4* dp = reinterpret_cast<float4*>(dst + (long long)wid * 128 + cl * 8);
        dp[0] = o0;
        dp[1] = o1;
    }
}

// ---------------- round-1 fallback (atomic scatter, f32) ----------------

__global__ void bias_relu_kernel(float* __restrict__ buf, const float* __restrict__ bias,
                                 long long total) {
    long long i = ((long long)blockIdx.x * blockDim.x + threadIdx.x) * 4;
    if (i >= total) return;
    float4 v = *reinterpret_cast<float4*>(buf + i);
    int ch = (int)(i & (CH - 1));
    float4 b = *reinterpret_cast<const float4*>(bias + ch);
    v.x = fmaxf(v.x + b.x, 0.0f);
    v.y = fmaxf(v.y + b.y, 0.0f);
    v.z = fmaxf(v.z + b.z, 0.0f);
    v.w = fmaxf(v.w + b.w, 0.0f);
    *reinterpret_cast<float4*>(buf + i) = v;
}

__global__ void spmm_scatter_kernel(const int* __restrict__ rows, const int* __restrict__ cols,
                                    const float* __restrict__ vals, const float* __restrict__ weight,
                                    float* __restrict__ out, int nnz) {
    long long tid = (long long)blockIdx.x * blockDim.x + threadIdx.x;
    if (tid >= (long long)nnz * 32) return;
    int e = (int)(tid >> 5), lane = (int)(tid & 31);
    int r = rows[e], c = cols[e];
    float v = vals[e];
    const float4 w = *reinterpret_cast<const float4*>(weight + (long long)c * CH + lane * 4);
    float* dst = out + (long long)r * CH + lane * 4;
    unsafeAtomicAdd(dst + 0, v * w.x);
    unsafeAtomicAdd(dst + 1, v * w.y);
    unsafeAtomicAdd(dst + 2, v * w.z);
    unsafeAtomicAdd(dst + 3, v * w.w);
}

__global__ void prop_scatter_kernel(const int* __restrict__ rows, const int* __restrict__ cols,
                                    const float* __restrict__ vals, const float* __restrict__ src,
                                    float* __restrict__ dst, int ne) {
    long long tid = (long long)blockIdx.x * blockDim.x + threadIdx.x;
    if (tid >= (long long)ne * 32) return;
    int e = (int)(tid >> 5), lane = (int)(tid & 31);
    int r = rows[e], c = cols[e];
    float v = vals[e];
    const float4 s = *reinterpret_cast<const float4*>(src + (long long)c * CH + lane * 4);
    float* d = dst + (long long)r * CH + lane * 4;
    unsafeAtomicAdd(d + 0, v * s.x);
    unsafeAtomicAdd(d + 1, v * s.y);
    unsafeAtomicAdd(d + 2, v * s.z);
    unsafeAtomicAdd(d + 3, v * s.w);
}

// ---------------- launch ----------------

static inline size_t align64(size_t x) { return (x + 63) & ~(size_t)63; }

extern "C" void kernel_launch(void* const* d_in, const int* in_sizes, int n_in,
                              void* d_out, int out_size, void* d_ws, size_t ws_size,
                              hipStream_t stream) {
    const int*   feat_rows = (const int*)d_in[0];
    const int*   feat_cols = (const int*)d_in[1];
    const float* feat_vals = (const float*)d_in[2];
    const int*   adj_rows  = (const int*)d_in[3];
    const int*   adj_cols  = (const int*)d_in[4];
    const float* adj_vals  = (const float*)d_in[5];
    const float* weight    = (const float*)d_in[6];
    const float* bias      = (const float*)d_in[7];

    const int nnz = in_sizes[0];
    const int ne  = in_sizes[3];
    const int n   = out_size / CH;   // n_nodes
    const int in_ch = in_sizes[6] / CH;

    float* out = (float*)d_out;
    char*  ws  = (char*)d_ws;

    const size_t NBF = (size_t)n * CH * sizeof(float);
    const size_t NBH = (size_t)n * CH * sizeof(__half);
    const long long total_elems = (long long)n * CH;
    const int BLK = 256;
    const int ew_blocks = (int)((total_elems / 4 + BLK - 1) / BLK);
    const int maxe = nnz > ne ? nnz : ne;
    const int nbuck = (n + BR - 1) / BR;
    const size_t bin_lds = (size_t)nbuck * 2 * sizeof(int);

    // ws layout (fast path); cv_tmp aliases pingh (builds precede prop1 write)
    size_t off = 0;
    __half2* baseh    = (__half2*)(ws + off); off += align64(NBH);
    __half2* pingh    = (__half2*)(ws + off); off += align64(NBH);
    int*   row_ptr   = (int*)(ws + off);   off += align64(((size_t)n + 1) * 4);
    int*   bcounts   = (int*)(ws + off);   off += align64((size_t)nbuck * 4);
    int*   bbase     = (int*)(ws + off);   off += align64(((size_t)nbuck + 1) * 4);
    int*   wg_counts = (int*)(ws + off);   off += align64((size_t)BIN_WGS * nbuck * 4);
    __half2* Wh      = (__half2*)(ws + off); off += align64((size_t)in_ch * 64 * 4);
    int2*  cv        = (int2*)(ws + off);  off += align64((size_t)maxe * 8);
    int2*  cv_tmp    = (int2*)pingh;       // 12.8MB inside the 25.6MB pingh buffer
    const bool fast = (ws_size >= off) && (nbuck <= SCAN_BLK) &&
                      (n <= (1 << 24)) && (bin_lds <= 64 * 1024) &&
                      (in_ch <= (1 << 22)) &&
                      ((size_t)maxe * 8 <= NBH);

    if (fast) {
        const int row_blocks = (int)(((long long)n * 64 + BLK - 1) / BLK);
        const int chunk_feat = (nnz + BIN_WGS - 1) / BIN_WGS;
        const int chunk_adj  = (ne + BIN_WGS - 1) / BIN_WGS;
        const int w2 = in_ch * 64;
        const size_t hist_lds = (size_t)nbuck * sizeof(int);
        const int wgscan_blocks = (nbuck + 3) / 4;

        // --- W fp16 conversion (independent of CSR build) ---
        wconv_kernel<<<(w2 + BLK - 1) / BLK, BLK, 0, stream>>>(weight, Wh, w2);

        // --- feat CSR (bucket-level build) ---
        bucket_hist_kernel<<<BIN_WGS, BIN_THR, hist_lds, stream>>>(
            feat_rows, wg_counts, nnz, nbuck, chunk_feat);
        wgscan_kernel<<<wgscan_blocks, 256, 0, stream>>>(wg_counts, bcounts, nbuck, BIN_WGS);
        bucket_scan_kernel<<<1, SCAN_BLK, 0, stream>>>(bcounts, bbase, row_ptr + n, nbuck);
        multisplit_bin_kernel<<<BIN_WGS, BIN_THR, bin_lds, stream>>>(
            feat_rows, feat_cols, feat_vals, bbase, wg_counts, cv_tmp, nnz, nbuck, chunk_feat);
        reorder2_kernel<<<nbuck, BIN_THR, 0, stream>>>(bbase, cv_tmp, cv, row_ptr, n);
        // --- base = relu(SpMM(feat, W) + bias) -> baseh (f16) ---
        spmm_g4_kernel<<<row_blocks, BLK, 0, stream>>>(
            row_ptr, (const long long*)cv, Wh, bias, baseh, n);

        // --- adj CSR (cv_tmp region free until prop1 writes pingh) ---
        bucket_hist_kernel<<<BIN_WGS, BIN_THR, hist_lds, stream>>>(
            adj_rows, wg_counts, ne, nbuck, chunk_adj);
        wgscan_kernel<<<wgscan_blocks, 256, 0, stream>>>(wg_counts, bcounts, nbuck, BIN_WGS);
        bucket_scan_kernel<<<1, SCAN_BLK, 0, stream>>>(bcounts, bbase, row_ptr + n, nbuck);
        multisplit_bin_kernel<<<BIN_WGS, BIN_THR, bin_lds, stream>>>(
            adj_rows, adj_cols, adj_vals, bbase, wg_counts, cv_tmp, ne, nbuck, chunk_adj);
        reorder2_kernel<<<nbuck, BIN_THR, 0, stream>>>(bbase, cv_tmp, cv, row_ptr, n);
        // --- prop x2 (g4 layout) ---
        prop_g4_h2h_kernel<<<row_blocks, BLK, 0, stream>>>(
            row_ptr, (const long long*)cv, baseh, pingh, n);
        prop_g4_h2f_kernel<<<row_blocks, BLK, 0, stream>>>(
            row_ptr, (const long long*)cv, pingh, out, n);
    } else {
        // round-1 fallback: atomic scatter (f32)
        float* ping = (float*)ws;
        const int spmm_blocks = (int)(((long long)nnz * 32 + BLK - 1) / BLK);
        const int prop_blocks = (int)(((long long)ne * 32 + BLK - 1) / BLK);
        hipMemsetAsync(d_out, 0, NBF, stream);
        spmm_scatter_kernel<<<spmm_blocks, BLK, 0, stream>>>(feat_rows, feat_cols, feat_vals,
                                                             weight, out, nnz);
        bias_relu_kernel<<<ew_blocks, BLK, 0, stream>>>(out, bias, total_elems);
        hipMemsetAsync(ping, 0, NBF, stream);
        prop_scatter_kernel<<<prop_blocks, BLK, 0, stream>>>(adj_rows, adj_cols, adj_vals,
                                                             out, ping, ne);
        hipMemsetAsync(d_out, 0, NBF, stream);
        prop_scatter_kernel<<<prop_blocks, BLK, 0, stream>>>(adj_rows, adj_cols, adj_vals,
                                                             ping, out, ne);
    }
}

// Round 12
// 246.108 us; speedup vs baseline: 32.6503x; 1.0286x over previous
//
#include <hip/hip_runtime.h>
#include <hip/hip_fp16.h>

// SparseNGCNLayer: base = relu(SpMM(feat, W) + bias); base = A @ base (x2)
// Round 12:
//   - merged CSR builds: hist2/wgscan2/bucket_scan2/bin2 each handle BOTH
//     matrices in one launch (2x parallelism for latency-bound phases,
//     4 fewer launches). cv_tmp_feat/adj = lo/hi halves of pingh.
//   - reorder runs per matrix around spmm so cv + row_ptr are reused
//     (ws stays at 66.1MB, under round-11's proven 66.6MB).
//   - gather kernels: #pragma unroll 4 on the edge loop -> 4 independent
//     dwordx4 gathers in flight per wave (props are L3-miss-BW/latency bound).

#define CH 128
#define BR 128            // rows per bucket (rlocal fits in 7 bits)
#define SCAN_BLK 1024
#define BIN_WGS 256       // multisplit workgroups per matrix
#define BIN_THR 512

// ---------------- CSR build (merged feat+adj) ----------------

// K1: per-WG LDS histogram for matrix m = blockIdx>>8, chunk wg = blockIdx&255.
__global__ void hist2_kernel(const int* __restrict__ rows_f, int nf, int chunk_f,
                             const int* __restrict__ rows_a, int na, int chunk_a,
                             int* __restrict__ wgc, int nbuck) {
    extern __shared__ int hcnt[];
    const int m  = blockIdx.x >> 8;
    const int wg = blockIdx.x & (BIN_WGS - 1);
    const int* rows = m ? rows_a : rows_f;
    const int nE    = m ? na : nf;
    const int chunk = m ? chunk_a : chunk_f;
    const int tid = threadIdx.x;
    const long long T = blockDim.x;
    long long start = (long long)wg * chunk;
    long long end = start + chunk;
    if (end > nE) end = nE;
    for (int b = tid; b < nbuck; b += blockDim.x) hcnt[b] = 0;
    __syncthreads();
    if (start < end) {
        long long i = start + tid;
        for (; i + 3 * T < end; i += 4 * T) {
            int r0 = rows[i], r1 = rows[i + T], r2 = rows[i + 2 * T], r3 = rows[i + 3 * T];
            atomicAdd(&hcnt[r0 >> 7], 1);
            atomicAdd(&hcnt[r1 >> 7], 1);
            atomicAdd(&hcnt[r2 >> 7], 1);
            atomicAdd(&hcnt[r3 >> 7], 1);
        }
        for (; i < end; i += T) atomicAdd(&hcnt[rows[i] >> 7], 1);
    }
    __syncthreads();
    int* out = wgc + ((long long)m * BIN_WGS + wg) * nbuck;
    for (int b = tid; b < nbuck; b += blockDim.x) out[b] = hcnt[b];
}

// K1b: per-(matrix,bucket) exclusive scan across the WG dimension (in place).
__global__ void wgscan2_kernel(int* __restrict__ wgc, int* __restrict__ bcounts,
                               int nbuck, int nwg) {
    int wpb = blockDim.x >> 6;
    int idx = blockIdx.x * wpb + (threadIdx.x >> 6);
    int lane = threadIdx.x & 63;
    if (idx >= 2 * nbuck) return;
    int m = (idx >= nbuck) ? 1 : 0;
    int b = idx - m * nbuck;
    int* base = wgc + (long long)m * nwg * nbuck + b;
    int carry = 0;
    for (int w0 = 0; w0 < nwg; w0 += 64) {
        int wg = w0 + lane;
        int v = (wg < nwg) ? base[(long long)wg * nbuck] : 0;
        int x = v;
        #pragma unroll
        for (int off = 1; off < 64; off <<= 1) {
            int y = __shfl_up(x, off);
            if (lane >= off) x += y;
        }
        if (wg < nwg) base[(long long)wg * nbuck] = carry + x - v;  // exclusive
        carry += __shfl(x, 63);
    }
    if (lane == 0) bcounts[idx] = carry;
}

// K2: bucket-total scan, one block per matrix -> bbase[m][0..nbuck]
__global__ void bucket_scan2_kernel(const int* __restrict__ bcounts,
                                    int* __restrict__ bbase, int nbuck) {
    __shared__ int lds[SCAN_BLK];
    int m = blockIdx.x;
    int tid = threadIdx.x;
    int x = (tid < nbuck) ? bcounts[m * nbuck + tid] : 0;
    lds[tid] = x;
    __syncthreads();
    for (int off = 1; off < SCAN_BLK; off <<= 1) {
        int y = (tid >= off) ? lds[tid - off] : 0;
        __syncthreads();
        lds[tid] += y;
        __syncthreads();
    }
    int* bb = bbase + m * (nbuck + 1);
    if (tid < nbuck) bb[tid] = lds[tid] - x;
    if (tid == nbuck - 1) bb[nbuck] = lds[tid];
}

// K3: scatter into precomputed WG-private subranges; both matrices.
// rlocal packed into col bits [24:31).
__global__ void bin2_kernel(const int* __restrict__ rows_f, const int* __restrict__ cols_f,
                            const float* __restrict__ vals_f, int nf, int chunk_f,
                            const int* __restrict__ rows_a, const int* __restrict__ cols_a,
                            const float* __restrict__ vals_a, int na, int chunk_a,
                            const int* __restrict__ bbase, const int* __restrict__ wgc,
                            int2* __restrict__ cvt_f, int2* __restrict__ cvt_a, int nbuck) {
    extern __shared__ int lds[];
    int* hcnt  = lds;            // [nbuck] local cursors
    int* hbase = lds + nbuck;    // [nbuck] this WG's subrange bases
    const int m  = blockIdx.x >> 8;
    const int wg = blockIdx.x & (BIN_WGS - 1);
    const int* rows = m ? rows_a : rows_f;
    const int* cols = m ? cols_a : cols_f;
    const float* vals = m ? vals_a : vals_f;
    const int nE    = m ? na : nf;
    const int chunk = m ? chunk_a : chunk_f;
    int2* cv_tmp = m ? cvt_a : cvt_f;
    const int* bb = bbase + m * (nbuck + 1);
    const int* wc = wgc + ((long long)m * BIN_WGS + wg) * nbuck;
    const int tid = threadIdx.x;
    const long long T = blockDim.x;
    long long start = (long long)wg * chunk;
    long long end = start + chunk;
    if (end > nE) end = nE;
    for (int b = tid; b < nbuck; b += blockDim.x) {
        hbase[b] = bb[b] + wc[b];
        hcnt[b] = 0;
    }
    __syncthreads();
    if (start >= end) return;
    long long i = start + tid;
    for (; i + 3 * T < end; i += 4 * T) {
        int r0 = rows[i], r1 = rows[i + T], r2 = rows[i + 2 * T], r3 = rows[i + 3 * T];
        int c0 = cols[i], c1 = cols[i + T], c2 = cols[i + 2 * T], c3 = cols[i + 3 * T];
        float v0 = vals[i], v1 = vals[i + T], v2 = vals[i + 2 * T], v3 = vals[i + 3 * T];
        int b0 = r0 >> 7, b1 = r1 >> 7, b2 = r2 >> 7, b3 = r3 >> 7;
        int p0 = hbase[b0] + atomicAdd(&hcnt[b0], 1);
        int p1 = hbase[b1] + atomicAdd(&hcnt[b1], 1);
        int p2 = hbase[b2] + atomicAdd(&hcnt[b2], 1);
        int p3 = hbase[b3] + atomicAdd(&hcnt[b3], 1);
        cv_tmp[p0] = make_int2(c0 | ((r0 & (BR - 1)) << 24), __float_as_int(v0));
        cv_tmp[p1] = make_int2(c1 | ((r1 & (BR - 1)) << 24), __float_as_int(v1));
        cv_tmp[p2] = make_int2(c2 | ((r2 & (BR - 1)) << 24), __float_as_int(v2));
        cv_tmp[p3] = make_int2(c3 | ((r3 & (BR - 1)) << 24), __float_as_int(v3));
    }
    for (; i < end; i += T) {
        int r = rows[i];
        int b = r >> 7;
        int p = hbase[b] + atomicAdd(&hcnt[b], 1);
        cv_tmp[p] = make_int2(cols[i] | ((r & (BR - 1)) << 24), __float_as_int(vals[i]));
    }
}

// K4: reorder within bucket; derives per-row offsets from rlocal tags,
// writes row_ptr for its 128 rows (+ row_ptr[n] in the last bucket).
__global__ void reorder2_kernel(const int* __restrict__ bucket_base,
                                const int2* __restrict__ cv_tmp, int2* __restrict__ cv,
                                int* __restrict__ row_ptr, int n) {
    __shared__ int cnt[BR];
    __shared__ int tmp[BR];
    int b = blockIdx.x;
    int rbase = b * BR;
    int tid = threadIdx.x;
    int s = bucket_base[b], e = bucket_base[b + 1];
    if (tid < BR) cnt[tid] = 0;
    __syncthreads();
    for (int i = s + tid; i < e; i += blockDim.x)
        atomicAdd(&cnt[((unsigned)cv_tmp[i].x) >> 24], 1);
    __syncthreads();
    if (tid < BR) tmp[tid] = cnt[tid];
    __syncthreads();
    for (int off = 1; off < BR; off <<= 1) {
        int y = 0;
        if (tid < BR && tid >= off) y = tmp[tid - off];
        __syncthreads();
        if (tid < BR) tmp[tid] += y;
        __syncthreads();
    }
    if (tid < BR) {
        int excl = s + tmp[tid] - cnt[tid];
        if (rbase + tid < n) row_ptr[rbase + tid] = excl;
        cnt[tid] = excl;       // becomes the scatter cursor
    }
    if (tid == 0 && b == gridDim.x - 1) row_ptr[n] = e;
    __syncthreads();
    for (int i = s + tid; i < e; i += blockDim.x) {
        int2 ent = cv_tmp[i];
        int rl = ((unsigned)ent.x) >> 24;
        int p = atomicAdd(&cnt[rl], 1);
        cv[p] = make_int2(ent.x & 0x00FFFFFF, ent.y);
    }
}

// ---------------- W fp16 conversion ----------------

__global__ void wconv_kernel(const float* __restrict__ W, __half2* __restrict__ Wh, int n2) {
    int i = blockIdx.x * blockDim.x + threadIdx.x;
    if (i < n2) Wh[i] = __float22half2_rn(reinterpret_cast<const float2*>(W)[i]);
}

// ---------------- gather-reduce row kernels (g4 layout) ----------------
// 4 edge-groups per wave (g = lane>>4), 16 lanes x 16B cover a 128ch f16 row.
// CSR entries via wave-private LDS scratch; zero-filled lanes self-mask.
// unroll 4: four independent dwordx4 gathers in flight per wave.

__global__ void spmm_g4_kernel(const int* __restrict__ row_ptr,
                               const long long* __restrict__ cv,
                               const __half2* __restrict__ Wh,   // [in_ch][64] half2
                               const float* __restrict__ bias,
                               __half2* __restrict__ outh, int n) {
    __shared__ long long sc[4 * 64];
    int gtid = blockIdx.x * blockDim.x + threadIdx.x;
    int wid = gtid >> 6;
    int lane = gtid & 63;
    if (wid >= n) return;
    int g = lane >> 4;
    int cl = lane & 15;
    long long* mysc = sc + (threadIdx.x >> 6) * 64;
    int s = row_ptr[wid], e = row_ptr[wid + 1];
    float acc0 = 0.f, acc1 = 0.f, acc2 = 0.f, acc3 = 0.f;
    float acc4 = 0.f, acc5 = 0.f, acc6 = 0.f, acc7 = 0.f;
    for (int base = s; base < e; base += 64) {
        int idx = base + lane;
        mysc[lane] = (idx < e) ? cv[idx] : 0;
        int m = e - base; if (m > 64) m = 64;
        #pragma unroll 4
        for (int k0 = 0; k0 < m; k0 += 4) {
            long long ck = mysc[k0 + g];
            int col = (int)ck;
            float v = __int_as_float((int)(ck >> 32));
            float4 wv = *reinterpret_cast<const float4*>(Wh + (long long)col * 64 + cl * 4);
            float2 f0 = __half22float2(*reinterpret_cast<const __half2*>(&wv.x));
            float2 f1 = __half22float2(*reinterpret_cast<const __half2*>(&wv.y));
            float2 f2 = __half22float2(*reinterpret_cast<const __half2*>(&wv.z));
            float2 f3 = __half22float2(*reinterpret_cast<const __half2*>(&wv.w));
            acc0 += v * f0.x; acc1 += v * f0.y;
            acc2 += v * f1.x; acc3 += v * f1.y;
            acc4 += v * f2.x; acc5 += v * f2.y;
            acc6 += v * f3.x; acc7 += v * f3.y;
        }
    }
    acc0 += __shfl_xor(acc0, 16); acc1 += __shfl_xor(acc1, 16);
    acc2 += __shfl_xor(acc2, 16); acc3 += __shfl_xor(acc3, 16);
    acc4 += __shfl_xor(acc4, 16); acc5 += __shfl_xor(acc5, 16);
    acc6 += __shfl_xor(acc6, 16); acc7 += __shfl_xor(acc7, 16);
    acc0 += __shfl_xor(acc0, 32); acc1 += __shfl_xor(acc1, 32);
    acc2 += __shfl_xor(acc2, 32); acc3 += __shfl_xor(acc3, 32);
    acc4 += __shfl_xor(acc4, 32); acc5 += __shfl_xor(acc5, 32);
    acc6 += __shfl_xor(acc6, 32); acc7 += __shfl_xor(acc7, 32);
    if (g == 0) {
        const float4* bp = reinterpret_cast<const float4*>(bias);
        float4 b0 = bp[cl * 2], b1 = bp[cl * 2 + 1];
        acc0 = fmaxf(acc0 + b0.x, 0.f); acc1 = fmaxf(acc1 + b0.y, 0.f);
        acc2 = fmaxf(acc2 + b0.z, 0.f); acc3 = fmaxf(acc3 + b0.w, 0.f);
        acc4 = fmaxf(acc4 + b1.x, 0.f); acc5 = fmaxf(acc5 + b1.y, 0.f);
        acc6 = fmaxf(acc6 + b1.z, 0.f); acc7 = fmaxf(acc7 + b1.w, 0.f);
        __half2 h0 = __floats2half2_rn(acc0, acc1);
        __half2 h1 = __floats2half2_rn(acc2, acc3);
        __half2 h2 = __floats2half2_rn(acc4, acc5);
        __half2 h3 = __floats2half2_rn(acc6, acc7);
        float4 ov;
        *reinterpret_cast<__half2*>(&ov.x) = h0;
        *reinterpret_cast<__half2*>(&ov.y) = h1;
        *reinterpret_cast<__half2*>(&ov.z) = h2;
        *reinterpret_cast<__half2*>(&ov.w) = h3;
        *reinterpret_cast<float4*>(outh + (long long)wid * 64 + cl * 4) = ov;
    }
}

__global__ void prop_g4_h2h_kernel(const int* __restrict__ row_ptr,
                                   const long long* __restrict__ cv,
                                   const __half2* __restrict__ src, __half2* __restrict__ dst,
                                   int n) {
    __shared__ long long sc[4 * 64];
    int gtid = blockIdx.x * blockDim.x + threadIdx.x;
    int wid = gtid >> 6;
    int lane = gtid & 63;
    if (wid >= n) return;
    int g = lane >> 4;
    int cl = lane & 15;
    long long* mysc = sc + (threadIdx.x >> 6) * 64;
    int s = row_ptr[wid], e = row_ptr[wid + 1];
    float acc0 = 0.f, acc1 = 0.f, acc2 = 0.f, acc3 = 0.f;
    float acc4 = 0.f, acc5 = 0.f, acc6 = 0.f, acc7 = 0.f;
    for (int base = s; base < e; base += 64) {
        int idx = base + lane;
        mysc[lane] = (idx < e) ? cv[idx] : 0;
        int m = e - base; if (m > 64) m = 64;
        #pragma unroll 4
        for (int k0 = 0; k0 < m; k0 += 4) {
            long long ck = mysc[k0 + g];
            int col = (int)ck;
            float v = __int_as_float((int)(ck >> 32));
            float4 sv = *reinterpret_cast<const float4*>(src + (long long)col * 64 + cl * 4);
            float2 f0 = __half22float2(*reinterpret_cast<const __half2*>(&sv.x));
            float2 f1 = __half22float2(*reinterpret_cast<const __half2*>(&sv.y));
            float2 f2 = __half22float2(*reinterpret_cast<const __half2*>(&sv.z));
            float2 f3 = __half22float2(*reinterpret_cast<const __half2*>(&sv.w));
            acc0 += v * f0.x; acc1 += v * f0.y;
            acc2 += v * f1.x; acc3 += v * f1.y;
            acc4 += v * f2.x; acc5 += v * f2.y;
            acc6 += v * f3.x; acc7 += v * f3.y;
        }
    }
    acc0 += __shfl_xor(acc0, 16); acc1 += __shfl_xor(acc1, 16);
    acc2 += __shfl_xor(acc2, 16); acc3 += __shfl_xor(acc3, 16);
    acc4 += __shfl_xor(acc4, 16); acc5 += __shfl_xor(acc5, 16);
    acc6 += __shfl_xor(acc6, 16); acc7 += __shfl_xor(acc7, 16);
    acc0 += __shfl_xor(acc0, 32); acc1 += __shfl_xor(acc1, 32);
    acc2 += __shfl_xor(acc2, 32); acc3 += __shfl_xor(acc3, 32);
    acc4 += __shfl_xor(acc4, 32); acc5 += __shfl_xor(acc5, 32);
    acc6 += __shfl_xor(acc6, 32); acc7 += __shfl_xor(acc7, 32);
    if (g == 0) {
        __half2 h0 = __floats2half2_rn(acc0, acc1);
        __half2 h1 = __floats2half2_rn(acc2, acc3);
        __half2 h2 = __floats2half2_rn(acc4, acc5);
        __half2 h3 = __floats2half2_rn(acc6, acc7);
        float4 ov;
        *reinterpret_cast<__half2*>(&ov.x) = h0;
        *reinterpret_cast<__half2*>(&ov.y) = h1;
        *reinterpret_cast<__half2*>(&ov.z) = h2;
        *reinterpret_cast<__half2*>(&ov.w) = h3;
        *reinterpret_cast<float4*>(dst + (long long)wid * 64 + cl * 4) = ov;
    }
}

__global__ void prop_g4_h2f_kernel(const int* __restrict__ row_ptr,
                                   const long long* __restrict__ cv,
                                   const __half2* __restrict__ src, float* __restrict__ dst,
                                   int n) {
    __shared__ long long sc[4 * 64];
    int gtid = blockIdx.x * blockDim.x + threadIdx.x;
    int wid = gtid >> 6;
    int lane = gtid & 63;
    if (wid >= n) return;
    int g = lane >> 4;
    int cl = lane & 15;
    long long* mysc = sc + (threadIdx.x >> 6) * 64;
    int s = row_ptr[wid], e = row_ptr[wid + 1];
    float acc0 = 0.f, acc1 = 0.f, acc2 = 0.f, acc3 = 0.f;
    float acc4 = 0.f, acc5 = 0.f, acc6 = 0.f, acc7 = 0.f;
    for (int base = s; base < e; base += 64) {
        int idx = base + lane;
        mysc[lane] = (idx < e) ? cv[idx] : 0;
        int m = e - base; if (m > 64) m = 64;
        #pragma unroll 4
        for (int k0 = 0; k0 < m; k0 += 4) {
            long long ck = mysc[k0 + g];
            int col = (int)ck;
            float v = __int_as_float((int)(ck >> 32));
            float4 sv = *reinterpret_cast<const float4*>(src + (long long)col * 64 + cl * 4);
            float2 f0 = __half22float2(*reinterpret_cast<const __half2*>(&sv.x));
            float2 f1 = __half22float2(*reinterpret_cast<const __half2*>(&sv.y));
            float2 f2 = __half22float2(*reinterpret_cast<const __half2*>(&sv.z));
            float2 f3 = __half22float2(*reinterpret_cast<const __half2*>(&sv.w));
            acc0 += v * f0.x; acc1 += v * f0.y;
            acc2 += v * f1.x; acc3 += v * f1.y;
            acc4 += v * f2.x; acc5 += v * f2.y;
            acc6 += v * f3.x; acc7 += v * f3.y;
        }
    }
    acc0 += __shfl_xor(acc0, 16); acc1 += __shfl_xor(acc1, 16);
    acc2 += __shfl_xor(acc2, 16); acc3 += __shfl_xor(acc3, 16);
    acc4 += __shfl_xor(acc4, 16); acc5 += __shfl_xor(acc5, 16);
    acc6 += __shfl_xor(acc6, 16); acc7 += __shfl_xor(acc7, 16);
    acc0 += __shfl_xor(acc0, 32); acc1 += __shfl_xor(acc1, 32);
    acc2 += __shfl_xor(acc2, 32); acc3 += __shfl_xor(acc3, 32);
    acc4 += __shfl_xor(acc4, 32); acc5 += __shfl_xor(acc5, 32);
    acc6 += __shfl_xor(acc6, 32); acc7 += __shfl_xor(acc7, 32);
    if (g == 0) {
        float4 o0 = make_float4(acc0, acc1, acc2, acc3);
        float4 o1 = make_float4(acc4, acc5, acc6, acc7);
        float4* dp = reinterpret_cast<float4*>(dst + (long long)wid * 128 + cl * 8);
        dp[0] = o0;
        dp[1] = o1;
    }
}

// ---------------- round-1 fallback (atomic scatter, f32) ----------------

__global__ void bias_relu_kernel(float* __restrict__ buf, const float* __restrict__ bias,
                                 long long total) {
    long long i = ((long long)blockIdx.x * blockDim.x + threadIdx.x) * 4;
    if (i >= total) return;
    float4 v = *reinterpret_cast<float4*>(buf + i);
    int ch = (int)(i & (CH - 1));
    float4 b = *reinterpret_cast<const float4*>(bias + ch);
    v.x = fmaxf(v.x + b.x, 0.0f);
    v.y = fmaxf(v.y + b.y, 0.0f);
    v.z = fmaxf(v.z + b.z, 0.0f);
    v.w = fmaxf(v.w + b.w, 0.0f);
    *reinterpret_cast<float4*>(buf + i) = v;
}

__global__ void spmm_scatter_kernel(const int* __restrict__ rows, const int* __restrict__ cols,
                                    const float* __restrict__ vals, const float* __restrict__ weight,
                                    float* __restrict__ out, int nnz) {
    long long tid = (long long)blockIdx.x * blockDim.x + threadIdx.x;
    if (tid >= (long long)nnz * 32) return;
    int e = (int)(tid >> 5), lane = (int)(tid & 31);
    int r = rows[e], c = cols[e];
    float v = vals[e];
    const float4 w = *reinterpret_cast<const float4*>(weight + (long long)c * CH + lane * 4);
    float* dst = out + (long long)r * CH + lane * 4;
    unsafeAtomicAdd(dst + 0, v * w.x);
    unsafeAtomicAdd(dst + 1, v * w.y);
    unsafeAtomicAdd(dst + 2, v * w.z);
    unsafeAtomicAdd(dst + 3, v * w.w);
}

__global__ void prop_scatter_kernel(const int* __restrict__ rows, const int* __restrict__ cols,
                                    const float* __restrict__ vals, const float* __restrict__ src,
                                    float* __restrict__ dst, int ne) {
    long long tid = (long long)blockIdx.x * blockDim.x + threadIdx.x;
    if (tid >= (long long)ne * 32) return;
    int e = (int)(tid >> 5), lane = (int)(tid & 31);
    int r = rows[e], c = cols[e];
    float v = vals[e];
    const float4 s = *reinterpret_cast<const float4*>(src + (long long)c * CH + lane * 4);
    float* d = dst + (long long)r * CH + lane * 4;
    unsafeAtomicAdd(d + 0, v * s.x);
    unsafeAtomicAdd(d + 1, v * s.y);
    unsafeAtomicAdd(d + 2, v * s.z);
    unsafeAtomicAdd(d + 3, v * s.w);
}

// ---------------- launch ----------------

static inline size_t align64(size_t x) { return (x + 63) & ~(size_t)63; }

extern "C" void kernel_launch(void* const* d_in, const int* in_sizes, int n_in,
                              void* d_out, int out_size, void* d_ws, size_t ws_size,
                              hipStream_t stream) {
    const int*   feat_rows = (const int*)d_in[0];
    const int*   feat_cols = (const int*)d_in[1];
    const float* feat_vals = (const float*)d_in[2];
    const int*   adj_rows  = (const int*)d_in[3];
    const int*   adj_cols  = (const int*)d_in[4];
    const float* adj_vals  = (const float*)d_in[5];
    const float* weight    = (const float*)d_in[6];
    const float* bias      = (const float*)d_in[7];

    const int nnz = in_sizes[0];
    const int ne  = in_sizes[3];
    const int n   = out_size / CH;   // n_nodes
    const int in_ch = in_sizes[6] / CH;

    float* out = (float*)d_out;
    char*  ws  = (char*)d_ws;

    const size_t NBF = (size_t)n * CH * sizeof(float);
    const size_t NBH = (size_t)n * CH * sizeof(__half);
    const long long total_elems = (long long)n * CH;
    const int BLK = 256;
    const int ew_blocks = (int)((total_elems / 4 + BLK - 1) / BLK);
    const int maxe = nnz > ne ? nnz : ne;
    const int nbuck = (n + BR - 1) / BR;
    const size_t bin_lds = (size_t)nbuck * 2 * sizeof(int);

    // ws layout (fast path); cv_tmp_feat/adj = lo/hi halves of pingh
    size_t off = 0;
    __half2* baseh   = (__half2*)(ws + off); off += align64(NBH);
    __half2* pingh   = (__half2*)(ws + off); off += align64(NBH);
    int*   row_ptr  = (int*)(ws + off);   off += align64(((size_t)n + 1) * 4);
    int*   bcounts  = (int*)(ws + off);   off += align64((size_t)2 * nbuck * 4);
    int*   bbase    = (int*)(ws + off);   off += align64((size_t)2 * (nbuck + 1) * 4);
    int*   wgc      = (int*)(ws + off);   off += align64((size_t)2 * BIN_WGS * nbuck * 4);
    __half2* Wh     = (__half2*)(ws + off); off += align64((size_t)in_ch * 64 * 4);
    int2*  cv       = (int2*)(ws + off);  off += align64((size_t)maxe * 8);
    int2*  cvt_f    = (int2*)pingh;
    int2*  cvt_a    = (int2*)((char*)pingh + (size_t)nnz * 8);
    const bool fast = (ws_size >= off) && (nbuck <= SCAN_BLK) &&
                      (n <= (1 << 24)) && (bin_lds <= 64 * 1024) &&
                      (in_ch <= (1 << 22)) &&
                      (((size_t)nnz + (size_t)ne) * 8 <= NBH);

    if (fast) {
        const int row_blocks = (int)(((long long)n * 64 + BLK - 1) / BLK);
        const int chunk_feat = (nnz + BIN_WGS - 1) / BIN_WGS;
        const int chunk_adj  = (ne + BIN_WGS - 1) / BIN_WGS;
        const int w2 = in_ch * 64;
        const size_t hist_lds = (size_t)nbuck * sizeof(int);
        const int wgscan_blocks = (2 * nbuck + 3) / 4;   // 4 waves / 256-thread block

        // --- W fp16 conversion ---
        wconv_kernel<<<(w2 + BLK - 1) / BLK, BLK, 0, stream>>>(weight, Wh, w2);

        // --- merged CSR build (both matrices) ---
        hist2_kernel<<<2 * BIN_WGS, BIN_THR, hist_lds, stream>>>(
            feat_rows, nnz, chunk_feat, adj_rows, ne, chunk_adj, wgc, nbuck);
        wgscan2_kernel<<<wgscan_blocks, 256, 0, stream>>>(wgc, bcounts, nbuck, BIN_WGS);
        bucket_scan2_kernel<<<2, SCAN_BLK, 0, stream>>>(bcounts, bbase, nbuck);
        bin2_kernel<<<2 * BIN_WGS, BIN_THR, bin_lds, stream>>>(
            feat_rows, feat_cols, feat_vals, nnz, chunk_feat,
            adj_rows, adj_cols, adj_vals, ne, chunk_adj,
            bbase, wgc, cvt_f, cvt_a, nbuck);

        // --- feat: reorder -> spmm ---
        reorder2_kernel<<<nbuck, BIN_THR, 0, stream>>>(bbase, cvt_f, cv, row_ptr, n);
        spmm_g4_kernel<<<row_blocks, BLK, 0, stream>>>(
            row_ptr, (const long long*)cv, Wh, bias, baseh, n);

        // --- adj: reorder (reuses cv + row_ptr after spmm) -> prop x2 ---
        reorder2_kernel<<<nbuck, BIN_THR, 0, stream>>>(bbase + (nbuck + 1), cvt_a, cv, row_ptr, n);
        prop_g4_h2h_kernel<<<row_blocks, BLK, 0, stream>>>(
            row_ptr, (const long long*)cv, baseh, pingh, n);
        prop_g4_h2f_kernel<<<row_blocks, BLK, 0, stream>>>(
            row_ptr, (const long long*)cv, pingh, out, n);
    } else {
        // round-1 fallback: atomic scatter (f32)
        float* ping = (float*)ws;
        const int spmm_blocks = (int)(((long long)nnz * 32 + BLK - 1) / BLK);
        const int prop_blocks = (int)(((long long)ne * 32 + BLK - 1) / BLK);
        hipMemsetAsync(d_out, 0, NBF, stream);
        spmm_scatter_kernel<<<spmm_blocks, BLK, 0, stream>>>(feat_rows, feat_cols, feat_vals,
                                                             weight, out, nnz);
        bias_relu_kernel<<<ew_blocks, BLK, 0, stream>>>(out, bias, total_elems);
        hipMemsetAsync(ping, 0, NBF, stream);
        prop_scatter_kernel<<<prop_blocks, BLK, 0, stream>>>(adj_rows, adj_cols, adj_vals,
                                                             out, ping, ne);
        hipMemsetAsync(d_out, 0, NBF, stream);
        prop_scatter_kernel<<<prop_blocks, BLK, 0, stream>>>(adj_rows, adj_cols, adj_vals,
                                                             ping, out, ne);
    }
}

// Round 13
// 237.046 us; speedup vs baseline: 33.8984x; 1.0382x over previous
//
#include <hip/hip_runtime.h>
#include <hip/hip_fp16.h>

// SparseNGCNLayer: base = relu(SpMM(feat, W) + bias); base = A @ base (x2)
// Round 13: forced 4-deep gather batching in all gather kernels.
// Round-12 post-mortem: #pragma unroll 4 was NULL (VGPR=20 -> compiler
// re-serialized to 1 load in flight). This round uses explicitly named
// ck0..ck3 / sv0..sv3 registers per 16-edge super-step over the zero-filled
// 64-entry wave scratch (masked slots gather col 0, L2-hot). CSR build
// (merged hist2/wgscan2/bucket_scan2/bin2 + reorder2) unchanged.

#define CH 128
#define BR 128            // rows per bucket (rlocal fits in 7 bits)
#define SCAN_BLK 1024
#define BIN_WGS 256       // multisplit workgroups per matrix
#define BIN_THR 512

// ---------------- CSR build (merged feat+adj) ----------------

__global__ void hist2_kernel(const int* __restrict__ rows_f, int nf, int chunk_f,
                             const int* __restrict__ rows_a, int na, int chunk_a,
                             int* __restrict__ wgc, int nbuck) {
    extern __shared__ int hcnt[];
    const int m  = blockIdx.x >> 8;
    const int wg = blockIdx.x & (BIN_WGS - 1);
    const int* rows = m ? rows_a : rows_f;
    const int nE    = m ? na : nf;
    const int chunk = m ? chunk_a : chunk_f;
    const int tid = threadIdx.x;
    const long long T = blockDim.x;
    long long start = (long long)wg * chunk;
    long long end = start + chunk;
    if (end > nE) end = nE;
    for (int b = tid; b < nbuck; b += blockDim.x) hcnt[b] = 0;
    __syncthreads();
    if (start < end) {
        long long i = start + tid;
        for (; i + 3 * T < end; i += 4 * T) {
            int r0 = rows[i], r1 = rows[i + T], r2 = rows[i + 2 * T], r3 = rows[i + 3 * T];
            atomicAdd(&hcnt[r0 >> 7], 1);
            atomicAdd(&hcnt[r1 >> 7], 1);
            atomicAdd(&hcnt[r2 >> 7], 1);
            atomicAdd(&hcnt[r3 >> 7], 1);
        }
        for (; i < end; i += T) atomicAdd(&hcnt[rows[i] >> 7], 1);
    }
    __syncthreads();
    int* out = wgc + ((long long)m * BIN_WGS + wg) * nbuck;
    for (int b = tid; b < nbuck; b += blockDim.x) out[b] = hcnt[b];
}

__global__ void wgscan2_kernel(int* __restrict__ wgc, int* __restrict__ bcounts,
                               int nbuck, int nwg) {
    int wpb = blockDim.x >> 6;
    int idx = blockIdx.x * wpb + (threadIdx.x >> 6);
    int lane = threadIdx.x & 63;
    if (idx >= 2 * nbuck) return;
    int m = (idx >= nbuck) ? 1 : 0;
    int b = idx - m * nbuck;
    int* base = wgc + (long long)m * nwg * nbuck + b;
    int carry = 0;
    for (int w0 = 0; w0 < nwg; w0 += 64) {
        int wg = w0 + lane;
        int v = (wg < nwg) ? base[(long long)wg * nbuck] : 0;
        int x = v;
        #pragma unroll
        for (int off = 1; off < 64; off <<= 1) {
            int y = __shfl_up(x, off);
            if (lane >= off) x += y;
        }
        if (wg < nwg) base[(long long)wg * nbuck] = carry + x - v;  // exclusive
        carry += __shfl(x, 63);
    }
    if (lane == 0) bcounts[idx] = carry;
}

__global__ void bucket_scan2_kernel(const int* __restrict__ bcounts,
                                    int* __restrict__ bbase, int nbuck) {
    __shared__ int lds[SCAN_BLK];
    int m = blockIdx.x;
    int tid = threadIdx.x;
    int x = (tid < nbuck) ? bcounts[m * nbuck + tid] : 0;
    lds[tid] = x;
    __syncthreads();
    for (int off = 1; off < SCAN_BLK; off <<= 1) {
        int y = (tid >= off) ? lds[tid - off] : 0;
        __syncthreads();
        lds[tid] += y;
        __syncthreads();
    }
    int* bb = bbase + m * (nbuck + 1);
    if (tid < nbuck) bb[tid] = lds[tid] - x;
    if (tid == nbuck - 1) bb[nbuck] = lds[tid];
}

__global__ void bin2_kernel(const int* __restrict__ rows_f, const int* __restrict__ cols_f,
                            const float* __restrict__ vals_f, int nf, int chunk_f,
                            const int* __restrict__ rows_a, const int* __restrict__ cols_a,
                            const float* __restrict__ vals_a, int na, int chunk_a,
                            const int* __restrict__ bbase, const int* __restrict__ wgc,
                            int2* __restrict__ cvt_f, int2* __restrict__ cvt_a, int nbuck) {
    extern __shared__ int lds[];
    int* hcnt  = lds;            // [nbuck] local cursors
    int* hbase = lds + nbuck;    // [nbuck] this WG's subrange bases
    const int m  = blockIdx.x >> 8;
    const int wg = blockIdx.x & (BIN_WGS - 1);
    const int* rows = m ? rows_a : rows_f;
    const int* cols = m ? cols_a : cols_f;
    const float* vals = m ? vals_a : vals_f;
    const int nE    = m ? na : nf;
    const int chunk = m ? chunk_a : chunk_f;
    int2* cv_tmp = m ? cvt_a : cvt_f;
    const int* bb = bbase + m * (nbuck + 1);
    const int* wc = wgc + ((long long)m * BIN_WGS + wg) * nbuck;
    const int tid = threadIdx.x;
    const long long T = blockDim.x;
    long long start = (long long)wg * chunk;
    long long end = start + chunk;
    if (end > nE) end = nE;
    for (int b = tid; b < nbuck; b += blockDim.x) {
        hbase[b] = bb[b] + wc[b];
        hcnt[b] = 0;
    }
    __syncthreads();
    if (start >= end) return;
    long long i = start + tid;
    for (; i + 3 * T < end; i += 4 * T) {
        int r0 = rows[i], r1 = rows[i + T], r2 = rows[i + 2 * T], r3 = rows[i + 3 * T];
        int c0 = cols[i], c1 = cols[i + T], c2 = cols[i + 2 * T], c3 = cols[i + 3 * T];
        float v0 = vals[i], v1 = vals[i + T], v2 = vals[i + 2 * T], v3 = vals[i + 3 * T];
        int b0 = r0 >> 7, b1 = r1 >> 7, b2 = r2 >> 7, b3 = r3 >> 7;
        int p0 = hbase[b0] + atomicAdd(&hcnt[b0], 1);
        int p1 = hbase[b1] + atomicAdd(&hcnt[b1], 1);
        int p2 = hbase[b2] + atomicAdd(&hcnt[b2], 1);
        int p3 = hbase[b3] + atomicAdd(&hcnt[b3], 1);
        cv_tmp[p0] = make_int2(c0 | ((r0 & (BR - 1)) << 24), __float_as_int(v0));
        cv_tmp[p1] = make_int2(c1 | ((r1 & (BR - 1)) << 24), __float_as_int(v1));
        cv_tmp[p2] = make_int2(c2 | ((r2 & (BR - 1)) << 24), __float_as_int(v2));
        cv_tmp[p3] = make_int2(c3 | ((r3 & (BR - 1)) << 24), __float_as_int(v3));
    }
    for (; i < end; i += T) {
        int r = rows[i];
        int b = r >> 7;
        int p = hbase[b] + atomicAdd(&hcnt[b], 1);
        cv_tmp[p] = make_int2(cols[i] | ((r & (BR - 1)) << 24), __float_as_int(vals[i]));
    }
}

__global__ void reorder2_kernel(const int* __restrict__ bucket_base,
                                const int2* __restrict__ cv_tmp, int2* __restrict__ cv,
                                int* __restrict__ row_ptr, int n) {
    __shared__ int cnt[BR];
    __shared__ int tmp[BR];
    int b = blockIdx.x;
    int rbase = b * BR;
    int tid = threadIdx.x;
    int s = bucket_base[b], e = bucket_base[b + 1];
    if (tid < BR) cnt[tid] = 0;
    __syncthreads();
    for (int i = s + tid; i < e; i += blockDim.x)
        atomicAdd(&cnt[((unsigned)cv_tmp[i].x) >> 24], 1);
    __syncthreads();
    if (tid < BR) tmp[tid] = cnt[tid];
    __syncthreads();
    for (int off = 1; off < BR; off <<= 1) {
        int y = 0;
        if (tid < BR && tid >= off) y = tmp[tid - off];
        __syncthreads();
        if (tid < BR) tmp[tid] += y;
        __syncthreads();
    }
    if (tid < BR) {
        int excl = s + tmp[tid] - cnt[tid];
        if (rbase + tid < n) row_ptr[rbase + tid] = excl;
        cnt[tid] = excl;       // becomes the scatter cursor
    }
    if (tid == 0 && b == gridDim.x - 1) row_ptr[n] = e;
    __syncthreads();
    for (int i = s + tid; i < e; i += blockDim.x) {
        int2 ent = cv_tmp[i];
        int rl = ((unsigned)ent.x) >> 24;
        int p = atomicAdd(&cnt[rl], 1);
        cv[p] = make_int2(ent.x & 0x00FFFFFF, ent.y);
    }
}

// ---------------- W fp16 conversion ----------------

__global__ void wconv_kernel(const float* __restrict__ W, __half2* __restrict__ Wh, int n2) {
    int i = blockIdx.x * blockDim.x + threadIdx.x;
    if (i < n2) Wh[i] = __float22half2_rn(reinterpret_cast<const float2*>(W)[i]);
}

// ---------------- gather-reduce row kernels (g4 + forced batch-4) ----------------
// group g = lane>>4 owns edges {k0+g, k0+4+g, k0+8+g, k0+12+g} per super-step;
// 16 lanes x 16B cover one edge's 128 f16 channels. Scratch is zero-filled to
// 64 entries, so masked super-step slots gather col 0 (L2-hot) and self-mask
// via v=0. Named registers force 4 dwordx4 gathers in flight.

#define GATHER_BODY(TBL)                                                            \
    for (int base = s; base < e; base += 64) {                                      \
        int idx = base + lane;                                                      \
        mysc[lane] = (idx < e) ? cv[idx] : 0;                                       \
        int m = e - base; if (m > 64) m = 64;                                       \
        int nb = (m + 15) >> 4;                                                     \
        for (int t = 0; t < nb; t++) {                                              \
            int k0 = t << 4;                                                        \
            long long ck0 = mysc[k0 + g];                                           \
            long long ck1 = mysc[k0 + 4 + g];                                       \
            long long ck2 = mysc[k0 + 8 + g];                                       \
            long long ck3 = mysc[k0 + 12 + g];                                      \
            float4 sv0 = *reinterpret_cast<const float4*>(TBL + (long long)(int)ck0 * 64 + cl * 4); \
            float4 sv1 = *reinterpret_cast<const float4*>(TBL + (long long)(int)ck1 * 64 + cl * 4); \
            float4 sv2 = *reinterpret_cast<const float4*>(TBL + (long long)(int)ck2 * 64 + cl * 4); \
            float4 sv3 = *reinterpret_cast<const float4*>(TBL + (long long)(int)ck3 * 64 + cl * 4); \
            float v0 = __int_as_float((int)(ck0 >> 32));                            \
            float v1 = __int_as_float((int)(ck1 >> 32));                            \
            float v2 = __int_as_float((int)(ck2 >> 32));                            \
            float v3 = __int_as_float((int)(ck3 >> 32));                            \
            ACC8(v0, sv0); ACC8(v1, sv1); ACC8(v2, sv2); ACC8(v3, sv3);             \
        }                                                                           \
    }

#define ACC8(V, SV) {                                                               \
    float2 f0 = __half22float2(*reinterpret_cast<const __half2*>(&(SV).x));         \
    float2 f1 = __half22float2(*reinterpret_cast<const __half2*>(&(SV).y));         \
    float2 f2 = __half22float2(*reinterpret_cast<const __half2*>(&(SV).z));         \
    float2 f3 = __half22float2(*reinterpret_cast<const __half2*>(&(SV).w));         \
    acc0 += (V) * f0.x; acc1 += (V) * f0.y;                                         \
    acc2 += (V) * f1.x; acc3 += (V) * f1.y;                                         \
    acc4 += (V) * f2.x; acc5 += (V) * f2.y;                                         \
    acc6 += (V) * f3.x; acc7 += (V) * f3.y; }

#define XREDUCE()                                                                   \
    acc0 += __shfl_xor(acc0, 16); acc1 += __shfl_xor(acc1, 16);                     \
    acc2 += __shfl_xor(acc2, 16); acc3 += __shfl_xor(acc3, 16);                     \
    acc4 += __shfl_xor(acc4, 16); acc5 += __shfl_xor(acc5, 16);                     \
    acc6 += __shfl_xor(acc6, 16); acc7 += __shfl_xor(acc7, 16);                     \
    acc0 += __shfl_xor(acc0, 32); acc1 += __shfl_xor(acc1, 32);                     \
    acc2 += __shfl_xor(acc2, 32); acc3 += __shfl_xor(acc3, 32);                     \
    acc4 += __shfl_xor(acc4, 32); acc5 += __shfl_xor(acc5, 32);                     \
    acc6 += __shfl_xor(acc6, 32); acc7 += __shfl_xor(acc7, 32);

__global__ void spmm_g4_kernel(const int* __restrict__ row_ptr,
                               const long long* __restrict__ cv,
                               const __half2* __restrict__ Wh,   // [in_ch][64] half2
                               const float* __restrict__ bias,
                               __half2* __restrict__ outh, int n) {
    __shared__ long long sc[4 * 64];
    int gtid = blockIdx.x * blockDim.x + threadIdx.x;
    int wid = gtid >> 6;
    int lane = gtid & 63;
    if (wid >= n) return;
    int g = lane >> 4;
    int cl = lane & 15;
    long long* mysc = sc + (threadIdx.x >> 6) * 64;
    int s = row_ptr[wid], e = row_ptr[wid + 1];
    float acc0 = 0.f, acc1 = 0.f, acc2 = 0.f, acc3 = 0.f;
    float acc4 = 0.f, acc5 = 0.f, acc6 = 0.f, acc7 = 0.f;
    GATHER_BODY(Wh)
    XREDUCE()
    if (g == 0) {
        const float4* bp = reinterpret_cast<const float4*>(bias);
        float4 b0 = bp[cl * 2], b1 = bp[cl * 2 + 1];
        acc0 = fmaxf(acc0 + b0.x, 0.f); acc1 = fmaxf(acc1 + b0.y, 0.f);
        acc2 = fmaxf(acc2 + b0.z, 0.f); acc3 = fmaxf(acc3 + b0.w, 0.f);
        acc4 = fmaxf(acc4 + b1.x, 0.f); acc5 = fmaxf(acc5 + b1.y, 0.f);
        acc6 = fmaxf(acc6 + b1.z, 0.f); acc7 = fmaxf(acc7 + b1.w, 0.f);
        __half2 h0 = __floats2half2_rn(acc0, acc1);
        __half2 h1 = __floats2half2_rn(acc2, acc3);
        __half2 h2 = __floats2half2_rn(acc4, acc5);
        __half2 h3 = __floats2half2_rn(acc6, acc7);
        float4 ov;
        *reinterpret_cast<__half2*>(&ov.x) = h0;
        *reinterpret_cast<__half2*>(&ov.y) = h1;
        *reinterpret_cast<__half2*>(&ov.z) = h2;
        *reinterpret_cast<__half2*>(&ov.w) = h3;
        *reinterpret_cast<float4*>(outh + (long long)wid * 64 + cl * 4) = ov;
    }
}

__global__ void prop_g4_h2h_kernel(const int* __restrict__ row_ptr,
                                   const long long* __restrict__ cv,
                                   const __half2* __restrict__ src, __half2* __restrict__ dst,
                                   int n) {
    __shared__ long long sc[4 * 64];
    int gtid = blockIdx.x * blockDim.x + threadIdx.x;
    int wid = gtid >> 6;
    int lane = gtid & 63;
    if (wid >= n) return;
    int g = lane >> 4;
    int cl = lane & 15;
    long long* mysc = sc + (threadIdx.x >> 6) * 64;
    int s = row_ptr[wid], e = row_ptr[wid + 1];
    float acc0 = 0.f, acc1 = 0.f, acc2 = 0.f, acc3 = 0.f;
    float acc4 = 0.f, acc5 = 0.f, acc6 = 0.f, acc7 = 0.f;
    GATHER_BODY(src)
    XREDUCE()
    if (g == 0) {
        __half2 h0 = __floats2half2_rn(acc0, acc1);
        __half2 h1 = __floats2half2_rn(acc2, acc3);
        __half2 h2 = __floats2half2_rn(acc4, acc5);
        __half2 h3 = __floats2half2_rn(acc6, acc7);
        float4 ov;
        *reinterpret_cast<__half2*>(&ov.x) = h0;
        *reinterpret_cast<__half2*>(&ov.y) = h1;
        *reinterpret_cast<__half2*>(&ov.z) = h2;
        *reinterpret_cast<__half2*>(&ov.w) = h3;
        *reinterpret_cast<float4*>(dst + (long long)wid * 64 + cl * 4) = ov;
    }
}

__global__ void prop_g4_h2f_kernel(const int* __restrict__ row_ptr,
                                   const long long* __restrict__ cv,
                                   const __half2* __restrict__ src, float* __restrict__ dst,
                                   int n) {
    __shared__ long long sc[4 * 64];
    int gtid = blockIdx.x * blockDim.x + threadIdx.x;
    int wid = gtid >> 6;
    int lane = gtid & 63;
    if (wid >= n) return;
    int g = lane >> 4;
    int cl = lane & 15;
    long long* mysc = sc + (threadIdx.x >> 6) * 64;
    int s = row_ptr[wid], e = row_ptr[wid + 1];
    float acc0 = 0.f, acc1 = 0.f, acc2 = 0.f, acc3 = 0.f;
    float acc4 = 0.f, acc5 = 0.f, acc6 = 0.f, acc7 = 0.f;
    GATHER_BODY(src)
    XREDUCE()
    if (g == 0) {
        float4 o0 = make_float4(acc0, acc1, acc2, acc3);
        float4 o1 = make_float4(acc4, acc5, acc6, acc7);
        float4* dp = reinterpret_cast<float4*>(dst + (long long)wid * 128 + cl * 8);
        dp[0] = o0;
        dp[1] = o1;
    }
}

// ---------------- round-1 fallback (atomic scatter, f32) ----------------

__global__ void bias_relu_kernel(float* __restrict__ buf, const float* __restrict__ bias,
                                 long long total) {
    long long i = ((long long)blockIdx.x * blockDim.x + threadIdx.x) * 4;
    if (i >= total) return;
    float4 v = *reinterpret_cast<float4*>(buf + i);
    int ch = (int)(i & (CH - 1));
    float4 b = *reinterpret_cast<const float4*>(bias + ch);
    v.x = fmaxf(v.x + b.x, 0.0f);
    v.y = fmaxf(v.y + b.y, 0.0f);
    v.z = fmaxf(v.z + b.z, 0.0f);
    v.w = fmaxf(v.w + b.w, 0.0f);
    *reinterpret_cast<float4*>(buf + i) = v;
}

__global__ void spmm_scatter_kernel(const int* __restrict__ rows, const int* __restrict__ cols,
                                    const float* __restrict__ vals, const float* __restrict__ weight,
                                    float* __restrict__ out, int nnz) {
    long long tid = (long long)blockIdx.x * blockDim.x + threadIdx.x;
    if (tid >= (long long)nnz * 32) return;
    int e = (int)(tid >> 5), lane = (int)(tid & 31);
    int r = rows[e], c = cols[e];
    float v = vals[e];
    const float4 w = *reinterpret_cast<const float4*>(weight + (long long)c * CH + lane * 4);
    float* dst = out + (long long)r * CH + lane * 4;
    unsafeAtomicAdd(dst + 0, v * w.x);
    unsafeAtomicAdd(dst + 1, v * w.y);
    unsafeAtomicAdd(dst + 2, v * w.z);
    unsafeAtomicAdd(dst + 3, v * w.w);
}

__global__ void prop_scatter_kernel(const int* __restrict__ rows, const int* __restrict__ cols,
                                    const float* __restrict__ vals, const float* __restrict__ src,
                                    float* __restrict__ dst, int ne) {
    long long tid = (long long)blockIdx.x * blockDim.x + threadIdx.x;
    if (tid >= (long long)ne * 32) return;
    int e = (int)(tid >> 5), lane = (int)(tid & 31);
    int r = rows[e], c = cols[e];
    float v = vals[e];
    const float4 s = *reinterpret_cast<const float4*>(src + (long long)c * CH + lane * 4);
    float* d = dst + (long long)r * CH + lane * 4;
    unsafeAtomicAdd(d + 0, v * s.x);
    unsafeAtomicAdd(d + 1, v * s.y);
    unsafeAtomicAdd(d + 2, v * s.z);
    unsafeAtomicAdd(d + 3, v * s.w);
}

// ---------------- launch ----------------

static inline size_t align64(size_t x) { return (x + 63) & ~(size_t)63; }

extern "C" void kernel_launch(void* const* d_in, const int* in_sizes, int n_in,
                              void* d_out, int out_size, void* d_ws, size_t ws_size,
                              hipStream_t stream) {
    const int*   feat_rows = (const int*)d_in[0];
    const int*   feat_cols = (const int*)d_in[1];
    const float* feat_vals = (const float*)d_in[2];
    const int*   adj_rows  = (const int*)d_in[3];
    const int*   adj_cols  = (const int*)d_in[4];
    const float* adj_vals  = (const float*)d_in[5];
    const float* weight    = (const float*)d_in[6];
    const float* bias      = (const float*)d_in[7];

    const int nnz = in_sizes[0];
    const int ne  = in_sizes[3];
    const int n   = out_size / CH;   // n_nodes
    const int in_ch = in_sizes[6] / CH;

    float* out = (float*)d_out;
    char*  ws  = (char*)d_ws;

    const size_t NBF = (size_t)n * CH * sizeof(float);
    const size_t NBH = (size_t)n * CH * sizeof(__half);
    const long long total_elems = (long long)n * CH;
    const int BLK = 256;
    const int ew_blocks = (int)((total_elems / 4 + BLK - 1) / BLK);
    const int maxe = nnz > ne ? nnz : ne;
    const int nbuck = (n + BR - 1) / BR;
    const size_t bin_lds = (size_t)nbuck * 2 * sizeof(int);

    // ws layout (fast path); cv_tmp_feat/adj = lo/hi halves of pingh
    size_t off = 0;
    __half2* baseh   = (__half2*)(ws + off); off += align64(NBH);
    __half2* pingh   = (__half2*)(ws + off); off += align64(NBH);
    int*   row_ptr  = (int*)(ws + off);   off += align64(((size_t)n + 1) * 4);
    int*   bcounts  = (int*)(ws + off);   off += align64((size_t)2 * nbuck * 4);
    int*   bbase    = (int*)(ws + off);   off += align64((size_t)2 * (nbuck + 1) * 4);
    int*   wgc      = (int*)(ws + off);   off += align64((size_t)2 * BIN_WGS * nbuck * 4);
    __half2* Wh     = (__half2*)(ws + off); off += align64((size_t)in_ch * 64 * 4);
    int2*  cv       = (int2*)(ws + off);  off += align64((size_t)maxe * 8);
    int2*  cvt_f    = (int2*)pingh;
    int2*  cvt_a    = (int2*)((char*)pingh + (size_t)nnz * 8);
    const bool fast = (ws_size >= off) && (nbuck <= SCAN_BLK) &&
                      (n <= (1 << 24)) && (bin_lds <= 64 * 1024) &&
                      (in_ch <= (1 << 22)) &&
                      (((size_t)nnz + (size_t)ne) * 8 <= NBH);

    if (fast) {
        const int row_blocks = (int)(((long long)n * 64 + BLK - 1) / BLK);
        const int chunk_feat = (nnz + BIN_WGS - 1) / BIN_WGS;
        const int chunk_adj  = (ne + BIN_WGS - 1) / BIN_WGS;
        const int w2 = in_ch * 64;
        const size_t hist_lds = (size_t)nbuck * sizeof(int);
        const int wgscan_blocks = (2 * nbuck + 3) / 4;   // 4 waves / 256-thread block

        // --- W fp16 conversion ---
        wconv_kernel<<<(w2 + BLK - 1) / BLK, BLK, 0, stream>>>(weight, Wh, w2);

        // --- merged CSR build (both matrices) ---
        hist2_kernel<<<2 * BIN_WGS, BIN_THR, hist_lds, stream>>>(
            feat_rows, nnz, chunk_feat, adj_rows, ne, chunk_adj, wgc, nbuck);
        wgscan2_kernel<<<wgscan_blocks, 256, 0, stream>>>(wgc, bcounts, nbuck, BIN_WGS);
        bucket_scan2_kernel<<<2, SCAN_BLK, 0, stream>>>(bcounts, bbase, nbuck);
        bin2_kernel<<<2 * BIN_WGS, BIN_THR, bin_lds, stream>>>(
            feat_rows, feat_cols, feat_vals, nnz, chunk_feat,
            adj_rows, adj_cols, adj_vals, ne, chunk_adj,
            bbase, wgc, cvt_f, cvt_a, nbuck);

        // --- feat: reorder -> spmm ---
        reorder2_kernel<<<nbuck, BIN_THR, 0, stream>>>(bbase, cvt_f, cv, row_ptr, n);
        spmm_g4_kernel<<<row_blocks, BLK, 0, stream>>>(
            row_ptr, (const long long*)cv, Wh, bias, baseh, n);

        // --- adj: reorder (reuses cv + row_ptr after spmm) -> prop x2 ---
        reorder2_kernel<<<nbuck, BIN_THR, 0, stream>>>(bbase + (nbuck + 1), cvt_a, cv, row_ptr, n);
        prop_g4_h2h_kernel<<<row_blocks, BLK, 0, stream>>>(
            row_ptr, (const long long*)cv, baseh, pingh, n);
        prop_g4_h2f_kernel<<<row_blocks, BLK, 0, stream>>>(
            row_ptr, (const long long*)cv, pingh, out, n);
    } else {
        // round-1 fallback: atomic scatter (f32)
        float* ping = (float*)ws;
        const int spmm_blocks = (int)(((long long)nnz * 32 + BLK - 1) / BLK);
        const int prop_blocks = (int)(((long long)ne * 32 + BLK - 1) / BLK);
        hipMemsetAsync(d_out, 0, NBF, stream);
        spmm_scatter_kernel<<<spmm_blocks, BLK, 0, stream>>>(feat_rows, feat_cols, feat_vals,
                                                             weight, out, nnz);
        bias_relu_kernel<<<ew_blocks, BLK, 0, stream>>>(out, bias, total_elems);
        hipMemsetAsync(ping, 0, NBF, stream);
        prop_scatter_kernel<<<prop_blocks, BLK, 0, stream>>>(adj_rows, adj_cols, adj_vals,
                                                             out, ping, ne);
        hipMemsetAsync(d_out, 0, NBF, stream);
        prop_scatter_kernel<<<prop_blocks, BLK, 0, stream>>>(adj_rows, adj_cols, adj_vals,
                                                             ping, out, ne);
    }
}

// Round 14
// 232.264 us; speedup vs baseline: 34.5964x; 1.0206x over previous
//
#include <hip/hip_runtime.h>
#include <hip/hip_fp16.h>

// SparseNGCNLayer: base = relu(SpMM(feat, W) + bias); base = A @ base (x2)
// Round 14: 4-rows-per-wave gather kernels (one 16-lane group per row).
// Removes the 16x shfl_xor cross-group reduce + single-group epilogue
// (~40% of per-row VALU work in the g4 scheme) and amortizes the CSR
// scratch fill over 4 contiguous rows. Batch-4 named-register gathers kept.
// CSR build (hist2/wgscan2/bucket_scan2/bin2 + reorder2) unchanged.

#define CH 128
#define BR 128            // rows per bucket (rlocal fits in 7 bits)
#define SCAN_BLK 1024
#define BIN_WGS 256       // multisplit workgroups per matrix
#define BIN_THR 512

// ---------------- CSR build (merged feat+adj) ----------------

__global__ void hist2_kernel(const int* __restrict__ rows_f, int nf, int chunk_f,
                             const int* __restrict__ rows_a, int na, int chunk_a,
                             int* __restrict__ wgc, int nbuck) {
    extern __shared__ int hcnt[];
    const int m  = blockIdx.x >> 8;
    const int wg = blockIdx.x & (BIN_WGS - 1);
    const int* rows = m ? rows_a : rows_f;
    const int nE    = m ? na : nf;
    const int chunk = m ? chunk_a : chunk_f;
    const int tid = threadIdx.x;
    const long long T = blockDim.x;
    long long start = (long long)wg * chunk;
    long long end = start + chunk;
    if (end > nE) end = nE;
    for (int b = tid; b < nbuck; b += blockDim.x) hcnt[b] = 0;
    __syncthreads();
    if (start < end) {
        long long i = start + tid;
        for (; i + 3 * T < end; i += 4 * T) {
            int r0 = rows[i], r1 = rows[i + T], r2 = rows[i + 2 * T], r3 = rows[i + 3 * T];
            atomicAdd(&hcnt[r0 >> 7], 1);
            atomicAdd(&hcnt[r1 >> 7], 1);
            atomicAdd(&hcnt[r2 >> 7], 1);
            atomicAdd(&hcnt[r3 >> 7], 1);
        }
        for (; i < end; i += T) atomicAdd(&hcnt[rows[i] >> 7], 1);
    }
    __syncthreads();
    int* out = wgc + ((long long)m * BIN_WGS + wg) * nbuck;
    for (int b = tid; b < nbuck; b += blockDim.x) out[b] = hcnt[b];
}

__global__ void wgscan2_kernel(int* __restrict__ wgc, int* __restrict__ bcounts,
                               int nbuck, int nwg) {
    int wpb = blockDim.x >> 6;
    int idx = blockIdx.x * wpb + (threadIdx.x >> 6);
    int lane = threadIdx.x & 63;
    if (idx >= 2 * nbuck) return;
    int m = (idx >= nbuck) ? 1 : 0;
    int b = idx - m * nbuck;
    int* base = wgc + (long long)m * nwg * nbuck + b;
    int carry = 0;
    for (int w0 = 0; w0 < nwg; w0 += 64) {
        int wg = w0 + lane;
        int v = (wg < nwg) ? base[(long long)wg * nbuck] : 0;
        int x = v;
        #pragma unroll
        for (int off = 1; off < 64; off <<= 1) {
            int y = __shfl_up(x, off);
            if (lane >= off) x += y;
        }
        if (wg < nwg) base[(long long)wg * nbuck] = carry + x - v;  // exclusive
        carry += __shfl(x, 63);
    }
    if (lane == 0) bcounts[idx] = carry;
}

__global__ void bucket_scan2_kernel(const int* __restrict__ bcounts,
                                    int* __restrict__ bbase, int nbuck) {
    __shared__ int lds[SCAN_BLK];
    int m = blockIdx.x;
    int tid = threadIdx.x;
    int x = (tid < nbuck) ? bcounts[m * nbuck + tid] : 0;
    lds[tid] = x;
    __syncthreads();
    for (int off = 1; off < SCAN_BLK; off <<= 1) {
        int y = (tid >= off) ? lds[tid - off] : 0;
        __syncthreads();
        lds[tid] += y;
        __syncthreads();
    }
    int* bb = bbase + m * (nbuck + 1);
    if (tid < nbuck) bb[tid] = lds[tid] - x;
    if (tid == nbuck - 1) bb[nbuck] = lds[tid];
}

__global__ void bin2_kernel(const int* __restrict__ rows_f, const int* __restrict__ cols_f,
                            const float* __restrict__ vals_f, int nf, int chunk_f,
                            const int* __restrict__ rows_a, const int* __restrict__ cols_a,
                            const float* __restrict__ vals_a, int na, int chunk_a,
                            const int* __restrict__ bbase, const int* __restrict__ wgc,
                            int2* __restrict__ cvt_f, int2* __restrict__ cvt_a, int nbuck) {
    extern __shared__ int lds[];
    int* hcnt  = lds;            // [nbuck] local cursors
    int* hbase = lds + nbuck;    // [nbuck] this WG's subrange bases
    const int m  = blockIdx.x >> 8;
    const int wg = blockIdx.x & (BIN_WGS - 1);
    const int* rows = m ? rows_a : rows_f;
    const int* cols = m ? cols_a : cols_f;
    const float* vals = m ? vals_a : vals_f;
    const int nE    = m ? na : nf;
    const int chunk = m ? chunk_a : chunk_f;
    int2* cv_tmp = m ? cvt_a : cvt_f;
    const int* bb = bbase + m * (nbuck + 1);
    const int* wc = wgc + ((long long)m * BIN_WGS + wg) * nbuck;
    const int tid = threadIdx.x;
    const long long T = blockDim.x;
    long long start = (long long)wg * chunk;
    long long end = start + chunk;
    if (end > nE) end = nE;
    for (int b = tid; b < nbuck; b += blockDim.x) {
        hbase[b] = bb[b] + wc[b];
        hcnt[b] = 0;
    }
    __syncthreads();
    if (start >= end) return;
    long long i = start + tid;
    for (; i + 3 * T < end; i += 4 * T) {
        int r0 = rows[i], r1 = rows[i + T], r2 = rows[i + 2 * T], r3 = rows[i + 3 * T];
        int c0 = cols[i], c1 = cols[i + T], c2 = cols[i + 2 * T], c3 = cols[i + 3 * T];
        float v0 = vals[i], v1 = vals[i + T], v2 = vals[i + 2 * T], v3 = vals[i + 3 * T];
        int b0 = r0 >> 7, b1 = r1 >> 7, b2 = r2 >> 7, b3 = r3 >> 7;
        int p0 = hbase[b0] + atomicAdd(&hcnt[b0], 1);
        int p1 = hbase[b1] + atomicAdd(&hcnt[b1], 1);
        int p2 = hbase[b2] + atomicAdd(&hcnt[b2], 1);
        int p3 = hbase[b3] + atomicAdd(&hcnt[b3], 1);
        cv_tmp[p0] = make_int2(c0 | ((r0 & (BR - 1)) << 24), __float_as_int(v0));
        cv_tmp[p1] = make_int2(c1 | ((r1 & (BR - 1)) << 24), __float_as_int(v1));
        cv_tmp[p2] = make_int2(c2 | ((r2 & (BR - 1)) << 24), __float_as_int(v2));
        cv_tmp[p3] = make_int2(c3 | ((r3 & (BR - 1)) << 24), __float_as_int(v3));
    }
    for (; i < end; i += T) {
        int r = rows[i];
        int b = r >> 7;
        int p = hbase[b] + atomicAdd(&hcnt[b], 1);
        cv_tmp[p] = make_int2(cols[i] | ((r & (BR - 1)) << 24), __float_as_int(vals[i]));
    }
}

__global__ void reorder2_kernel(const int* __restrict__ bucket_base,
                                const int2* __restrict__ cv_tmp, int2* __restrict__ cv,
                                int* __restrict__ row_ptr, int n) {
    __shared__ int cnt[BR];
    __shared__ int tmp[BR];
    int b = blockIdx.x;
    int rbase = b * BR;
    int tid = threadIdx.x;
    int s = bucket_base[b], e = bucket_base[b + 1];
    if (tid < BR) cnt[tid] = 0;
    __syncthreads();
    for (int i = s + tid; i < e; i += blockDim.x)
        atomicAdd(&cnt[((unsigned)cv_tmp[i].x) >> 24], 1);
    __syncthreads();
    if (tid < BR) tmp[tid] = cnt[tid];
    __syncthreads();
    for (int off = 1; off < BR; off <<= 1) {
        int y = 0;
        if (tid < BR && tid >= off) y = tmp[tid - off];
        __syncthreads();
        if (tid < BR) tmp[tid] += y;
        __syncthreads();
    }
    if (tid < BR) {
        int excl = s + tmp[tid] - cnt[tid];
        if (rbase + tid < n) row_ptr[rbase + tid] = excl;
        cnt[tid] = excl;       // becomes the scatter cursor
    }
    if (tid == 0 && b == gridDim.x - 1) row_ptr[n] = e;
    __syncthreads();
    for (int i = s + tid; i < e; i += blockDim.x) {
        int2 ent = cv_tmp[i];
        int rl = ((unsigned)ent.x) >> 24;
        int p = atomicAdd(&cnt[rl], 1);
        cv[p] = make_int2(ent.x & 0x00FFFFFF, ent.y);
    }
}

// ---------------- W fp16 conversion ----------------

__global__ void wconv_kernel(const float* __restrict__ W, __half2* __restrict__ Wh, int n2) {
    int i = blockIdx.x * blockDim.x + threadIdx.x;
    if (i < n2) Wh[i] = __float22half2_rn(reinterpret_cast<const float2*>(W)[i]);
}

// ---------------- gather-reduce row kernels (4 rows / wave) ----------------
// group g = lane>>4 owns row wid0+g entirely: 16 lanes x 16B cover the row's
// 128 f16 channels; group walks its own CSR range [rs,re) -- no cross-group
// reduce. Rows are contiguous in cv, so one 64-entry scratch window serves
// all 4 rows. Batch-4 named registers keep 4 dwordx4 gathers in flight.

#define ACC8(V, SV) {                                                               \
    float2 f0 = __half22float2(*reinterpret_cast<const __half2*>(&(SV).x));         \
    float2 f1 = __half22float2(*reinterpret_cast<const __half2*>(&(SV).y));         \
    float2 f2 = __half22float2(*reinterpret_cast<const __half2*>(&(SV).z));         \
    float2 f3 = __half22float2(*reinterpret_cast<const __half2*>(&(SV).w));         \
    acc0 += (V) * f0.x; acc1 += (V) * f0.y;                                         \
    acc2 += (V) * f1.x; acc3 += (V) * f1.y;                                         \
    acc4 += (V) * f2.x; acc5 += (V) * f2.y;                                         \
    acc6 += (V) * f3.x; acc7 += (V) * f3.y; }

#define R4_BODY(TBL)                                                                \
    for (int base = s4; base < e4; base += 64) {                                    \
        int idx = base + lane;                                                      \
        mysc[lane] = (idx < e4) ? cv[idx] : 0;                                      \
        int klo = rs > base ? rs : base;                                            \
        int lim = base + 64;                                                        \
        int khi = re < lim ? re : lim;                                              \
        int k = klo;                                                                \
        for (; k + 4 <= khi; k += 4) {                                              \
            long long ck0 = mysc[k - base + 0];                                     \
            long long ck1 = mysc[k - base + 1];                                     \
            long long ck2 = mysc[k - base + 2];                                     \
            long long ck3 = mysc[k - base + 3];                                     \
            float4 sv0 = *reinterpret_cast<const float4*>(TBL + (long long)(int)ck0 * 64 + cl * 4); \
            float4 sv1 = *reinterpret_cast<const float4*>(TBL + (long long)(int)ck1 * 64 + cl * 4); \
            float4 sv2 = *reinterpret_cast<const float4*>(TBL + (long long)(int)ck2 * 64 + cl * 4); \
            float4 sv3 = *reinterpret_cast<const float4*>(TBL + (long long)(int)ck3 * 64 + cl * 4); \
            float v0 = __int_as_float((int)(ck0 >> 32));                            \
            float v1 = __int_as_float((int)(ck1 >> 32));                            \
            float v2 = __int_as_float((int)(ck2 >> 32));                            \
            float v3 = __int_as_float((int)(ck3 >> 32));                            \
            ACC8(v0, sv0); ACC8(v1, sv1); ACC8(v2, sv2); ACC8(v3, sv3);             \
        }                                                                           \
        for (; k < khi; k++) {                                                      \
            long long ck = mysc[k - base];                                          \
            float v = __int_as_float((int)(ck >> 32));                              \
            float4 sv = *reinterpret_cast<const float4*>(TBL + (long long)(int)ck * 64 + cl * 4); \
            ACC8(v, sv);                                                            \
        }                                                                           \
    }

#define R4_PROLOGUE()                                                               \
    int gtid = blockIdx.x * blockDim.x + threadIdx.x;                               \
    int wid0 = (gtid >> 6) << 2;                                                    \
    int lane = gtid & 63;                                                           \
    if (wid0 >= n) return;                                                          \
    int g = lane >> 4;                                                              \
    int cl = lane & 15;                                                             \
    long long* mysc = sc + ((threadIdx.x >> 6) << 6);                               \
    int r = wid0 + g;                                                               \
    bool valid = (r < n);                                                           \
    int rv = valid ? r : (n - 1);                                                   \
    int rs = row_ptr[rv];                                                           \
    int re = row_ptr[rv + 1];                                                       \
    if (!valid) { rs = 0; re = 0; }                                                 \
    int s4 = row_ptr[wid0];                                                         \
    int rend = wid0 + 4 < n ? wid0 + 4 : n;                                         \
    int e4 = row_ptr[rend];                                                         \
    float acc0 = 0.f, acc1 = 0.f, acc2 = 0.f, acc3 = 0.f;                           \
    float acc4 = 0.f, acc5 = 0.f, acc6 = 0.f, acc7 = 0.f;

__global__ void spmm_r4_kernel(const int* __restrict__ row_ptr,
                               const long long* __restrict__ cv,
                               const __half2* __restrict__ Wh,   // [in_ch][64] half2
                               const float* __restrict__ bias,
                               __half2* __restrict__ outh, int n) {
    __shared__ long long sc[4 * 64];
    R4_PROLOGUE()
    R4_BODY(Wh)
    if (valid) {
        const float4* bp = reinterpret_cast<const float4*>(bias);
        float4 b0 = bp[cl * 2], b1 = bp[cl * 2 + 1];
        acc0 = fmaxf(acc0 + b0.x, 0.f); acc1 = fmaxf(acc1 + b0.y, 0.f);
        acc2 = fmaxf(acc2 + b0.z, 0.f); acc3 = fmaxf(acc3 + b0.w, 0.f);
        acc4 = fmaxf(acc4 + b1.x, 0.f); acc5 = fmaxf(acc5 + b1.y, 0.f);
        acc6 = fmaxf(acc6 + b1.z, 0.f); acc7 = fmaxf(acc7 + b1.w, 0.f);
        __half2 h0 = __floats2half2_rn(acc0, acc1);
        __half2 h1 = __floats2half2_rn(acc2, acc3);
        __half2 h2 = __floats2half2_rn(acc4, acc5);
        __half2 h3 = __floats2half2_rn(acc6, acc7);
        float4 ov;
        *reinterpret_cast<__half2*>(&ov.x) = h0;
        *reinterpret_cast<__half2*>(&ov.y) = h1;
        *reinterpret_cast<__half2*>(&ov.z) = h2;
        *reinterpret_cast<__half2*>(&ov.w) = h3;
        *reinterpret_cast<float4*>(outh + (long long)r * 64 + cl * 4) = ov;
    }
}

__global__ void prop_r4_h2h_kernel(const int* __restrict__ row_ptr,
                                   const long long* __restrict__ cv,
                                   const __half2* __restrict__ src, __half2* __restrict__ dst,
                                   int n) {
    __shared__ long long sc[4 * 64];
    R4_PROLOGUE()
    R4_BODY(src)
    if (valid) {
        __half2 h0 = __floats2half2_rn(acc0, acc1);
        __half2 h1 = __floats2half2_rn(acc2, acc3);
        __half2 h2 = __floats2half2_rn(acc4, acc5);
        __half2 h3 = __floats2half2_rn(acc6, acc7);
        float4 ov;
        *reinterpret_cast<__half2*>(&ov.x) = h0;
        *reinterpret_cast<__half2*>(&ov.y) = h1;
        *reinterpret_cast<__half2*>(&ov.z) = h2;
        *reinterpret_cast<__half2*>(&ov.w) = h3;
        *reinterpret_cast<float4*>(dst + (long long)r * 64 + cl * 4) = ov;
    }
}

__global__ void prop_r4_h2f_kernel(const int* __restrict__ row_ptr,
                                   const long long* __restrict__ cv,
                                   const __half2* __restrict__ src, float* __restrict__ dst,
                                   int n) {
    __shared__ long long sc[4 * 64];
    R4_PROLOGUE()
    R4_BODY(src)
    if (valid) {
        float4 o0 = make_float4(acc0, acc1, acc2, acc3);
        float4 o1 = make_float4(acc4, acc5, acc6, acc7);
        float4* dp = reinterpret_cast<float4*>(dst + (long long)r * 128 + cl * 8);
        dp[0] = o0;
        dp[1] = o1;
    }
}

// ---------------- round-1 fallback (atomic scatter, f32) ----------------

__global__ void bias_relu_kernel(float* __restrict__ buf, const float* __restrict__ bias,
                                 long long total) {
    long long i = ((long long)blockIdx.x * blockDim.x + threadIdx.x) * 4;
    if (i >= total) return;
    float4 v = *reinterpret_cast<float4*>(buf + i);
    int ch = (int)(i & (CH - 1));
    float4 b = *reinterpret_cast<const float4*>(bias + ch);
    v.x = fmaxf(v.x + b.x, 0.0f);
    v.y = fmaxf(v.y + b.y, 0.0f);
    v.z = fmaxf(v.z + b.z, 0.0f);
    v.w = fmaxf(v.w + b.w, 0.0f);
    *reinterpret_cast<float4*>(buf + i) = v;
}

__global__ void spmm_scatter_kernel(const int* __restrict__ rows, const int* __restrict__ cols,
                                    const float* __restrict__ vals, const float* __restrict__ weight,
                                    float* __restrict__ out, int nnz) {
    long long tid = (long long)blockIdx.x * blockDim.x + threadIdx.x;
    if (tid >= (long long)nnz * 32) return;
    int e = (int)(tid >> 5), lane = (int)(tid & 31);
    int r = rows[e], c = cols[e];
    float v = vals[e];
    const float4 w = *reinterpret_cast<const float4*>(weight + (long long)c * CH + lane * 4);
    float* dst = out + (long long)r * CH + lane * 4;
    unsafeAtomicAdd(dst + 0, v * w.x);
    unsafeAtomicAdd(dst + 1, v * w.y);
    unsafeAtomicAdd(dst + 2, v * w.z);
    unsafeAtomicAdd(dst + 3, v * w.w);
}

__global__ void prop_scatter_kernel(const int* __restrict__ rows, const int* __restrict__ cols,
                                    const float* __restrict__ vals, const float* __restrict__ src,
                                    float* __restrict__ dst, int ne) {
    long long tid = (long long)blockIdx.x * blockDim.x + threadIdx.x;
    if (tid >= (long long)ne * 32) return;
    int e = (int)(tid >> 5), lane = (int)(tid & 31);
    int r = rows[e], c = cols[e];
    float v = vals[e];
    const float4 s = *reinterpret_cast<const float4*>(src + (long long)c * CH + lane * 4);
    float* d = dst + (long long)r * CH + lane * 4;
    unsafeAtomicAdd(d + 0, v * s.x);
    unsafeAtomicAdd(d + 1, v * s.y);
    unsafeAtomicAdd(d + 2, v * s.z);
    unsafeAtomicAdd(d + 3, v * s.w);
}

// ---------------- launch ----------------

static inline size_t align64(size_t x) { return (x + 63) & ~(size_t)63; }

extern "C" void kernel_launch(void* const* d_in, const int* in_sizes, int n_in,
                              void* d_out, int out_size, void* d_ws, size_t ws_size,
                              hipStream_t stream) {
    const int*   feat_rows = (const int*)d_in[0];
    const int*   feat_cols = (const int*)d_in[1];
    const float* feat_vals = (const float*)d_in[2];
    const int*   adj_rows  = (const int*)d_in[3];
    const int*   adj_cols  = (const int*)d_in[4];
    const float* adj_vals  = (const float*)d_in[5];
    const float* weight    = (const float*)d_in[6];
    const float* bias      = (const float*)d_in[7];

    const int nnz = in_sizes[0];
    const int ne  = in_sizes[3];
    const int n   = out_size / CH;   // n_nodes
    const int in_ch = in_sizes[6] / CH;

    float* out = (float*)d_out;
    char*  ws  = (char*)d_ws;

    const size_t NBF = (size_t)n * CH * sizeof(float);
    const size_t NBH = (size_t)n * CH * sizeof(__half);
    const long long total_elems = (long long)n * CH;
    const int BLK = 256;
    const int ew_blocks = (int)((total_elems / 4 + BLK - 1) / BLK);
    const int maxe = nnz > ne ? nnz : ne;
    const int nbuck = (n + BR - 1) / BR;
    const size_t bin_lds = (size_t)nbuck * 2 * sizeof(int);

    // ws layout (fast path); cv_tmp_feat/adj = lo/hi halves of pingh
    size_t off = 0;
    __half2* baseh   = (__half2*)(ws + off); off += align64(NBH);
    __half2* pingh   = (__half2*)(ws + off); off += align64(NBH);
    int*   row_ptr  = (int*)(ws + off);   off += align64(((size_t)n + 1) * 4);
    int*   bcounts  = (int*)(ws + off);   off += align64((size_t)2 * nbuck * 4);
    int*   bbase    = (int*)(ws + off);   off += align64((size_t)2 * (nbuck + 1) * 4);
    int*   wgc      = (int*)(ws + off);   off += align64((size_t)2 * BIN_WGS * nbuck * 4);
    __half2* Wh     = (__half2*)(ws + off); off += align64((size_t)in_ch * 64 * 4);
    int2*  cv       = (int2*)(ws + off);  off += align64((size_t)maxe * 8);
    int2*  cvt_f    = (int2*)pingh;
    int2*  cvt_a    = (int2*)((char*)pingh + (size_t)nnz * 8);
    const bool fast = (ws_size >= off) && (nbuck <= SCAN_BLK) &&
                      (n <= (1 << 24)) && (bin_lds <= 64 * 1024) &&
                      (in_ch <= (1 << 22)) &&
                      (((size_t)nnz + (size_t)ne) * 8 <= NBH);

    if (fast) {
        const int nwaves = (n + 3) / 4;
        const int row_blocks = (int)(((long long)nwaves * 64 + BLK - 1) / BLK);
        const int chunk_feat = (nnz + BIN_WGS - 1) / BIN_WGS;
        const int chunk_adj  = (ne + BIN_WGS - 1) / BIN_WGS;
        const int w2 = in_ch * 64;
        const size_t hist_lds = (size_t)nbuck * sizeof(int);
        const int wgscan_blocks = (2 * nbuck + 3) / 4;   // 4 waves / 256-thread block

        // --- W fp16 conversion ---
        wconv_kernel<<<(w2 + BLK - 1) / BLK, BLK, 0, stream>>>(weight, Wh, w2);

        // --- merged CSR build (both matrices) ---
        hist2_kernel<<<2 * BIN_WGS, BIN_THR, hist_lds, stream>>>(
            feat_rows, nnz, chunk_feat, adj_rows, ne, chunk_adj, wgc, nbuck);
        wgscan2_kernel<<<wgscan_blocks, 256, 0, stream>>>(wgc, bcounts, nbuck, BIN_WGS);
        bucket_scan2_kernel<<<2, SCAN_BLK, 0, stream>>>(bcounts, bbase, nbuck);
        bin2_kernel<<<2 * BIN_WGS, BIN_THR, bin_lds, stream>>>(
            feat_rows, feat_cols, feat_vals, nnz, chunk_feat,
            adj_rows, adj_cols, adj_vals, ne, chunk_adj,
            bbase, wgc, cvt_f, cvt_a, nbuck);

        // --- feat: reorder -> spmm ---
        reorder2_kernel<<<nbuck, BIN_THR, 0, stream>>>(bbase, cvt_f, cv, row_ptr, n);
        spmm_r4_kernel<<<row_blocks, BLK, 0, stream>>>(
            row_ptr, (const long long*)cv, Wh, bias, baseh, n);

        // --- adj: reorder (reuses cv + row_ptr after spmm) -> prop x2 ---
        reorder2_kernel<<<nbuck, BIN_THR, 0, stream>>>(bbase + (nbuck + 1), cvt_a, cv, row_ptr, n);
        prop_r4_h2h_kernel<<<row_blocks, BLK, 0, stream>>>(
            row_ptr, (const long long*)cv, baseh, pingh, n);
        prop_r4_h2f_kernel<<<row_blocks, BLK, 0, stream>>>(
            row_ptr, (const long long*)cv, pingh, out, n);
    } else {
        // round-1 fallback: atomic scatter (f32)
        float* ping = (float*)ws;
        const int spmm_blocks = (int)(((long long)nnz * 32 + BLK - 1) / BLK);
        const int prop_blocks = (int)(((long long)ne * 32 + BLK - 1) / BLK);
        hipMemsetAsync(d_out, 0, NBF, stream);
        spmm_scatter_kernel<<<spmm_blocks, BLK, 0, stream>>>(feat_rows, feat_cols, feat_vals,
                                                             weight, out, nnz);
        bias_relu_kernel<<<ew_blocks, BLK, 0, stream>>>(out, bias, total_elems);
        hipMemsetAsync(ping, 0, NBF, stream);
        prop_scatter_kernel<<<prop_blocks, BLK, 0, stream>>>(adj_rows, adj_cols, adj_vals,
                                                             out, ping, ne);
        hipMemsetAsync(d_out, 0, NBF, stream);
        prop_scatter_kernel<<<prop_blocks, BLK, 0, stream>>>(adj_rows, adj_cols, adj_vals,
                                                             ping, out, ne);
    }
}

// Round 15
// 231.453 us; speedup vs baseline: 34.7176x; 1.0035x over previous
//
#include <hip/hip_runtime.h>
#include <hip/hip_fp16.h>

// SparseNGCNLayer: base = relu(SpMM(feat, W) + bias); base = A @ base (x2)
// Round 15: MLP boost for the L3-gather-bound kernels.
//   - batch-8 named-register gathers (8 dwordx4 in flight per 16-lane group)
//   - scratch-window prefetch: next 64 CSR entries loaded into a register at
//     window start; latency hides under current window's gather+ACC work.
// FETCH floor (8 XCDs x 25.6MB table) is architectural; this round targets
// the stream *rate* (3.7 -> ~4.6 TB/s). CSR build unchanged.

#define CH 128
#define BR 128            // rows per bucket (rlocal fits in 7 bits)
#define SCAN_BLK 1024
#define BIN_WGS 256       // multisplit workgroups per matrix
#define BIN_THR 512

// ---------------- CSR build (merged feat+adj) ----------------

__global__ void hist2_kernel(const int* __restrict__ rows_f, int nf, int chunk_f,
                             const int* __restrict__ rows_a, int na, int chunk_a,
                             int* __restrict__ wgc, int nbuck) {
    extern __shared__ int hcnt[];
    const int m  = blockIdx.x >> 8;
    const int wg = blockIdx.x & (BIN_WGS - 1);
    const int* rows = m ? rows_a : rows_f;
    const int nE    = m ? na : nf;
    const int chunk = m ? chunk_a : chunk_f;
    const int tid = threadIdx.x;
    const long long T = blockDim.x;
    long long start = (long long)wg * chunk;
    long long end = start + chunk;
    if (end > nE) end = nE;
    for (int b = tid; b < nbuck; b += blockDim.x) hcnt[b] = 0;
    __syncthreads();
    if (start < end) {
        long long i = start + tid;
        for (; i + 3 * T < end; i += 4 * T) {
            int r0 = rows[i], r1 = rows[i + T], r2 = rows[i + 2 * T], r3 = rows[i + 3 * T];
            atomicAdd(&hcnt[r0 >> 7], 1);
            atomicAdd(&hcnt[r1 >> 7], 1);
            atomicAdd(&hcnt[r2 >> 7], 1);
            atomicAdd(&hcnt[r3 >> 7], 1);
        }
        for (; i < end; i += T) atomicAdd(&hcnt[rows[i] >> 7], 1);
    }
    __syncthreads();
    int* out = wgc + ((long long)m * BIN_WGS + wg) * nbuck;
    for (int b = tid; b < nbuck; b += blockDim.x) out[b] = hcnt[b];
}

__global__ void wgscan2_kernel(int* __restrict__ wgc, int* __restrict__ bcounts,
                               int nbuck, int nwg) {
    int wpb = blockDim.x >> 6;
    int idx = blockIdx.x * wpb + (threadIdx.x >> 6);
    int lane = threadIdx.x & 63;
    if (idx >= 2 * nbuck) return;
    int m = (idx >= nbuck) ? 1 : 0;
    int b = idx - m * nbuck;
    int* base = wgc + (long long)m * nwg * nbuck + b;
    int carry = 0;
    for (int w0 = 0; w0 < nwg; w0 += 64) {
        int wg = w0 + lane;
        int v = (wg < nwg) ? base[(long long)wg * nbuck] : 0;
        int x = v;
        #pragma unroll
        for (int off = 1; off < 64; off <<= 1) {
            int y = __shfl_up(x, off);
            if (lane >= off) x += y;
        }
        if (wg < nwg) base[(long long)wg * nbuck] = carry + x - v;  // exclusive
        carry += __shfl(x, 63);
    }
    if (lane == 0) bcounts[idx] = carry;
}

__global__ void bucket_scan2_kernel(const int* __restrict__ bcounts,
                                    int* __restrict__ bbase, int nbuck) {
    __shared__ int lds[SCAN_BLK];
    int m = blockIdx.x;
    int tid = threadIdx.x;
    int x = (tid < nbuck) ? bcounts[m * nbuck + tid] : 0;
    lds[tid] = x;
    __syncthreads();
    for (int off = 1; off < SCAN_BLK; off <<= 1) {
        int y = (tid >= off) ? lds[tid - off] : 0;
        __syncthreads();
        lds[tid] += y;
        __syncthreads();
    }
    int* bb = bbase + m * (nbuck + 1);
    if (tid < nbuck) bb[tid] = lds[tid] - x;
    if (tid == nbuck - 1) bb[nbuck] = lds[tid];
}

__global__ void bin2_kernel(const int* __restrict__ rows_f, const int* __restrict__ cols_f,
                            const float* __restrict__ vals_f, int nf, int chunk_f,
                            const int* __restrict__ rows_a, const int* __restrict__ cols_a,
                            const float* __restrict__ vals_a, int na, int chunk_a,
                            const int* __restrict__ bbase, const int* __restrict__ wgc,
                            int2* __restrict__ cvt_f, int2* __restrict__ cvt_a, int nbuck) {
    extern __shared__ int lds[];
    int* hcnt  = lds;            // [nbuck] local cursors
    int* hbase = lds + nbuck;    // [nbuck] this WG's subrange bases
    const int m  = blockIdx.x >> 8;
    const int wg = blockIdx.x & (BIN_WGS - 1);
    const int* rows = m ? rows_a : rows_f;
    const int* cols = m ? cols_a : cols_f;
    const float* vals = m ? vals_a : vals_f;
    const int nE    = m ? na : nf;
    const int chunk = m ? chunk_a : chunk_f;
    int2* cv_tmp = m ? cvt_a : cvt_f;
    const int* bb = bbase + m * (nbuck + 1);
    const int* wc = wgc + ((long long)m * BIN_WGS + wg) * nbuck;
    const int tid = threadIdx.x;
    const long long T = blockDim.x;
    long long start = (long long)wg * chunk;
    long long end = start + chunk;
    if (end > nE) end = nE;
    for (int b = tid; b < nbuck; b += blockDim.x) {
        hbase[b] = bb[b] + wc[b];
        hcnt[b] = 0;
    }
    __syncthreads();
    if (start >= end) return;
    long long i = start + tid;
    for (; i + 3 * T < end; i += 4 * T) {
        int r0 = rows[i], r1 = rows[i + T], r2 = rows[i + 2 * T], r3 = rows[i + 3 * T];
        int c0 = cols[i], c1 = cols[i + T], c2 = cols[i + 2 * T], c3 = cols[i + 3 * T];
        float v0 = vals[i], v1 = vals[i + T], v2 = vals[i + 2 * T], v3 = vals[i + 3 * T];
        int b0 = r0 >> 7, b1 = r1 >> 7, b2 = r2 >> 7, b3 = r3 >> 7;
        int p0 = hbase[b0] + atomicAdd(&hcnt[b0], 1);
        int p1 = hbase[b1] + atomicAdd(&hcnt[b1], 1);
        int p2 = hbase[b2] + atomicAdd(&hcnt[b2], 1);
        int p3 = hbase[b3] + atomicAdd(&hcnt[b3], 1);
        cv_tmp[p0] = make_int2(c0 | ((r0 & (BR - 1)) << 24), __float_as_int(v0));
        cv_tmp[p1] = make_int2(c1 | ((r1 & (BR - 1)) << 24), __float_as_int(v1));
        cv_tmp[p2] = make_int2(c2 | ((r2 & (BR - 1)) << 24), __float_as_int(v2));
        cv_tmp[p3] = make_int2(c3 | ((r3 & (BR - 1)) << 24), __float_as_int(v3));
    }
    for (; i < end; i += T) {
        int r = rows[i];
        int b = r >> 7;
        int p = hbase[b] + atomicAdd(&hcnt[b], 1);
        cv_tmp[p] = make_int2(cols[i] | ((r & (BR - 1)) << 24), __float_as_int(vals[i]));
    }
}

__global__ void reorder2_kernel(const int* __restrict__ bucket_base,
                                const int2* __restrict__ cv_tmp, int2* __restrict__ cv,
                                int* __restrict__ row_ptr, int n) {
    __shared__ int cnt[BR];
    __shared__ int tmp[BR];
    int b = blockIdx.x;
    int rbase = b * BR;
    int tid = threadIdx.x;
    int s = bucket_base[b], e = bucket_base[b + 1];
    if (tid < BR) cnt[tid] = 0;
    __syncthreads();
    for (int i = s + tid; i < e; i += blockDim.x)
        atomicAdd(&cnt[((unsigned)cv_tmp[i].x) >> 24], 1);
    __syncthreads();
    if (tid < BR) tmp[tid] = cnt[tid];
    __syncthreads();
    for (int off = 1; off < BR; off <<= 1) {
        int y = 0;
        if (tid < BR && tid >= off) y = tmp[tid - off];
        __syncthreads();
        if (tid < BR) tmp[tid] += y;
        __syncthreads();
    }
    if (tid < BR) {
        int excl = s + tmp[tid] - cnt[tid];
        if (rbase + tid < n) row_ptr[rbase + tid] = excl;
        cnt[tid] = excl;       // becomes the scatter cursor
    }
    if (tid == 0 && b == gridDim.x - 1) row_ptr[n] = e;
    __syncthreads();
    for (int i = s + tid; i < e; i += blockDim.x) {
        int2 ent = cv_tmp[i];
        int rl = ((unsigned)ent.x) >> 24;
        int p = atomicAdd(&cnt[rl], 1);
        cv[p] = make_int2(ent.x & 0x00FFFFFF, ent.y);
    }
}

// ---------------- W fp16 conversion ----------------

__global__ void wconv_kernel(const float* __restrict__ W, __half2* __restrict__ Wh, int n2) {
    int i = blockIdx.x * blockDim.x + threadIdx.x;
    if (i < n2) Wh[i] = __float22half2_rn(reinterpret_cast<const float2*>(W)[i]);
}

// ---------------- gather-reduce row kernels (4 rows / wave, batch-8) --------
// group g = lane>>4 owns row wid0+g entirely; 16 lanes x 16B cover the row's
// 128 f16 channels. Rows contiguous in cv -> one 64-entry scratch window per
// wave, prefetched one window ahead. Batch-8 named registers keep 8 dwordx4
// gathers in flight per group.

#define ACC8(V, SV) {                                                               \
    float2 f0 = __half22float2(*reinterpret_cast<const __half2*>(&(SV).x));         \
    float2 f1 = __half22float2(*reinterpret_cast<const __half2*>(&(SV).y));         \
    float2 f2 = __half22float2(*reinterpret_cast<const __half2*>(&(SV).z));         \
    float2 f3 = __half22float2(*reinterpret_cast<const __half2*>(&(SV).w));         \
    acc0 += (V) * f0.x; acc1 += (V) * f0.y;                                         \
    acc2 += (V) * f1.x; acc3 += (V) * f1.y;                                         \
    acc4 += (V) * f2.x; acc5 += (V) * f2.y;                                         \
    acc6 += (V) * f3.x; acc7 += (V) * f3.y; }

#define GLD(CK) *reinterpret_cast<const float4*>(tbl + (long long)(int)(CK) * 64 + cl * 4)

#define R4_BODY()                                                                   \
    long long nextv = (s4 + lane < e4) ? cv[s4 + lane] : 0;                         \
    for (int base = s4; base < e4; base += 64) {                                    \
        mysc[lane] = nextv;                                                         \
        int nidx = base + 64 + lane;                                                \
        nextv = (nidx < e4) ? cv[nidx] : 0;  /* prefetch next window */             \
        int klo = rs > base ? rs : base;                                            \
        int lim = base + 64;                                                        \
        int khi = re < lim ? re : lim;                                              \
        int k = klo;                                                                \
        for (; k + 8 <= khi; k += 8) {                                              \
            long long ck0 = mysc[k - base + 0];                                     \
            long long ck1 = mysc[k - base + 1];                                     \
            long long ck2 = mysc[k - base + 2];                                     \
            long long ck3 = mysc[k - base + 3];                                     \
            long long ck4 = mysc[k - base + 4];                                     \
            long long ck5 = mysc[k - base + 5];                                     \
            long long ck6 = mysc[k - base + 6];                                     \
            long long ck7 = mysc[k - base + 7];                                     \
            float4 sv0 = GLD(ck0); float4 sv1 = GLD(ck1);                           \
            float4 sv2 = GLD(ck2); float4 sv3 = GLD(ck3);                           \
            float4 sv4 = GLD(ck4); float4 sv5 = GLD(ck5);                           \
            float4 sv6 = GLD(ck6); float4 sv7 = GLD(ck7);                           \
            float v0 = __int_as_float((int)(ck0 >> 32));                            \
            float v1 = __int_as_float((int)(ck1 >> 32));                            \
            float v2 = __int_as_float((int)(ck2 >> 32));                            \
            float v3 = __int_as_float((int)(ck3 >> 32));                            \
            float v4 = __int_as_float((int)(ck4 >> 32));                            \
            float v5 = __int_as_float((int)(ck5 >> 32));                            \
            float v6 = __int_as_float((int)(ck6 >> 32));                            \
            float v7 = __int_as_float((int)(ck7 >> 32));                            \
            ACC8(v0, sv0); ACC8(v1, sv1); ACC8(v2, sv2); ACC8(v3, sv3);             \
            ACC8(v4, sv4); ACC8(v5, sv5); ACC8(v6, sv6); ACC8(v7, sv7);             \
        }                                                                           \
        for (; k + 4 <= khi; k += 4) {                                              \
            long long ck0 = mysc[k - base + 0];                                     \
            long long ck1 = mysc[k - base + 1];                                     \
            long long ck2 = mysc[k - base + 2];                                     \
            long long ck3 = mysc[k - base + 3];                                     \
            float4 sv0 = GLD(ck0); float4 sv1 = GLD(ck1);                           \
            float4 sv2 = GLD(ck2); float4 sv3 = GLD(ck3);                           \
            float v0 = __int_as_float((int)(ck0 >> 32));                            \
            float v1 = __int_as_float((int)(ck1 >> 32));                            \
            float v2 = __int_as_float((int)(ck2 >> 32));                            \
            float v3 = __int_as_float((int)(ck3 >> 32));                            \
            ACC8(v0, sv0); ACC8(v1, sv1); ACC8(v2, sv2); ACC8(v3, sv3);             \
        }                                                                           \
        for (; k < khi; k++) {                                                      \
            long long ck = mysc[k - base];                                          \
            float v = __int_as_float((int)(ck >> 32));                              \
            float4 sv = GLD(ck);                                                    \
            ACC8(v, sv);                                                            \
        }                                                                           \
    }

#define R4_PROLOGUE()                                                               \
    int gtid = blockIdx.x * blockDim.x + threadIdx.x;                               \
    int wid0 = (gtid >> 6) << 2;                                                    \
    int lane = gtid & 63;                                                           \
    if (wid0 >= n) return;                                                          \
    int g = lane >> 4;                                                              \
    int cl = lane & 15;                                                             \
    long long* mysc = sc + ((threadIdx.x >> 6) << 6);                               \
    int r = wid0 + g;                                                               \
    bool valid = (r < n);                                                           \
    int rv = valid ? r : (n - 1);                                                   \
    int rs = row_ptr[rv];                                                           \
    int re = row_ptr[rv + 1];                                                       \
    if (!valid) { rs = 0; re = 0; }                                                 \
    int s4 = row_ptr[wid0];                                                         \
    int rend = wid0 + 4 < n ? wid0 + 4 : n;                                         \
    int e4 = row_ptr[rend];                                                         \
    float acc0 = 0.f, acc1 = 0.f, acc2 = 0.f, acc3 = 0.f;                           \
    float acc4 = 0.f, acc5 = 0.f, acc6 = 0.f, acc7 = 0.f;

__global__ void spmm_r4_kernel(const int* __restrict__ row_ptr,
                               const long long* __restrict__ cv,
                               const __half2* __restrict__ tbl,   // Wh [in_ch][64] half2
                               const float* __restrict__ bias,
                               __half2* __restrict__ outh, int n) {
    __shared__ long long sc[4 * 64];
    R4_PROLOGUE()
    R4_BODY()
    if (valid) {
        const float4* bp = reinterpret_cast<const float4*>(bias);
        float4 b0 = bp[cl * 2], b1 = bp[cl * 2 + 1];
        acc0 = fmaxf(acc0 + b0.x, 0.f); acc1 = fmaxf(acc1 + b0.y, 0.f);
        acc2 = fmaxf(acc2 + b0.z, 0.f); acc3 = fmaxf(acc3 + b0.w, 0.f);
        acc4 = fmaxf(acc4 + b1.x, 0.f); acc5 = fmaxf(acc5 + b1.y, 0.f);
        acc6 = fmaxf(acc6 + b1.z, 0.f); acc7 = fmaxf(acc7 + b1.w, 0.f);
        __half2 h0 = __floats2half2_rn(acc0, acc1);
        __half2 h1 = __floats2half2_rn(acc2, acc3);
        __half2 h2 = __floats2half2_rn(acc4, acc5);
        __half2 h3 = __floats2half2_rn(acc6, acc7);
        float4 ov;
        *reinterpret_cast<__half2*>(&ov.x) = h0;
        *reinterpret_cast<__half2*>(&ov.y) = h1;
        *reinterpret_cast<__half2*>(&ov.z) = h2;
        *reinterpret_cast<__half2*>(&ov.w) = h3;
        *reinterpret_cast<float4*>(outh + (long long)r * 64 + cl * 4) = ov;
    }
}

__global__ void prop_r4_h2h_kernel(const int* __restrict__ row_ptr,
                                   const long long* __restrict__ cv,
                                   const __half2* __restrict__ tbl, __half2* __restrict__ dst,
                                   int n) {
    __shared__ long long sc[4 * 64];
    R4_PROLOGUE()
    R4_BODY()
    if (valid) {
        __half2 h0 = __floats2half2_rn(acc0, acc1);
        __half2 h1 = __floats2half2_rn(acc2, acc3);
        __half2 h2 = __floats2half2_rn(acc4, acc5);
        __half2 h3 = __floats2half2_rn(acc6, acc7);
        float4 ov;
        *reinterpret_cast<__half2*>(&ov.x) = h0;
        *reinterpret_cast<__half2*>(&ov.y) = h1;
        *reinterpret_cast<__half2*>(&ov.z) = h2;
        *reinterpret_cast<__half2*>(&ov.w) = h3;
        *reinterpret_cast<float4*>(dst + (long long)r * 64 + cl * 4) = ov;
    }
}

__global__ void prop_r4_h2f_kernel(const int* __restrict__ row_ptr,
                                   const long long* __restrict__ cv,
                                   const __half2* __restrict__ tbl, float* __restrict__ dst,
                                   int n) {
    __shared__ long long sc[4 * 64];
    R4_PROLOGUE()
    R4_BODY()
    if (valid) {
        float4 o0 = make_float4(acc0, acc1, acc2, acc3);
        float4 o1 = make_float4(acc4, acc5, acc6, acc7);
        float4* dp = reinterpret_cast<float4*>(dst + (long long)r * 128 + cl * 8);
        dp[0] = o0;
        dp[1] = o1;
    }
}

// ---------------- round-1 fallback (atomic scatter, f32) ----------------

__global__ void bias_relu_kernel(float* __restrict__ buf, const float* __restrict__ bias,
                                 long long total) {
    long long i = ((long long)blockIdx.x * blockDim.x + threadIdx.x) * 4;
    if (i >= total) return;
    float4 v = *reinterpret_cast<float4*>(buf + i);
    int ch = (int)(i & (CH - 1));
    float4 b = *reinterpret_cast<const float4*>(bias + ch);
    v.x = fmaxf(v.x + b.x, 0.0f);
    v.y = fmaxf(v.y + b.y, 0.0f);
    v.z = fmaxf(v.z + b.z, 0.0f);
    v.w = fmaxf(v.w + b.w, 0.0f);
    *reinterpret_cast<float4*>(buf + i) = v;
}

__global__ void spmm_scatter_kernel(const int* __restrict__ rows, const int* __restrict__ cols,
                                    const float* __restrict__ vals, const float* __restrict__ weight,
                                    float* __restrict__ out, int nnz) {
    long long tid = (long long)blockIdx.x * blockDim.x + threadIdx.x;
    if (tid >= (long long)nnz * 32) return;
    int e = (int)(tid >> 5), lane = (int)(tid & 31);
    int r = rows[e], c = cols[e];
    float v = vals[e];
    const float4 w = *reinterpret_cast<const float4*>(weight + (long long)c * CH + lane * 4);
    float* dst = out + (long long)r * CH + lane * 4;
    unsafeAtomicAdd(dst + 0, v * w.x);
    unsafeAtomicAdd(dst + 1, v * w.y);
    unsafeAtomicAdd(dst + 2, v * w.z);
    unsafeAtomicAdd(dst + 3, v * w.w);
}

__global__ void prop_scatter_kernel(const int* __restrict__ rows, const int* __restrict__ cols,
                                    const float* __restrict__ vals, const float* __restrict__ src,
                                    float* __restrict__ dst, int ne) {
    long long tid = (long long)blockIdx.x * blockDim.x + threadIdx.x;
    if (tid >= (long long)ne * 32) return;
    int e = (int)(tid >> 5), lane = (int)(tid & 31);
    int r = rows[e], c = cols[e];
    float v = vals[e];
    const float4 s = *reinterpret_cast<const float4*>(src + (long long)c * CH + lane * 4);
    float* d = dst + (long long)r * CH + lane * 4;
    unsafeAtomicAdd(d + 0, v * s.x);
    unsafeAtomicAdd(d + 1, v * s.y);
    unsafeAtomicAdd(d + 2, v * s.z);
    unsafeAtomicAdd(d + 3, v * s.w);
}

// ---------------- launch ----------------

static inline size_t align64(size_t x) { return (x + 63) & ~(size_t)63; }

extern "C" void kernel_launch(void* const* d_in, const int* in_sizes, int n_in,
                              void* d_out, int out_size, void* d_ws, size_t ws_size,
                              hipStream_t stream) {
    const int*   feat_rows = (const int*)d_in[0];
    const int*   feat_cols = (const int*)d_in[1];
    const float* feat_vals = (const float*)d_in[2];
    const int*   adj_rows  = (const int*)d_in[3];
    const int*   adj_cols  = (const int*)d_in[4];
    const float* adj_vals  = (const float*)d_in[5];
    const float* weight    = (const float*)d_in[6];
    const float* bias      = (const float*)d_in[7];

    const int nnz = in_sizes[0];
    const int ne  = in_sizes[3];
    const int n   = out_size / CH;   // n_nodes
    const int in_ch = in_sizes[6] / CH;

    float* out = (float*)d_out;
    char*  ws  = (char*)d_ws;

    const size_t NBF = (size_t)n * CH * sizeof(float);
    const size_t NBH = (size_t)n * CH * sizeof(__half);
    const long long total_elems = (long long)n * CH;
    const int BLK = 256;
    const int ew_blocks = (int)((total_elems / 4 + BLK - 1) / BLK);
    const int maxe = nnz > ne ? nnz : ne;
    const int nbuck = (n + BR - 1) / BR;
    const size_t bin_lds = (size_t)nbuck * 2 * sizeof(int);

    // ws layout (fast path); cv_tmp_feat/adj = lo/hi halves of pingh
    size_t off = 0;
    __half2* baseh   = (__half2*)(ws + off); off += align64(NBH);
    __half2* pingh   = (__half2*)(ws + off); off += align64(NBH);
    int*   row_ptr  = (int*)(ws + off);   off += align64(((size_t)n + 1) * 4);
    int*   bcounts  = (int*)(ws + off);   off += align64((size_t)2 * nbuck * 4);
    int*   bbase    = (int*)(ws + off);   off += align64((size_t)2 * (nbuck + 1) * 4);
    int*   wgc      = (int*)(ws + off);   off += align64((size_t)2 * BIN_WGS * nbuck * 4);
    __half2* Wh     = (__half2*)(ws + off); off += align64((size_t)in_ch * 64 * 4);
    int2*  cv       = (int2*)(ws + off);  off += align64((size_t)maxe * 8);
    int2*  cvt_f    = (int2*)pingh;
    int2*  cvt_a    = (int2*)((char*)pingh + (size_t)nnz * 8);
    const bool fast = (ws_size >= off) && (nbuck <= SCAN_BLK) &&
                      (n <= (1 << 24)) && (bin_lds <= 64 * 1024) &&
                      (in_ch <= (1 << 22)) &&
                      (((size_t)nnz + (size_t)ne) * 8 <= NBH);

    if (fast) {
        const int nwaves = (n + 3) / 4;
        const int row_blocks = (int)(((long long)nwaves * 64 + BLK - 1) / BLK);
        const int chunk_feat = (nnz + BIN_WGS - 1) / BIN_WGS;
        const int chunk_adj  = (ne + BIN_WGS - 1) / BIN_WGS;
        const int w2 = in_ch * 64;
        const size_t hist_lds = (size_t)nbuck * sizeof(int);
        const int wgscan_blocks = (2 * nbuck + 3) / 4;   // 4 waves / 256-thread block

        // --- W fp16 conversion ---
        wconv_kernel<<<(w2 + BLK - 1) / BLK, BLK, 0, stream>>>(weight, Wh, w2);

        // --- merged CSR build (both matrices) ---
        hist2_kernel<<<2 * BIN_WGS, BIN_THR, hist_lds, stream>>>(
            feat_rows, nnz, chunk_feat, adj_rows, ne, chunk_adj, wgc, nbuck);
        wgscan2_kernel<<<wgscan_blocks, 256, 0, stream>>>(wgc, bcounts, nbuck, BIN_WGS);
        bucket_scan2_kernel<<<2, SCAN_BLK, 0, stream>>>(bcounts, bbase, nbuck);
        bin2_kernel<<<2 * BIN_WGS, BIN_THR, bin_lds, stream>>>(
            feat_rows, feat_cols, feat_vals, nnz, chunk_feat,
            adj_rows, adj_cols, adj_vals, ne, chunk_adj,
            bbase, wgc, cvt_f, cvt_a, nbuck);

        // --- feat: reorder -> spmm ---
        reorder2_kernel<<<nbuck, BIN_THR, 0, stream>>>(bbase, cvt_f, cv, row_ptr, n);
        spmm_r4_kernel<<<row_blocks, BLK, 0, stream>>>(
            row_ptr, (const long long*)cv, Wh, bias, baseh, n);

        // --- adj: reorder (reuses cv + row_ptr after spmm) -> prop x2 ---
        reorder2_kernel<<<nbuck, BIN_THR, 0, stream>>>(bbase + (nbuck + 1), cvt_a, cv, row_ptr, n);
        prop_r4_h2h_kernel<<<row_blocks, BLK, 0, stream>>>(
            row_ptr, (const long long*)cv, baseh, pingh, n);
        prop_r4_h2f_kernel<<<row_blocks, BLK, 0, stream>>>(
            row_ptr, (const long long*)cv, pingh, out, n);
    } else {
        // round-1 fallback: atomic scatter (f32)
        float* ping = (float*)ws;
        const int spmm_blocks = (int)(((long long)nnz * 32 + BLK - 1) / BLK);
        const int prop_blocks = (int)(((long long)ne * 32 + BLK - 1) / BLK);
        hipMemsetAsync(d_out, 0, NBF, stream);
        spmm_scatter_kernel<<<spmm_blocks, BLK, 0, stream>>>(feat_rows, feat_cols, feat_vals,
                                                             weight, out, nnz);
        bias_relu_kernel<<<ew_blocks, BLK, 0, stream>>>(out, bias, total_elems);
        hipMemsetAsync(ping, 0, NBF, stream);
        prop_scatter_kernel<<<prop_blocks, BLK, 0, stream>>>(adj_rows, adj_cols, adj_vals,
                                                             out, ping, ne);
        hipMemsetAsync(d_out, 0, NBF, stream);
        prop_scatter_kernel<<<prop_blocks, BLK, 0, stream>>>(adj_rows, adj_cols, adj_vals,
                                                             ping, out, ne);
    }
}